// Round 1
// baseline (1255.973 us; speedup 1.0000x reference)
//
#include <hip/hip_runtime.h>
#include <cmath>

// Problem dims
#define TN 4
#define TC1 256
#define TCH 128
#define TC2 256
#define TH 80
#define TW 80
#define THP 82     // padded rows for cv1 input
#define TWP 84     // padded row stride (alignment-friendly)
#define NPIX (TN*TH*TW)   // 25600

// Workspace layout (float offsets). Total = 17,356,288 floats = 69.4 MB.
#define OFF_W1T   0         // [ky][ci][kx][co]  294912
#define OFF_W2T   294912    // [ci][co]          32768
#define OFF_INWT  327680    // [ci][co]          65536
#define OFF_OUTWT 393216    // [ci][co]          65536
#define OFF_DWT   458752    // [tap][c]          2304
#define OFF_WCAT  461056    // [j<27][c]         6912
#define OFF_WCATB 467968    // 27 (padded 32)
#define OFF_S1    468000
#define OFF_T1    468128
#define OFF_S2    468256
#define OFF_T2    468512
#define OFF_S3    468768
#define OFF_T3    469024
#define OFF_XPAD  469504    // 4*256*82*84 = 7,056,384
#define OFF_Y1    7525888   // 4*128*80*80 = 3,276,800
#define OFF_Y2    10802688  // 4*256*80*80 = 6,553,600 -> end 17,356,288
// aliases (dead-before-reuse verified by stream order):
#define OFF_DW    OFF_XPAD  // dw/LN/GELU output (26.2MB <= 28.2MB)
#define OFF_RAW   OFF_Y1    // 27 floats/pixel (2.76MB <= 13.1MB)
#define OFF_Z     OFF_Y2    // DCN output

__device__ __forceinline__ float siluf(float v) { return v / (1.f + expf(-v)); }

// ---------------- prep: weight transposes + BN constant folding ----------------
__global__ __launch_bounds__(256) void k_prep(
    const float* __restrict__ w1, const float* __restrict__ g1, const float* __restrict__ b1,
    const float* __restrict__ m1, const float* __restrict__ v1,
    const float* __restrict__ w2, const float* __restrict__ g2, const float* __restrict__ b2,
    const float* __restrict__ m2, const float* __restrict__ v2,
    const float* __restrict__ dww, const float* __restrict__ offw, const float* __restrict__ offb,
    const float* __restrict__ mskw, const float* __restrict__ mskb,
    const float* __restrict__ inw, const float* __restrict__ outw,
    const float* __restrict__ g3, const float* __restrict__ b3,
    const float* __restrict__ m3, const float* __restrict__ v3,
    float* __restrict__ ws)
{
  int i = blockIdx.x * 256 + threadIdx.x;
  if (i < 294912) {                 // w1t[ky][ci][kx][co] <- w1[co][ci][ky][kx]
    int co = i & 127; int r = i >> 7; int kx = r % 3; r /= 3; int ci = r & 255; int ky = r >> 8;
    ws[OFF_W1T + i] = w1[((co * TC1 + ci) * 3 + ky) * 3 + kx];
    return;
  }
  i -= 294912;
  if (i < 32768) { int co = i & 255; int ci = i >> 8; ws[OFF_W2T + i] = w2[co * TCH + ci]; return; }
  i -= 32768;
  if (i < 65536) { int co = i & 255; int ci = i >> 8; ws[OFF_INWT + i] = inw[co * TC2 + ci]; return; }
  i -= 65536;
  if (i < 65536) { int co = i & 255; int ci = i >> 8; ws[OFF_OUTWT + i] = outw[co * TC2 + ci]; return; }
  i -= 65536;
  if (i < 2304) { int c = i & 255; int j = i >> 8; ws[OFF_DWT + i] = dww[c * 9 + j]; return; }
  i -= 2304;
  if (i < 6912) {
    int c = i & 255; int j = i >> 8;
    ws[OFF_WCAT + i] = (j < 18) ? offw[j * 256 + c] : mskw[(j - 18) * 256 + c];
    return;
  }
  i -= 6912;
  if (i < 27) { ws[OFF_WCATB + i] = (i < 18) ? offb[i] : mskb[i - 18]; return; }
  i -= 27;
  if (i < 128) { float s = g1[i] / sqrtf(v1[i] + 1e-5f); ws[OFF_S1 + i] = s; ws[OFF_T1 + i] = b1[i] - m1[i] * s; return; }
  i -= 128;
  if (i < 256) { float s = g2[i] / sqrtf(v2[i] + 1e-5f); ws[OFF_S2 + i] = s; ws[OFF_T2 + i] = b2[i] - m2[i] * s; return; }
  i -= 256;
  if (i < 256) { float s = g3[i] / sqrtf(v3[i] + 1e-5f); ws[OFF_S3 + i] = s; ws[OFF_T3 + i] = b3[i] - m3[i] * s; return; }
}

// ---------------- zero-padded, aligned copy of x for cv1 ----------------
__global__ __launch_bounds__(256) void k_padx(const float* __restrict__ x, float* __restrict__ xpad)
{
  int i = blockIdx.x * 256 + threadIdx.x;     // grid is exact: 4*256*82*84 / 256
  int cc = i % TWP; int r = (i / TWP) % THP; int q = i / (TWP * THP);  // q = n*256+ci
  int rr = r - 1, c2 = cc - 1;
  float v = 0.f;
  if (rr >= 0 && rr < TH && c2 >= 0 && c2 < TW) v = x[q * (TH * TW) + rr * TW + c2];
  xpad[i] = v;
}

// ---------------- cv1: 3x3 conv 256->128 + BN + SiLU (NCHW out) ----------------
// grid 400 = 4n * 20ht(4 rows) * 5wt(16 cols); thread tile 4co x 8px
__global__ __launch_bounds__(256) void k_cv1(const float* __restrict__ xpad, const float* __restrict__ w1t,
                                             const float* __restrict__ s1v, const float* __restrict__ t1v,
                                             float* __restrict__ y1)
{
  int b = blockIdx.x;
  int wt = b % 5; b /= 5; int ht = b % 20; int n = b / 20;
  int h0 = ht * 4, w0 = wt * 16;
  int tid = threadIdx.x;
  int cog = tid & 31, pg = tid >> 5;
  int py = pg >> 1, px0 = (pg & 1) * 8;
  int co = cog * 4;
  float acc[4][8];
#pragma unroll
  for (int c = 0; c < 4; ++c)
#pragma unroll
    for (int q = 0; q < 8; ++q) acc[c][q] = 0.f;

  for (int ky = 0; ky < 3; ++ky) {
    const float* xr = xpad + ((n * TC1) * THP + (h0 + py + ky)) * TWP + (w0 + px0);
    const float* wr = w1t + ky * (TC1 * 3 * TCH) + co;
#pragma unroll 2
    for (int ci = 0; ci < TC1; ++ci) {
      const float* xp = xr + ci * (THP * TWP);
      float4 a0 = *(const float4*)(xp);
      float4 a1 = *(const float4*)(xp + 4);
      float4 a2 = *(const float4*)(xp + 8);
      const float* wp = wr + ci * (3 * TCH);
      float4 wv0 = *(const float4*)(wp);
      float4 wv1 = *(const float4*)(wp + TCH);
      float4 wv2 = *(const float4*)(wp + 2 * TCH);
      float xv[12] = {a0.x, a0.y, a0.z, a0.w, a1.x, a1.y, a1.z, a1.w, a2.x, a2.y, a2.z, a2.w};
#pragma unroll
      for (int q = 0; q < 8; ++q) {
        float x0 = xv[q], x1 = xv[q + 1], x2 = xv[q + 2];
        acc[0][q] += wv0.x * x0 + wv1.x * x1 + wv2.x * x2;
        acc[1][q] += wv0.y * x0 + wv1.y * x1 + wv2.y * x2;
        acc[2][q] += wv0.z * x0 + wv1.z * x1 + wv2.z * x2;
        acc[3][q] += wv0.w * x0 + wv1.w * x1 + wv2.w * x2;
      }
    }
  }
#pragma unroll
  for (int c = 0; c < 4; ++c) {
    float s = s1v[co + c], t = t1v[co + c];
    float* yp = y1 + ((n * TCH + co + c) * TH + (h0 + py)) * TW + (w0 + px0);
    float o[8];
#pragma unroll
    for (int q = 0; q < 8; ++q) o[q] = siluf(acc[c][q] * s + t);
    *(float4*)(yp)     = make_float4(o[0], o[1], o[2], o[3]);
    *(float4*)(yp + 4) = make_float4(o[4], o[5], o[6], o[7]);
  }
}

// ---------------- cv2: 1x1 conv 128->256 + BN + SiLU -> y2 NHWC ----------------
// grid 800 = 4n * 40ht(2 rows) * 5wt(16 cols); thread tile 4co x 8px
__global__ __launch_bounds__(256) void k_cv2(const float* __restrict__ y1, const float* __restrict__ w2t,
                                             const float* __restrict__ s2v, const float* __restrict__ t2v,
                                             float* __restrict__ y2)
{
  int b = blockIdx.x;
  int wt = b % 5; b /= 5; int ht = b % 40; int n = b / 40;
  int h0 = ht * 2, w0 = wt * 16;
  int tid = threadIdx.x;
  int cog = tid & 63, pg = tid >> 6;
  int py = pg >> 1, px0 = (pg & 1) * 8;
  int co = cog * 4;
  float acc[4][8];
#pragma unroll
  for (int c = 0; c < 4; ++c)
#pragma unroll
    for (int q = 0; q < 8; ++q) acc[c][q] = 0.f;

  const float* xr = y1 + ((n * TCH) * TH + (h0 + py)) * TW + (w0 + px0);
#pragma unroll 2
  for (int ci = 0; ci < TCH; ++ci) {
    const float* xp = xr + ci * (TH * TW);
    float4 a0 = *(const float4*)(xp);
    float4 a1 = *(const float4*)(xp + 4);
    float4 wv = *(const float4*)(w2t + ci * TC2 + co);
    float xv[8] = {a0.x, a0.y, a0.z, a0.w, a1.x, a1.y, a1.z, a1.w};
#pragma unroll
    for (int q = 0; q < 8; ++q) {
      acc[0][q] += wv.x * xv[q];
      acc[1][q] += wv.y * xv[q];
      acc[2][q] += wv.z * xv[q];
      acc[3][q] += wv.w * xv[q];
    }
  }
  int pixbase = (n * TH + (h0 + py)) * TW + (w0 + px0);
  float s0 = s2v[co], s1 = s2v[co + 1], s2 = s2v[co + 2], s3 = s2v[co + 3];
  float t0 = t2v[co], t1 = t2v[co + 1], t2 = t2v[co + 2], t3 = t2v[co + 3];
#pragma unroll
  for (int q = 0; q < 8; ++q) {
    float4 o;
    o.x = siluf(acc[0][q] * s0 + t0);
    o.y = siluf(acc[1][q] * s1 + t1);
    o.z = siluf(acc[2][q] * s2 + t2);
    o.w = siluf(acc[3][q] * s3 + t3);
    *(float4*)(y2 + (pixbase + q) * TC2 + co) = o;
  }
}

// ---------------- input_proj: xproj = y2 @ in_w.T + in_b (NHWC) ----------------
__global__ __launch_bounds__(256) void k_proj_in(const float* __restrict__ y2, const float* __restrict__ inwt,
                                                 const float* __restrict__ inb, float* __restrict__ xproj)
{
  int b = blockIdx.x;
  int wt = b % 5; b /= 5; int ht = b % 40; int n = b / 40;
  int h0 = ht * 2, w0 = wt * 16;
  int tid = threadIdx.x;
  int cog = tid & 63, pg = tid >> 6;
  int py = pg >> 1, px0 = (pg & 1) * 8;
  int co = cog * 4;
  int pixbase = (n * TH + (h0 + py)) * TW + (w0 + px0);
  const float* xr = y2 + pixbase * TC2;   // xr[q*256 + ci]
  float acc[4][8];
#pragma unroll
  for (int c = 0; c < 4; ++c)
#pragma unroll
    for (int q = 0; q < 8; ++q) acc[c][q] = 0.f;

#pragma unroll 2
  for (int ci = 0; ci < TC2; ++ci) {
    float4 wv = *(const float4*)(inwt + ci * TC2 + co);
#pragma unroll
    for (int q = 0; q < 8; ++q) {
      float xq = xr[q * TC2 + ci];        // wave-uniform broadcast load
      acc[0][q] += wv.x * xq;
      acc[1][q] += wv.y * xq;
      acc[2][q] += wv.z * xq;
      acc[3][q] += wv.w * xq;
    }
  }
  float b0 = inb[co], b1 = inb[co + 1], b2 = inb[co + 2], b3 = inb[co + 3];
#pragma unroll
  for (int q = 0; q < 8; ++q) {
    float4 o = make_float4(acc[0][q] + b0, acc[1][q] + b1, acc[2][q] + b2, acc[3][q] + b3);
    *(float4*)(xproj + (pixbase + q) * TC2 + co) = o;
  }
}

// ---------------- depthwise 3x3 + bias + LayerNorm + GELU (block per pixel) ----------------
__global__ __launch_bounds__(256) void k_dwln(const float* __restrict__ y2, const float* __restrict__ dwt,
                                              const float* __restrict__ dwb, const float* __restrict__ lng,
                                              const float* __restrict__ lnb, float* __restrict__ dwo)
{
  int pix = blockIdx.x;
  int c = threadIdx.x;
  int w = pix % TW; int h = (pix / TW) % TH; int n = pix / (TH * TW);
  float v = dwb[c];
#pragma unroll
  for (int dy = 0; dy < 3; ++dy) {
    int hh = h + dy - 1;
    if (hh < 0 || hh >= TH) continue;       // block-uniform branch
#pragma unroll
    for (int dx = 0; dx < 3; ++dx) {
      int ww = w + dx - 1;
      if (ww < 0 || ww >= TW) continue;
      v += y2[((n * TH + hh) * TW + ww) * TC2 + c] * dwt[(dy * 3 + dx) * TC2 + c];
    }
  }
  float sv = v, sq = v * v;
#pragma unroll
  for (int o = 32; o > 0; o >>= 1) { sv += __shfl_xor(sv, o); sq += __shfl_xor(sq, o); }
  __shared__ float red[8];
  int wid = c >> 6;
  if ((c & 63) == 0) { red[wid] = sv; red[4 + wid] = sq; }
  __syncthreads();
  float ts = red[0] + red[1] + red[2] + red[3];
  float tq = red[4] + red[5] + red[6] + red[7];
  float mu = ts * (1.f / 256.f);
  float var = tq * (1.f / 256.f) - mu * mu;
  float nv = (v - mu) / sqrtf(var + 1e-6f);
  nv = nv * lng[c] + lnb[c];
  float g = 0.5f * nv * (1.f + erff(nv * 0.70710678118654752f));
  dwo[pix * TC2 + c] = g;
}

// ---------------- offset/mask logits: raw27[pix][27] ----------------
__global__ __launch_bounds__(256) void k_offmask(const float* __restrict__ dw, const float* __restrict__ wcat,
                                                 const float* __restrict__ wcatb, float* __restrict__ raw)
{
  int g = blockIdx.x * 256 + threadIdx.x;
  if (g >= NPIX * 27) return;
  int j = g % 27, pix = g / 27;
  const float4* a = (const float4*)(dw + pix * TC2);
  const float4* wv = (const float4*)(wcat + j * TC2);
  float acc = 0.f;
#pragma unroll 4
  for (int i = 0; i < 64; ++i) {
    float4 xx = a[i], yy = wv[i];
    acc += xx.x * yy.x + xx.y * yy.y + xx.z * yy.z + xx.w * yy.w;
  }
  raw[g] = acc + wcatb[j];
}

// ---------------- DCN core: softmax(mask) + bilinear gather (block per pixel) ----------------
__device__ __forceinline__ float dcn_sample(const float* __restrict__ xb, int yi, int xi, float wt)
{
  // padded coords; nonzero-value region is [1..80]^2 (zeros padding elsewhere)
  bool valid = (xi >= 1) & (xi <= TW) & (yi >= 1) & (yi <= TH);
  int idx = valid ? (((yi - 1) * TW + (xi - 1)) * TC2) : 0;
  float wv = valid ? wt : 0.f;
  return wv * xb[idx];
}

__global__ __launch_bounds__(256) void k_dcn(const float* __restrict__ xproj, const float* __restrict__ raw,
                                             float* __restrict__ z)
{
  int pix = blockIdx.x;
  int c = threadIdx.x;
  int w = pix % TW; int h = (pix / TW) % TH; int n = pix / (TH * TW);
  const float* r = raw + pix * 27;
  // softmax over the 9 mask logits (redundant per thread: pure VALU, no LDS serialization)
  float mx = r[18];
#pragma unroll
  for (int k = 1; k < 9; ++k) mx = fmaxf(mx, r[18 + k]);
  float e[9]; float sum = 0.f;
#pragma unroll
  for (int k = 0; k < 9; ++k) { float ee = expf(r[18 + k] - mx); e[k] = ee; sum += ee; }
  float inv = 1.f / sum;

  float acc = 0.f;
  const float* xb = xproj + n * (TH * TW * TC2) + c;
#pragma unroll
  for (int k = 0; k < 9; ++k) {
    // padded-coordinate sample position: px = w + (k/3) + off_x ; py = h + (k%3) + off_y
    float px = (float)(w + k / 3) + r[2 * k];
    float py = (float)(h + k % 3) + r[2 * k + 1];
    float x0f = floorf(px), y0f = floorf(py);
    float lw = px - x0f, lh = py - y0f;
    int x0 = (int)x0f, y0 = (int)y0f;
    float mk = e[k] * inv;
    float w00 = mk * (1.f - lh) * (1.f - lw);
    float w01 = mk * (1.f - lh) * lw;
    float w10 = mk * lh * (1.f - lw);
    float w11 = mk * lh * lw;
    acc += dcn_sample(xb, y0,     x0,     w00);
    acc += dcn_sample(xb, y0,     x0 + 1, w01);
    acc += dcn_sample(xb, y0 + 1, x0,     w10);
    acc += dcn_sample(xb, y0 + 1, x0 + 1, w11);
  }
  z[pix * TC2 + c] = acc;
}

// ---------------- output_proj + BN + SiLU + residual -> d_out NCHW ----------------
__global__ __launch_bounds__(256) void k_proj_out(const float* __restrict__ z, const float* __restrict__ outwt,
                                                  const float* __restrict__ outb,
                                                  const float* __restrict__ s3v, const float* __restrict__ t3v,
                                                  const float* __restrict__ x, float* __restrict__ out)
{
  int b = blockIdx.x;
  int wt = b % 5; b /= 5; int ht = b % 40; int n = b / 40;
  int h0 = ht * 2, w0 = wt * 16;
  int tid = threadIdx.x;
  int cog = tid & 63, pg = tid >> 6;
  int py = pg >> 1, px0 = (pg & 1) * 8;
  int co = cog * 4;
  int pixbase = (n * TH + (h0 + py)) * TW + (w0 + px0);
  const float* xr = z + pixbase * TC2;
  float acc[4][8];
#pragma unroll
  for (int c = 0; c < 4; ++c)
#pragma unroll
    for (int q = 0; q < 8; ++q) acc[c][q] = 0.f;

#pragma unroll 2
  for (int ci = 0; ci < TC2; ++ci) {
    float4 wv = *(const float4*)(outwt + ci * TC2 + co);
#pragma unroll
    for (int q = 0; q < 8; ++q) {
      float xq = xr[q * TC2 + ci];        // wave-uniform broadcast load
      acc[0][q] += wv.x * xq;
      acc[1][q] += wv.y * xq;
      acc[2][q] += wv.z * xq;
      acc[3][q] += wv.w * xq;
    }
  }
#pragma unroll
  for (int c = 0; c < 4; ++c) {
    float s = s3v[co + c], t = t3v[co + c], bo = outb[co + c];
    int base = ((n * TC2 + co + c) * TH + (h0 + py)) * TW + (w0 + px0);
    const float* xin = x + base;
    float* op = out + base;
    float o[8];
#pragma unroll
    for (int q = 0; q < 8; ++q) {
      float v = acc[c][q] + bo;
      v = v * s + t;
      o[q] = xin[q] + siluf(v);
    }
    *(float4*)(op)     = make_float4(o[0], o[1], o[2], o[3]);
    *(float4*)(op + 4) = make_float4(o[4], o[5], o[6], o[7]);
  }
}

extern "C" void kernel_launch(void* const* d_in, const int* in_sizes, int n_in,
                              void* d_out, int out_size, void* d_ws, size_t ws_size,
                              hipStream_t stream)
{
  const float* x    = (const float*)d_in[0];
  const float* w1   = (const float*)d_in[1];
  const float* g1   = (const float*)d_in[2];
  const float* b1   = (const float*)d_in[3];
  const float* m1   = (const float*)d_in[4];
  const float* v1   = (const float*)d_in[5];
  const float* w2   = (const float*)d_in[6];
  const float* g2   = (const float*)d_in[7];
  const float* b2   = (const float*)d_in[8];
  const float* m2   = (const float*)d_in[9];
  const float* v2   = (const float*)d_in[10];
  const float* dww  = (const float*)d_in[11];
  const float* dwb  = (const float*)d_in[12];
  const float* lng  = (const float*)d_in[13];
  const float* lnb  = (const float*)d_in[14];
  const float* offw = (const float*)d_in[15];
  const float* offb = (const float*)d_in[16];
  const float* mskw = (const float*)d_in[17];
  const float* mskb = (const float*)d_in[18];
  const float* inw  = (const float*)d_in[19];
  const float* inb  = (const float*)d_in[20];
  const float* outw = (const float*)d_in[21];
  const float* outb = (const float*)d_in[22];
  const float* g3   = (const float*)d_in[23];
  const float* b3   = (const float*)d_in[24];
  const float* m3   = (const float*)d_in[25];
  const float* v3   = (const float*)d_in[26];

  float* ws  = (float*)d_ws;
  float* out = (float*)d_out;

  float* xpad  = ws + OFF_XPAD;
  float* y1    = ws + OFF_Y1;
  float* y2    = ws + OFF_Y2;
  float* dwo   = ws + OFF_DW;     // aliases xpad (dead after cv1)
  float* raw   = ws + OFF_RAW;    // aliases y1  (dead after cv2)
  float* zb    = ws + OFF_Z;      // aliases y2  (dead after proj_in & dwln)
  float* xproj = out;             // d_out doubles as x_proj scratch (overwritten by proj_out)

  hipLaunchKernelGGL(k_prep, dim3(1831), dim3(256), 0, stream,
                     w1, g1, b1, m1, v1, w2, g2, b2, m2, v2,
                     dww, offw, offb, mskw, mskb, inw, outw, g3, b3, m3, v3, ws);
  hipLaunchKernelGGL(k_padx,     dim3(27564), dim3(256), 0, stream, x, xpad);
  hipLaunchKernelGGL(k_cv1,      dim3(400),   dim3(256), 0, stream, xpad, ws + OFF_W1T, ws + OFF_S1, ws + OFF_T1, y1);
  hipLaunchKernelGGL(k_cv2,      dim3(800),   dim3(256), 0, stream, y1, ws + OFF_W2T, ws + OFF_S2, ws + OFF_T2, y2);
  hipLaunchKernelGGL(k_proj_in,  dim3(800),   dim3(256), 0, stream, y2, ws + OFF_INWT, inb, xproj);
  hipLaunchKernelGGL(k_dwln,     dim3(25600), dim3(256), 0, stream, y2, ws + OFF_DWT, dwb, lng, lnb, dwo);
  hipLaunchKernelGGL(k_offmask,  dim3(2700),  dim3(256), 0, stream, dwo, ws + OFF_WCAT, ws + OFF_WCATB, raw);
  hipLaunchKernelGGL(k_dcn,      dim3(25600), dim3(256), 0, stream, xproj, raw, zb);
  hipLaunchKernelGGL(k_proj_out, dim3(800),   dim3(256), 0, stream, zb, ws + OFF_OUTWT, outb, ws + OFF_S3, ws + OFF_T3, x, out);
}

// Round 2
// 920.704 us; speedup vs baseline: 1.3641x; 1.3641x over previous
//
#include <hip/hip_runtime.h>
#include <cmath>

// Problem dims
#define TN 4
#define TC1 256
#define TCH 128
#define TC2 256
#define TH 80
#define TW 80
#define THP 82     // padded rows
#define TWP 84     // padded row stride
#define NPIX (TN*TH*TW)   // 25600

// Workspace layout (float offsets). Total = 17,356,288 floats = 69.4 MB.
#define OFF_WBF   0         // bf16 wbf[co][tap*256+ci] : 294912 shorts = 147456 floats (region 294912 floats)
#define OFF_W2T   294912    // [ci][co]          32768
#define OFF_INWT  327680    // [ci][co]          65536
#define OFF_OUTWT 393216    // [ci][co]          65536
#define OFF_DWT   458752    // [tap][c]          2304
#define OFF_WCAT  461056    // [j<27][c]         6912
#define OFF_WCATB 467968    // 27 (padded 32)
#define OFF_S1    468000
#define OFF_T1    468128
#define OFF_S2    468256
#define OFF_T2    468512
#define OFF_S3    468768
#define OFF_T3    469024
#define OFF_XPAD  469504    // bf16 NHWC padded x: 4*82*84*256 shorts = 3,528,192 floats (region 7,056,384)
#define OFF_Y1    7525888   // 4*128*80*80 = 3,276,800
#define OFF_Y2    10802688  // 4*256*80*80 = 6,553,600 -> end 17,356,288
// aliases (dead-before-reuse verified by stream order):
#define OFF_DW    OFF_XPAD  // dw/LN/GELU output (xpad dead after cv1)
#define OFF_RAW   OFF_Y1    // 27 floats/pixel (y1 dead after cv2)
#define OFF_Z     OFF_Y2    // DCN output (y2 dead after proj_in & dwln)

typedef __attribute__((ext_vector_type(8))) short bf16x8;
typedef __attribute__((ext_vector_type(4))) float f32x4;

__device__ __forceinline__ float siluf(float v) { return v / (1.f + expf(-v)); }
__device__ __forceinline__ short rnbf(float f) {
  unsigned u = __float_as_uint(f);
  unsigned r = (u + 0x7fffu + ((u >> 16) & 1u)) >> 16;
  return (short)r;
}

// ---------------- prep: weight transposes + BN constant folding ----------------
__global__ __launch_bounds__(256) void k_prep(
    const float* __restrict__ w1, const float* __restrict__ g1, const float* __restrict__ b1,
    const float* __restrict__ m1, const float* __restrict__ v1,
    const float* __restrict__ w2, const float* __restrict__ g2, const float* __restrict__ b2,
    const float* __restrict__ m2, const float* __restrict__ v2,
    const float* __restrict__ dww, const float* __restrict__ offw, const float* __restrict__ offb,
    const float* __restrict__ mskw, const float* __restrict__ mskb,
    const float* __restrict__ inw, const float* __restrict__ outw,
    const float* __restrict__ g3, const float* __restrict__ b3,
    const float* __restrict__ m3, const float* __restrict__ v3,
    float* __restrict__ ws)
{
  int i = blockIdx.x * 256 + threadIdx.x;
  if (i < 294912) {                 // wbf[co][(ky*3+kx)*256+ci] = w1[co][ci][ky][kx] * s1[co]  (bf16)
    int co = i / 2304; int r = i - co * 2304;
    int tap = r >> 8; int ci = r & 255; int ky = tap / 3; int kx = tap - ky * 3;
    float s = g1[co] * __frsqrt_rn(v1[co] + 1e-5f);
    ((short*)(ws + OFF_WBF))[i] = rnbf(w1[((co * TC1 + ci) * 3 + ky) * 3 + kx] * s);
    return;
  }
  i -= 294912;
  if (i < 32768) { int co = i & 255; int ci = i >> 8; ws[OFF_W2T + i] = w2[co * TCH + ci]; return; }
  i -= 32768;
  if (i < 65536) { int co = i & 255; int ci = i >> 8; ws[OFF_INWT + i] = inw[co * TC2 + ci]; return; }
  i -= 65536;
  if (i < 65536) { int co = i & 255; int ci = i >> 8; ws[OFF_OUTWT + i] = outw[co * TC2 + ci]; return; }
  i -= 65536;
  if (i < 2304) { int c = i & 255; int j = i >> 8; ws[OFF_DWT + i] = dww[c * 9 + j]; return; }
  i -= 2304;
  if (i < 6912) {
    int c = i & 255; int j = i >> 8;
    ws[OFF_WCAT + i] = (j < 18) ? offw[j * 256 + c] : mskw[(j - 18) * 256 + c];
    return;
  }
  i -= 6912;
  if (i < 27) { ws[OFF_WCATB + i] = (i < 18) ? offb[i] : mskb[i - 18]; return; }
  i -= 27;
  if (i < 128) { float s = g1[i] / sqrtf(v1[i] + 1e-5f); ws[OFF_S1 + i] = s; ws[OFF_T1 + i] = b1[i] - m1[i] * s; return; }
  i -= 128;
  if (i < 256) { float s = g2[i] / sqrtf(v2[i] + 1e-5f); ws[OFF_S2 + i] = s; ws[OFF_T2 + i] = b2[i] - m2[i] * s; return; }
  i -= 256;
  if (i < 256) { float s = g3[i] / sqrtf(v3[i] + 1e-5f); ws[OFF_S3 + i] = s; ws[OFF_T3 + i] = b3[i] - m3[i] * s; return; }
}

// ---------------- x -> bf16 NHWC padded [4][82][84][256], zero halo ----------------
// grid = 4n * 82hp * 8(ci-chunks of 32) = 2624 blocks
__global__ __launch_bounds__(256) void k_padx(const float* __restrict__ x, short* __restrict__ xpn)
{
  __shared__ short lds[80 * 33];
  int b = blockIdx.x;
  int cc = b & 7; int hp = (b >> 3) % THP; int n = b / (THP * 8);
  int c0 = cc * 32;
  int t = threadIdx.x;
  int h = hp - 1;
  if (h >= 0 && h < TH) {
    for (int f = t; f < 80 * 32; f += 256) {
      int ci = f / 80; int w = f - ci * 80;
      lds[w * 33 + ci] = rnbf(x[((n * TC1 + c0 + ci) * TH + h) * TW + w]);
    }
  }
  __syncthreads();
  bool hv = (h >= 0 && h < TH);
  short* op = xpn + ((n * THP + hp) * TWP) * TC2 + c0;
  for (int g = t; g < TWP * 32; g += 256) {
    int ci = g & 31; int wp = g >> 5;
    short v = 0;
    if (hv && wp >= 1 && wp <= TW) v = lds[(wp - 1) * 33 + ci];
    op[wp * TC2 + ci] = v;
  }
}

// ---------------- cv1: bf16 MFMA implicit-GEMM 3x3 conv 256->128 + BN + SiLU ----------------
// grid 800 = 2 co-halves * 4n * 20(h/4) * 5(w/16); 4 waves, wave = one row x 16 px, co 64
__global__ __launch_bounds__(256) void k_cv1(const short* __restrict__ xpn, const short* __restrict__ wbf,
                                             const float* __restrict__ t1v, float* __restrict__ y1)
{
  int b = blockIdx.x;
  int wt = b % 5; b /= 5; int ht = b % 20; b /= 20; int n = b & 3; int ch = b >> 2;
  int co0 = ch * 64, h0 = ht * 4, w0 = wt * 16;
  int tid = threadIdx.x;
  int wave = tid >> 6, lane = tid & 63;
  int ln = lane & 15, q = lane >> 4;
  int row = h0 + wave;

  f32x4 acc0 = {0.f, 0.f, 0.f, 0.f};
  f32x4 acc1 = acc0, acc2 = acc0, acc3 = acc0;

  const short* wb = wbf + (co0 + ln) * 2304 + q * 8;

  for (int tap = 0; tap < 9; ++tap) {
    int ky = tap / 3, kx = tap - ky * 3;
    const short* xb = xpn + (((n * THP + row + ky) * TWP) + (w0 + ln + kx)) * TC2 + q * 8;
    const short* wtp = wb + tap * 256;
#pragma unroll
    for (int c0 = 0; c0 < 256; c0 += 32) {
      bf16x8 bfrag = *(const bf16x8*)(xb + c0);
      bf16x8 a0 = *(const bf16x8*)(wtp + 0 * 16 * 2304 + c0);
      bf16x8 a1 = *(const bf16x8*)(wtp + 1 * 16 * 2304 + c0);
      bf16x8 a2 = *(const bf16x8*)(wtp + 2 * 16 * 2304 + c0);
      bf16x8 a3 = *(const bf16x8*)(wtp + 3 * 16 * 2304 + c0);
      acc0 = __builtin_amdgcn_mfma_f32_16x16x32_bf16(a0, bfrag, acc0, 0, 0, 0);
      acc1 = __builtin_amdgcn_mfma_f32_16x16x32_bf16(a1, bfrag, acc1, 0, 0, 0);
      acc2 = __builtin_amdgcn_mfma_f32_16x16x32_bf16(a2, bfrag, acc2, 0, 0, 0);
      acc3 = __builtin_amdgcn_mfma_f32_16x16x32_bf16(a3, bfrag, acc3, 0, 0, 0);
    }
  }

  f32x4 accs[4] = {acc0, acc1, acc2, acc3};
#pragma unroll
  for (int mt = 0; mt < 4; ++mt) {
#pragma unroll
    for (int r = 0; r < 4; ++r) {
      int co = co0 + mt * 16 + q * 4 + r;
      float v = siluf(accs[mt][r] + t1v[co]);
      y1[((n * TCH + co) * TH + row) * TW + (w0 + ln)] = v;
    }
  }
}

// ---------------- cv2: 1x1 conv 128->256 + BN + SiLU -> y2 NHWC ----------------
__global__ __launch_bounds__(256) void k_cv2(const float* __restrict__ y1, const float* __restrict__ w2t,
                                             const float* __restrict__ s2v, const float* __restrict__ t2v,
                                             float* __restrict__ y2)
{
  int b = blockIdx.x;
  int wt = b % 5; b /= 5; int ht = b % 40; int n = b / 40;
  int h0 = ht * 2, w0 = wt * 16;
  int tid = threadIdx.x;
  int cog = tid & 63, pg = tid >> 6;
  int py = pg >> 1, px0 = (pg & 1) * 8;
  int co = cog * 4;
  float acc[4][8];
#pragma unroll
  for (int c = 0; c < 4; ++c)
#pragma unroll
    for (int q = 0; q < 8; ++q) acc[c][q] = 0.f;

  const float* xr = y1 + ((n * TCH) * TH + (h0 + py)) * TW + (w0 + px0);
#pragma unroll 2
  for (int ci = 0; ci < TCH; ++ci) {
    const float* xp = xr + ci * (TH * TW);
    float4 a0 = *(const float4*)(xp);
    float4 a1 = *(const float4*)(xp + 4);
    float4 wv = *(const float4*)(w2t + ci * TC2 + co);
    float xv[8] = {a0.x, a0.y, a0.z, a0.w, a1.x, a1.y, a1.z, a1.w};
#pragma unroll
    for (int q = 0; q < 8; ++q) {
      acc[0][q] += wv.x * xv[q];
      acc[1][q] += wv.y * xv[q];
      acc[2][q] += wv.z * xv[q];
      acc[3][q] += wv.w * xv[q];
    }
  }
  int pixbase = (n * TH + (h0 + py)) * TW + (w0 + px0);
  float s0 = s2v[co], s1 = s2v[co + 1], s2 = s2v[co + 2], s3 = s2v[co + 3];
  float t0 = t2v[co], t1 = t2v[co + 1], t2 = t2v[co + 2], t3 = t2v[co + 3];
#pragma unroll
  for (int q = 0; q < 8; ++q) {
    float4 o;
    o.x = siluf(acc[0][q] * s0 + t0);
    o.y = siluf(acc[1][q] * s1 + t1);
    o.z = siluf(acc[2][q] * s2 + t2);
    o.w = siluf(acc[3][q] * s3 + t3);
    *(float4*)(y2 + (pixbase + q) * TC2 + co) = o;
  }
}

// ---------------- input_proj: xproj = y2 @ in_w.T + in_b (NHWC) ----------------
__global__ __launch_bounds__(256) void k_proj_in(const float* __restrict__ y2, const float* __restrict__ inwt,
                                                 const float* __restrict__ inb, float* __restrict__ xproj)
{
  int b = blockIdx.x;
  int wt = b % 5; b /= 5; int ht = b % 40; int n = b / 40;
  int h0 = ht * 2, w0 = wt * 16;
  int tid = threadIdx.x;
  int cog = tid & 63, pg = tid >> 6;
  int py = pg >> 1, px0 = (pg & 1) * 8;
  int co = cog * 4;
  int pixbase = (n * TH + (h0 + py)) * TW + (w0 + px0);
  const float* xr = y2 + pixbase * TC2;
  float acc[4][8];
#pragma unroll
  for (int c = 0; c < 4; ++c)
#pragma unroll
    for (int q = 0; q < 8; ++q) acc[c][q] = 0.f;

#pragma unroll 2
  for (int ci = 0; ci < TC2; ++ci) {
    float4 wv = *(const float4*)(inwt + ci * TC2 + co);
#pragma unroll
    for (int q = 0; q < 8; ++q) {
      float xq = xr[q * TC2 + ci];
      acc[0][q] += wv.x * xq;
      acc[1][q] += wv.y * xq;
      acc[2][q] += wv.z * xq;
      acc[3][q] += wv.w * xq;
    }
  }
  float b0 = inb[co], b1 = inb[co + 1], b2 = inb[co + 2], b3 = inb[co + 3];
#pragma unroll
  for (int q = 0; q < 8; ++q) {
    float4 o = make_float4(acc[0][q] + b0, acc[1][q] + b1, acc[2][q] + b2, acc[3][q] + b3);
    *(float4*)(xproj + (pixbase + q) * TC2 + co) = o;
  }
}

// ---------------- depthwise 3x3 + bias + LayerNorm + GELU (block per pixel) ----------------
__global__ __launch_bounds__(256) void k_dwln(const float* __restrict__ y2, const float* __restrict__ dwt,
                                              const float* __restrict__ dwb, const float* __restrict__ lng,
                                              const float* __restrict__ lnb, float* __restrict__ dwo)
{
  int pix = blockIdx.x;
  int c = threadIdx.x;
  int w = pix % TW; int h = (pix / TW) % TH; int n = pix / (TH * TW);
  float v = dwb[c];
#pragma unroll
  for (int dy = 0; dy < 3; ++dy) {
    int hh = h + dy - 1;
    if (hh < 0 || hh >= TH) continue;
#pragma unroll
    for (int dx = 0; dx < 3; ++dx) {
      int ww = w + dx - 1;
      if (ww < 0 || ww >= TW) continue;
      v += y2[((n * TH + hh) * TW + ww) * TC2 + c] * dwt[(dy * 3 + dx) * TC2 + c];
    }
  }
  float sv = v, sq = v * v;
#pragma unroll
  for (int o = 32; o > 0; o >>= 1) { sv += __shfl_xor(sv, o); sq += __shfl_xor(sq, o); }
  __shared__ float red[8];
  int wid = c >> 6;
  if ((c & 63) == 0) { red[wid] = sv; red[4 + wid] = sq; }
  __syncthreads();
  float ts = red[0] + red[1] + red[2] + red[3];
  float tq = red[4] + red[5] + red[6] + red[7];
  float mu = ts * (1.f / 256.f);
  float var = tq * (1.f / 256.f) - mu * mu;
  float nv = (v - mu) / sqrtf(var + 1e-6f);
  nv = nv * lng[c] + lnb[c];
  float g = 0.5f * nv * (1.f + erff(nv * 0.70710678118654752f));
  dwo[pix * TC2 + c] = g;
}

// ---------------- offset/mask logits: raw27[pix][27] ----------------
__global__ __launch_bounds__(256) void k_offmask(const float* __restrict__ dw, const float* __restrict__ wcat,
                                                 const float* __restrict__ wcatb, float* __restrict__ raw)
{
  int g = blockIdx.x * 256 + threadIdx.x;
  if (g >= NPIX * 27) return;
  int j = g % 27, pix = g / 27;
  const float4* a = (const float4*)(dw + pix * TC2);
  const float4* wv = (const float4*)(wcat + j * TC2);
  float acc = 0.f;
#pragma unroll 4
  for (int i = 0; i < 64; ++i) {
    float4 xx = a[i], yy = wv[i];
    acc += xx.x * yy.x + xx.y * yy.y + xx.z * yy.z + xx.w * yy.w;
  }
  raw[g] = acc + wcatb[j];
}

// ---------------- DCN core: softmax(mask) + bilinear gather (block per pixel) ----------------
__device__ __forceinline__ float dcn_sample(const float* __restrict__ xb, int yi, int xi, float wt)
{
  bool valid = (xi >= 1) & (xi <= TW) & (yi >= 1) & (yi <= TH);
  int idx = valid ? (((yi - 1) * TW + (xi - 1)) * TC2) : 0;
  float wv = valid ? wt : 0.f;
  return wv * xb[idx];
}

__global__ __launch_bounds__(256) void k_dcn(const float* __restrict__ xproj, const float* __restrict__ raw,
                                             float* __restrict__ z)
{
  int pix = blockIdx.x;
  int c = threadIdx.x;
  int w = pix % TW; int h = (pix / TW) % TH; int n = pix / (TH * TW);
  const float* r = raw + pix * 27;
  float mx = r[18];
#pragma unroll
  for (int k = 1; k < 9; ++k) mx = fmaxf(mx, r[18 + k]);
  float e[9]; float sum = 0.f;
#pragma unroll
  for (int k = 0; k < 9; ++k) { float ee = expf(r[18 + k] - mx); e[k] = ee; sum += ee; }
  float inv = 1.f / sum;

  float acc = 0.f;
  const float* xb = xproj + n * (TH * TW * TC2) + c;
#pragma unroll
  for (int k = 0; k < 9; ++k) {
    float px = (float)(w + k / 3) + r[2 * k];
    float py = (float)(h + k % 3) + r[2 * k + 1];
    float x0f = floorf(px), y0f = floorf(py);
    float lw = px - x0f, lh = py - y0f;
    int x0 = (int)x0f, y0 = (int)y0f;
    float mk = e[k] * inv;
    float w00 = mk * (1.f - lh) * (1.f - lw);
    float w01 = mk * (1.f - lh) * lw;
    float w10 = mk * lh * (1.f - lw);
    float w11 = mk * lh * lw;
    acc += dcn_sample(xb, y0,     x0,     w00);
    acc += dcn_sample(xb, y0,     x0 + 1, w01);
    acc += dcn_sample(xb, y0 + 1, x0,     w10);
    acc += dcn_sample(xb, y0 + 1, x0 + 1, w11);
  }
  z[pix * TC2 + c] = acc;
}

// ---------------- output_proj + BN + SiLU + residual -> d_out NCHW ----------------
__global__ __launch_bounds__(256) void k_proj_out(const float* __restrict__ z, const float* __restrict__ outwt,
                                                  const float* __restrict__ outb,
                                                  const float* __restrict__ s3v, const float* __restrict__ t3v,
                                                  const float* __restrict__ x, float* __restrict__ out)
{
  int b = blockIdx.x;
  int wt = b % 5; b /= 5; int ht = b % 40; int n = b / 40;
  int h0 = ht * 2, w0 = wt * 16;
  int tid = threadIdx.x;
  int cog = tid & 63, pg = tid >> 6;
  int py = pg >> 1, px0 = (pg & 1) * 8;
  int co = cog * 4;
  int pixbase = (n * TH + (h0 + py)) * TW + (w0 + px0);
  const float* xr = z + pixbase * TC2;
  float acc[4][8];
#pragma unroll
  for (int c = 0; c < 4; ++c)
#pragma unroll
    for (int q = 0; q < 8; ++q) acc[c][q] = 0.f;

#pragma unroll 2
  for (int ci = 0; ci < TC2; ++ci) {
    float4 wv = *(const float4*)(outwt + ci * TC2 + co);
#pragma unroll
    for (int q = 0; q < 8; ++q) {
      float xq = xr[q * TC2 + ci];
      acc[0][q] += wv.x * xq;
      acc[1][q] += wv.y * xq;
      acc[2][q] += wv.z * xq;
      acc[3][q] += wv.w * xq;
    }
  }
#pragma unroll
  for (int c = 0; c < 4; ++c) {
    float s = s3v[co + c], t = t3v[co + c], bo = outb[co + c];
    int base = ((n * TC2 + co + c) * TH + (h0 + py)) * TW + (w0 + px0);
    const float* xin = x + base;
    float* op = out + base;
    float o[8];
#pragma unroll
    for (int q = 0; q < 8; ++q) {
      float v = acc[c][q] + bo;
      v = v * s + t;
      o[q] = xin[q] + siluf(v);
    }
    *(float4*)(op)     = make_float4(o[0], o[1], o[2], o[3]);
    *(float4*)(op + 4) = make_float4(o[4], o[5], o[6], o[7]);
  }
}

extern "C" void kernel_launch(void* const* d_in, const int* in_sizes, int n_in,
                              void* d_out, int out_size, void* d_ws, size_t ws_size,
                              hipStream_t stream)
{
  const float* x    = (const float*)d_in[0];
  const float* w1   = (const float*)d_in[1];
  const float* g1   = (const float*)d_in[2];
  const float* b1   = (const float*)d_in[3];
  const float* m1   = (const float*)d_in[4];
  const float* v1   = (const float*)d_in[5];
  const float* w2   = (const float*)d_in[6];
  const float* g2   = (const float*)d_in[7];
  const float* b2   = (const float*)d_in[8];
  const float* m2   = (const float*)d_in[9];
  const float* v2   = (const float*)d_in[10];
  const float* dww  = (const float*)d_in[11];
  const float* dwb  = (const float*)d_in[12];
  const float* lng  = (const float*)d_in[13];
  const float* lnb  = (const float*)d_in[14];
  const float* offw = (const float*)d_in[15];
  const float* offb = (const float*)d_in[16];
  const float* mskw = (const float*)d_in[17];
  const float* mskb = (const float*)d_in[18];
  const float* inw  = (const float*)d_in[19];
  const float* inb  = (const float*)d_in[20];
  const float* outw = (const float*)d_in[21];
  const float* outb = (const float*)d_in[22];
  const float* g3   = (const float*)d_in[23];
  const float* b3   = (const float*)d_in[24];
  const float* m3   = (const float*)d_in[25];
  const float* v3   = (const float*)d_in[26];

  float* ws  = (float*)d_ws;
  float* out = (float*)d_out;

  short* xpn   = (short*)(ws + OFF_XPAD);
  short* wbf   = (short*)(ws + OFF_WBF);
  float* y1    = ws + OFF_Y1;
  float* y2    = ws + OFF_Y2;
  float* dwo   = ws + OFF_DW;     // aliases xpad region (dead after cv1)
  float* raw   = ws + OFF_RAW;    // aliases y1  (dead after cv2)
  float* zb    = ws + OFF_Z;      // aliases y2  (dead after proj_in & dwln)
  float* xproj = out;             // d_out doubles as x_proj scratch

  hipLaunchKernelGGL(k_prep, dim3(1831), dim3(256), 0, stream,
                     w1, g1, b1, m1, v1, w2, g2, b2, m2, v2,
                     dww, offw, offb, mskw, mskb, inw, outw, g3, b3, m3, v3, ws);
  hipLaunchKernelGGL(k_padx,     dim3(TN * THP * 8), dim3(256), 0, stream, x, xpn);
  hipLaunchKernelGGL(k_cv1,      dim3(800),   dim3(256), 0, stream, xpn, wbf, ws + OFF_T1, y1);
  hipLaunchKernelGGL(k_cv2,      dim3(800),   dim3(256), 0, stream, y1, ws + OFF_W2T, ws + OFF_S2, ws + OFF_T2, y2);
  hipLaunchKernelGGL(k_proj_in,  dim3(800),   dim3(256), 0, stream, y2, ws + OFF_INWT, inb, xproj);
  hipLaunchKernelGGL(k_dwln,     dim3(25600), dim3(256), 0, stream, y2, ws + OFF_DWT, dwb, lng, lnb, dwo);
  hipLaunchKernelGGL(k_offmask,  dim3(2700),  dim3(256), 0, stream, dwo, ws + OFF_WCAT, ws + OFF_WCATB, raw);
  hipLaunchKernelGGL(k_dcn,      dim3(25600), dim3(256), 0, stream, xproj, raw, zb);
  hipLaunchKernelGGL(k_proj_out, dim3(800),   dim3(256), 0, stream, zb, ws + OFF_OUTWT, outb, ws + OFF_S3, ws + OFF_T3, x, out);
}

// Round 3
// 640.154 us; speedup vs baseline: 1.9620x; 1.4383x over previous
//
#include <hip/hip_runtime.h>
#include <cmath>

// Problem dims
#define TN 4
#define TC1 256
#define TCH 128
#define TC2 256
#define TH 80
#define TW 80
#define THP 82
#define TWP 84
#define NPIX (TN*TH*TW)   // 25600

// Workspace layout (float offsets). Total = 17,356,288 floats = 69.4 MB.
#define OFF_WBF   0         // bf16 wbf[co][tap*256+ci], s1-folded: 294912 shorts
#define OFF_W2B   294912    // bf16 [co][ci=128], s2-folded: 32768 shorts
#define OFF_INWB  327680    // bf16 [co][ci=256]: 65536 shorts
#define OFF_OUTWB 393216    // bf16 [co][ci=256], s3-folded: 65536 shorts
#define OFF_DWT   458752    // fp32 [tap][c] 2304
#define OFF_WCAT  461056    // fp32 [j<27][c] 6912
#define OFF_WCATB 467968    // 27
#define OFF_T1    468128    // 128
#define OFF_T2    468512    // 256
#define OFF_T3P   469024    // 256  (= out_b*s3 + b3 - m3*s3)
#define OFF_XPAD  469504    // bf16 NHWC padded x [4][82][84][256] shorts
#define OFF_Y1    7525888   // bf16 y1 [25600][128] shorts (region 3.27M floats)
#define OFF_Y2    10802688  // bf16 y2 [25600][256] shorts (region 6.55M floats)
// aliases (dead-before-reuse by stream order):
#define OFF_DW    OFF_XPAD  // fp32 dw/LN/GELU output (xpad dead after cv1)
#define OFF_RAW   OFF_Y1    // fp32 27/pixel (y1 dead after cv2)
#define OFF_Z     OFF_Y2    // bf16 DCN output (y2 dead after proj_in/dwln/offmask)

typedef __attribute__((ext_vector_type(8))) short bf16x8;
typedef __attribute__((ext_vector_type(4))) float f32x4;

__device__ __forceinline__ float siluf(float v) { return v / (1.f + expf(-v)); }
__device__ __forceinline__ short rnbf(float f) {
  unsigned u = __float_as_uint(f);
  unsigned r = (u + 0x7fffu + ((u >> 16) & 1u)) >> 16;
  return (short)r;
}
__device__ __forceinline__ float bf2f(short s) {
  return __uint_as_float(((unsigned)(unsigned short)s) << 16);
}

// ---------------- prep: weight transposes + BN constant folding ----------------
__global__ __launch_bounds__(256) void k_prep(
    const float* __restrict__ w1, const float* __restrict__ g1, const float* __restrict__ b1,
    const float* __restrict__ m1, const float* __restrict__ v1,
    const float* __restrict__ w2, const float* __restrict__ g2, const float* __restrict__ b2,
    const float* __restrict__ m2, const float* __restrict__ v2,
    const float* __restrict__ dww, const float* __restrict__ offw, const float* __restrict__ offb,
    const float* __restrict__ mskw, const float* __restrict__ mskb,
    const float* __restrict__ inw, const float* __restrict__ outw, const float* __restrict__ outb,
    const float* __restrict__ g3, const float* __restrict__ b3,
    const float* __restrict__ m3, const float* __restrict__ v3,
    float* __restrict__ ws)
{
  int i = blockIdx.x * 256 + threadIdx.x;
  if (i < 294912) {                 // wbf[co][(ky*3+kx)*256+ci] = w1[co][ci][ky][kx] * s1[co]
    int co = i / 2304; int r = i - co * 2304;
    int tap = r >> 8; int ci = r & 255; int ky = tap / 3; int kx = tap - ky * 3;
    float s = g1[co] * __frsqrt_rn(v1[co] + 1e-5f);
    ((short*)(ws + OFF_WBF))[i] = rnbf(w1[((co * TC1 + ci) * 3 + ky) * 3 + kx] * s);
    return;
  }
  i -= 294912;
  if (i < 32768) {                  // w2b[co][ci] = w2[co][ci] * s2[co]
    int co = i >> 7; int ci = i & 127;
    float s = g2[co] * __frsqrt_rn(v2[co] + 1e-5f);
    ((short*)(ws + OFF_W2B))[i] = rnbf(w2[co * TCH + ci] * s);
    return;
  }
  i -= 32768;
  if (i < 65536) {                  // inwb[co][ci]
    int co = i >> 8; int ci = i & 255;
    ((short*)(ws + OFF_INWB))[i] = rnbf(inw[co * TC2 + ci]);
    return;
  }
  i -= 65536;
  if (i < 65536) {                  // outwb[co][ci] = outw[co][ci] * s3[co]
    int co = i >> 8; int ci = i & 255;
    float s = g3[co] * __frsqrt_rn(v3[co] + 1e-5f);
    ((short*)(ws + OFF_OUTWB))[i] = rnbf(outw[co * TC2 + ci] * s);
    return;
  }
  i -= 65536;
  if (i < 2304) { int c = i & 255; int j = i >> 8; ws[OFF_DWT + i] = dww[c * 9 + j]; return; }
  i -= 2304;
  if (i < 6912) {
    int c = i & 255; int j = i >> 8;
    ws[OFF_WCAT + i] = (j < 18) ? offw[j * 256 + c] : mskw[(j - 18) * 256 + c];
    return;
  }
  i -= 6912;
  if (i < 27) { ws[OFF_WCATB + i] = (i < 18) ? offb[i] : mskb[i - 18]; return; }
  i -= 27;
  if (i < 128) { float s = g1[i] / sqrtf(v1[i] + 1e-5f); ws[OFF_T1 + i] = b1[i] - m1[i] * s; return; }
  i -= 128;
  if (i < 256) { float s = g2[i] / sqrtf(v2[i] + 1e-5f); ws[OFF_T2 + i] = b2[i] - m2[i] * s; return; }
  i -= 256;
  if (i < 256) { float s = g3[i] / sqrtf(v3[i] + 1e-5f); ws[OFF_T3P + i] = outb[i] * s + b3[i] - m3[i] * s; return; }
}

// ---------------- x -> bf16 NHWC padded [4][82][84][256], zero halo ----------------
__global__ __launch_bounds__(256) void k_padx(const float* __restrict__ x, short* __restrict__ xpn)
{
  __shared__ short lds[80 * 33];
  int b = blockIdx.x;
  int cc = b & 7; int hp = (b >> 3) % THP; int n = b / (THP * 8);
  int c0 = cc * 32;
  int t = threadIdx.x;
  int h = hp - 1;
  if (h >= 0 && h < TH) {
    for (int f = t; f < 80 * 32; f += 256) {
      int ci = f / 80; int w = f - ci * 80;
      lds[w * 33 + ci] = rnbf(x[((n * TC1 + c0 + ci) * TH + h) * TW + w]);
    }
  }
  __syncthreads();
  bool hv = (h >= 0 && h < TH);
  short* op = xpn + ((n * THP + hp) * TWP) * TC2 + c0;
  for (int g = t; g < TWP * 32; g += 256) {
    int ci = g & 31; int wp = g >> 5;
    short v = 0;
    if (hv && wp >= 1 && wp <= TW) v = lds[(wp - 1) * 33 + ci];
    op[wp * TC2 + ci] = v;
  }
}

// ---------------- cv1: bf16 MFMA implicit-GEMM 3x3 conv 256->128 + BN + SiLU -> y1 bf16 NHWC ----------------
__global__ __launch_bounds__(256) void k_cv1(const short* __restrict__ xpn, const short* __restrict__ wbf,
                                             const float* __restrict__ t1v, short* __restrict__ y1b)
{
  int b = blockIdx.x;
  int wt = b % 5; b /= 5; int ht = b % 20; b /= 20; int n = b & 3; int ch = b >> 2;
  int co0 = ch * 64, h0 = ht * 4, w0 = wt * 16;
  int tid = threadIdx.x;
  int wave = tid >> 6, lane = tid & 63;
  int ln = lane & 15, q = lane >> 4;
  int row = h0 + wave;

  f32x4 acc0 = {0.f, 0.f, 0.f, 0.f};
  f32x4 acc1 = acc0, acc2 = acc0, acc3 = acc0;

  const short* wb = wbf + (co0 + ln) * 2304 + q * 8;

  for (int tap = 0; tap < 9; ++tap) {
    int ky = tap / 3, kx = tap - ky * 3;
    const short* xb = xpn + (((n * THP + row + ky) * TWP) + (w0 + ln + kx)) * TC2 + q * 8;
    const short* wtp = wb + tap * 256;
#pragma unroll
    for (int c0 = 0; c0 < 256; c0 += 32) {
      bf16x8 bfrag = *(const bf16x8*)(xb + c0);
      bf16x8 a0 = *(const bf16x8*)(wtp + 0 * 16 * 2304 + c0);
      bf16x8 a1 = *(const bf16x8*)(wtp + 1 * 16 * 2304 + c0);
      bf16x8 a2 = *(const bf16x8*)(wtp + 2 * 16 * 2304 + c0);
      bf16x8 a3 = *(const bf16x8*)(wtp + 3 * 16 * 2304 + c0);
      acc0 = __builtin_amdgcn_mfma_f32_16x16x32_bf16(a0, bfrag, acc0, 0, 0, 0);
      acc1 = __builtin_amdgcn_mfma_f32_16x16x32_bf16(a1, bfrag, acc1, 0, 0, 0);
      acc2 = __builtin_amdgcn_mfma_f32_16x16x32_bf16(a2, bfrag, acc2, 0, 0, 0);
      acc3 = __builtin_amdgcn_mfma_f32_16x16x32_bf16(a3, bfrag, acc3, 0, 0, 0);
    }
  }

  f32x4 accs[4] = {acc0, acc1, acc2, acc3};
  int pix = (n * TH + row) * TW + (w0 + ln);
#pragma unroll
  for (int mt = 0; mt < 4; ++mt) {
    int co = co0 + mt * 16 + q * 4;
    short4 p;
    p.x = rnbf(siluf(accs[mt][0] + t1v[co]));
    p.y = rnbf(siluf(accs[mt][1] + t1v[co + 1]));
    p.z = rnbf(siluf(accs[mt][2] + t1v[co + 2]));
    p.w = rnbf(siluf(accs[mt][3] + t1v[co + 3]));
    *(short4*)(y1b + pix * TCH + co) = p;
  }
}

// ---------------- cv2: bf16 MFMA GEMM 128->256 + BN + SiLU -> y2 bf16 NHWC ----------------
// grid 1600 = 4 co-chunks * 400 pix-tiles(64); 4 waves x 16 pix
__global__ __launch_bounds__(256) void k_cv2(const short* __restrict__ y1b, const short* __restrict__ w2b,
                                             const float* __restrict__ t2v, short* __restrict__ y2b)
{
  int b = blockIdx.x;
  int cc = b & 3; int pt = b >> 2;
  int co0 = cc * 64;
  int tid = threadIdx.x;
  int wave = tid >> 6, lane = tid & 63;
  int ln = lane & 15, q = lane >> 4;
  int pix = pt * 64 + wave * 16 + ln;

  f32x4 acc0 = {0.f, 0.f, 0.f, 0.f};
  f32x4 acc1 = acc0, acc2 = acc0, acc3 = acc0;

  const short* wb = w2b + (co0 + ln) * TCH + q * 8;
  const short* xb = y1b + pix * TCH + q * 8;
#pragma unroll
  for (int kk = 0; kk < TCH; kk += 32) {
    bf16x8 bfrag = *(const bf16x8*)(xb + kk);
    bf16x8 a0 = *(const bf16x8*)(wb + 0 * 16 * TCH + kk);
    bf16x8 a1 = *(const bf16x8*)(wb + 1 * 16 * TCH + kk);
    bf16x8 a2 = *(const bf16x8*)(wb + 2 * 16 * TCH + kk);
    bf16x8 a3 = *(const bf16x8*)(wb + 3 * 16 * TCH + kk);
    acc0 = __builtin_amdgcn_mfma_f32_16x16x32_bf16(a0, bfrag, acc0, 0, 0, 0);
    acc1 = __builtin_amdgcn_mfma_f32_16x16x32_bf16(a1, bfrag, acc1, 0, 0, 0);
    acc2 = __builtin_amdgcn_mfma_f32_16x16x32_bf16(a2, bfrag, acc2, 0, 0, 0);
    acc3 = __builtin_amdgcn_mfma_f32_16x16x32_bf16(a3, bfrag, acc3, 0, 0, 0);
  }

  f32x4 accs[4] = {acc0, acc1, acc2, acc3};
#pragma unroll
  for (int mt = 0; mt < 4; ++mt) {
    int co = co0 + mt * 16 + q * 4;
    short4 p;
    p.x = rnbf(siluf(accs[mt][0] + t2v[co]));
    p.y = rnbf(siluf(accs[mt][1] + t2v[co + 1]));
    p.z = rnbf(siluf(accs[mt][2] + t2v[co + 2]));
    p.w = rnbf(siluf(accs[mt][3] + t2v[co + 3]));
    *(short4*)(y2b + pix * TC2 + co) = p;
  }
}

// ---------------- input_proj: bf16 MFMA GEMM 256->256 + bias -> xproj bf16 NHWC ----------------
__global__ __launch_bounds__(256) void k_proj_in(const short* __restrict__ y2b, const short* __restrict__ inwb,
                                                 const float* __restrict__ inb, short* __restrict__ xproj)
{
  int b = blockIdx.x;
  int cc = b & 3; int pt = b >> 2;
  int co0 = cc * 64;
  int tid = threadIdx.x;
  int wave = tid >> 6, lane = tid & 63;
  int ln = lane & 15, q = lane >> 4;
  int pix = pt * 64 + wave * 16 + ln;

  f32x4 acc0 = {0.f, 0.f, 0.f, 0.f};
  f32x4 acc1 = acc0, acc2 = acc0, acc3 = acc0;

  const short* wb = inwb + (co0 + ln) * TC2 + q * 8;
  const short* xb = y2b + pix * TC2 + q * 8;
#pragma unroll
  for (int kk = 0; kk < TC2; kk += 32) {
    bf16x8 bfrag = *(const bf16x8*)(xb + kk);
    bf16x8 a0 = *(const bf16x8*)(wb + 0 * 16 * TC2 + kk);
    bf16x8 a1 = *(const bf16x8*)(wb + 1 * 16 * TC2 + kk);
    bf16x8 a2 = *(const bf16x8*)(wb + 2 * 16 * TC2 + kk);
    bf16x8 a3 = *(const bf16x8*)(wb + 3 * 16 * TC2 + kk);
    acc0 = __builtin_amdgcn_mfma_f32_16x16x32_bf16(a0, bfrag, acc0, 0, 0, 0);
    acc1 = __builtin_amdgcn_mfma_f32_16x16x32_bf16(a1, bfrag, acc1, 0, 0, 0);
    acc2 = __builtin_amdgcn_mfma_f32_16x16x32_bf16(a2, bfrag, acc2, 0, 0, 0);
    acc3 = __builtin_amdgcn_mfma_f32_16x16x32_bf16(a3, bfrag, acc3, 0, 0, 0);
  }

  f32x4 accs[4] = {acc0, acc1, acc2, acc3};
#pragma unroll
  for (int mt = 0; mt < 4; ++mt) {
    int co = co0 + mt * 16 + q * 4;
    short4 p;
    p.x = rnbf(accs[mt][0] + inb[co]);
    p.y = rnbf(accs[mt][1] + inb[co + 1]);
    p.z = rnbf(accs[mt][2] + inb[co + 2]);
    p.w = rnbf(accs[mt][3] + inb[co + 3]);
    *(short4*)(xproj + pix * TC2 + co) = p;
  }
}

// ---------------- depthwise 3x3 + bias + LayerNorm + GELU (block per pixel) ----------------
__global__ __launch_bounds__(256) void k_dwln(const short* __restrict__ y2b, const float* __restrict__ dwt,
                                              const float* __restrict__ dwb, const float* __restrict__ lng,
                                              const float* __restrict__ lnb, float* __restrict__ dwo)
{
  int pix = blockIdx.x;
  int c = threadIdx.x;
  int w = pix % TW; int h = (pix / TW) % TH; int n = pix / (TH * TW);
  float v = dwb[c];
#pragma unroll
  for (int dy = 0; dy < 3; ++dy) {
    int hh = h + dy - 1;
    if (hh < 0 || hh >= TH) continue;
#pragma unroll
    for (int dx = 0; dx < 3; ++dx) {
      int ww = w + dx - 1;
      if (ww < 0 || ww >= TW) continue;
      v += bf2f(y2b[((n * TH + hh) * TW + ww) * TC2 + c]) * dwt[(dy * 3 + dx) * TC2 + c];
    }
  }
  float sv = v, sq = v * v;
#pragma unroll
  for (int o = 32; o > 0; o >>= 1) { sv += __shfl_xor(sv, o); sq += __shfl_xor(sq, o); }
  __shared__ float red[8];
  int wid = c >> 6;
  if ((c & 63) == 0) { red[wid] = sv; red[4 + wid] = sq; }
  __syncthreads();
  float ts = red[0] + red[1] + red[2] + red[3];
  float tq = red[4] + red[5] + red[6] + red[7];
  float mu = ts * (1.f / 256.f);
  float var = tq * (1.f / 256.f) - mu * mu;
  float nv = (v - mu) / sqrtf(var + 1e-6f);
  nv = nv * lng[c] + lnb[c];
  float g = 0.5f * nv * (1.f + erff(nv * 0.70710678118654752f));
  dwo[pix * TC2 + c] = g;
}

// ---------------- offset/mask logits: raw27[pix][27] ----------------
__global__ __launch_bounds__(256) void k_offmask(const float* __restrict__ dw, const float* __restrict__ wcat,
                                                 const float* __restrict__ wcatb, float* __restrict__ raw)
{
  int g = blockIdx.x * 256 + threadIdx.x;
  if (g >= NPIX * 27) return;
  int j = g % 27, pix = g / 27;
  const float4* a = (const float4*)(dw + pix * TC2);
  const float4* wv = (const float4*)(wcat + j * TC2);
  float acc = 0.f;
#pragma unroll 4
  for (int i = 0; i < 64; ++i) {
    float4 xx = a[i], yy = wv[i];
    acc += xx.x * yy.x + xx.y * yy.y + xx.z * yy.z + xx.w * yy.w;
  }
  raw[g] = acc + wcatb[j];
}

// ---------------- DCN core: softmax(mask) + bilinear gather (block per pixel) ----------------
__device__ __forceinline__ float dcn_sample(const short* __restrict__ xb, int yi, int xi, float wt)
{
  bool valid = (xi >= 1) & (xi <= TW) & (yi >= 1) & (yi <= TH);
  int idx = valid ? (((yi - 1) * TW + (xi - 1)) * TC2) : 0;
  float wv = valid ? wt : 0.f;
  return wv * bf2f(xb[idx]);
}

__global__ __launch_bounds__(256) void k_dcn(const short* __restrict__ xproj, const float* __restrict__ raw,
                                             short* __restrict__ z)
{
  int pix = blockIdx.x;
  int c = threadIdx.x;
  int w = pix % TW; int h = (pix / TW) % TH; int n = pix / (TH * TW);
  const float* r = raw + pix * 27;
  float mx = r[18];
#pragma unroll
  for (int k = 1; k < 9; ++k) mx = fmaxf(mx, r[18 + k]);
  float e[9]; float sum = 0.f;
#pragma unroll
  for (int k = 0; k < 9; ++k) { float ee = expf(r[18 + k] - mx); e[k] = ee; sum += ee; }
  float inv = 1.f / sum;

  float acc = 0.f;
  const short* xb = xproj + n * (TH * TW * TC2) + c;
#pragma unroll
  for (int k = 0; k < 9; ++k) {
    float px = (float)(w + k / 3) + r[2 * k];
    float py = (float)(h + k % 3) + r[2 * k + 1];
    float x0f = floorf(px), y0f = floorf(py);
    float lw = px - x0f, lh = py - y0f;
    int x0 = (int)x0f, y0 = (int)y0f;
    float mk = e[k] * inv;
    float w00 = mk * (1.f - lh) * (1.f - lw);
    float w01 = mk * (1.f - lh) * lw;
    float w10 = mk * lh * (1.f - lw);
    float w11 = mk * lh * lw;
    acc += dcn_sample(xb, y0,     x0,     w00);
    acc += dcn_sample(xb, y0,     x0 + 1, w01);
    acc += dcn_sample(xb, y0 + 1, x0,     w10);
    acc += dcn_sample(xb, y0 + 1, x0 + 1, w11);
  }
  z[pix * TC2 + c] = rnbf(acc);
}

// ---------------- output_proj (MFMA) + BN + SiLU + residual -> d_out NCHW fp32 ----------------
__global__ __launch_bounds__(256) void k_proj_out(const short* __restrict__ zb, const short* __restrict__ outwb,
                                                  const float* __restrict__ t3p,
                                                  const float* __restrict__ x, float* __restrict__ out)
{
  int b = blockIdx.x;
  int cc = b & 3; int pt = b >> 2;
  int co0 = cc * 64;
  int tid = threadIdx.x;
  int wave = tid >> 6, lane = tid & 63;
  int ln = lane & 15, q = lane >> 4;
  int pix = pt * 64 + wave * 16 + ln;

  f32x4 acc0 = {0.f, 0.f, 0.f, 0.f};
  f32x4 acc1 = acc0, acc2 = acc0, acc3 = acc0;

  const short* wb = outwb + (co0 + ln) * TC2 + q * 8;
  const short* xb = zb + pix * TC2 + q * 8;
#pragma unroll
  for (int kk = 0; kk < TC2; kk += 32) {
    bf16x8 bfrag = *(const bf16x8*)(xb + kk);
    bf16x8 a0 = *(const bf16x8*)(wb + 0 * 16 * TC2 + kk);
    bf16x8 a1 = *(const bf16x8*)(wb + 1 * 16 * TC2 + kk);
    bf16x8 a2 = *(const bf16x8*)(wb + 2 * 16 * TC2 + kk);
    bf16x8 a3 = *(const bf16x8*)(wb + 3 * 16 * TC2 + kk);
    acc0 = __builtin_amdgcn_mfma_f32_16x16x32_bf16(a0, bfrag, acc0, 0, 0, 0);
    acc1 = __builtin_amdgcn_mfma_f32_16x16x32_bf16(a1, bfrag, acc1, 0, 0, 0);
    acc2 = __builtin_amdgcn_mfma_f32_16x16x32_bf16(a2, bfrag, acc2, 0, 0, 0);
    acc3 = __builtin_amdgcn_mfma_f32_16x16x32_bf16(a3, bfrag, acc3, 0, 0, 0);
  }

  int n = pix / (TH * TW);
  int pp = pix - n * (TH * TW);
  f32x4 accs[4] = {acc0, acc1, acc2, acc3};
#pragma unroll
  for (int mt = 0; mt < 4; ++mt) {
#pragma unroll
    for (int r = 0; r < 4; ++r) {
      int co = co0 + mt * 16 + q * 4 + r;
      int addr = (n * TC2 + co) * (TH * TW) + pp;
      out[addr] = x[addr] + siluf(accs[mt][r] + t3p[co]);
    }
  }
}

extern "C" void kernel_launch(void* const* d_in, const int* in_sizes, int n_in,
                              void* d_out, int out_size, void* d_ws, size_t ws_size,
                              hipStream_t stream)
{
  const float* x    = (const float*)d_in[0];
  const float* w1   = (const float*)d_in[1];
  const float* g1   = (const float*)d_in[2];
  const float* b1   = (const float*)d_in[3];
  const float* m1   = (const float*)d_in[4];
  const float* v1   = (const float*)d_in[5];
  const float* w2   = (const float*)d_in[6];
  const float* g2   = (const float*)d_in[7];
  const float* b2   = (const float*)d_in[8];
  const float* m2   = (const float*)d_in[9];
  const float* v2   = (const float*)d_in[10];
  const float* dww  = (const float*)d_in[11];
  const float* dwb  = (const float*)d_in[12];
  const float* lng  = (const float*)d_in[13];
  const float* lnb  = (const float*)d_in[14];
  const float* offw = (const float*)d_in[15];
  const float* offb = (const float*)d_in[16];
  const float* mskw = (const float*)d_in[17];
  const float* mskb = (const float*)d_in[18];
  const float* inw  = (const float*)d_in[19];
  const float* inb  = (const float*)d_in[20];
  const float* outw = (const float*)d_in[21];
  const float* outb = (const float*)d_in[22];
  const float* g3   = (const float*)d_in[23];
  const float* b3   = (const float*)d_in[24];
  const float* m3   = (const float*)d_in[25];
  const float* v3   = (const float*)d_in[26];

  float* ws  = (float*)d_ws;
  float* out = (float*)d_out;

  short* xpn   = (short*)(ws + OFF_XPAD);
  short* wbf   = (short*)(ws + OFF_WBF);
  short* w2b   = (short*)(ws + OFF_W2B);
  short* inwb  = (short*)(ws + OFF_INWB);
  short* outwb = (short*)(ws + OFF_OUTWB);
  short* y1b   = (short*)(ws + OFF_Y1);
  short* y2b   = (short*)(ws + OFF_Y2);
  float* dwo   = ws + OFF_DW;            // aliases xpad (dead after cv1)
  float* raw   = ws + OFF_RAW;           // aliases y1  (dead after cv2)
  short* zb    = (short*)(ws + OFF_Z);   // aliases y2  (dead after proj_in/dwln)
  short* xproj = (short*)d_out;          // d_out doubles as bf16 x_proj scratch

  hipLaunchKernelGGL(k_prep, dim3(1831), dim3(256), 0, stream,
                     w1, g1, b1, m1, v1, w2, g2, b2, m2, v2,
                     dww, offw, offb, mskw, mskb, inw, outw, outb, g3, b3, m3, v3, ws);
  hipLaunchKernelGGL(k_padx,     dim3(TN * THP * 8), dim3(256), 0, stream, x, xpn);
  hipLaunchKernelGGL(k_cv1,      dim3(800),   dim3(256), 0, stream, xpn, wbf, ws + OFF_T1, y1b);
  hipLaunchKernelGGL(k_cv2,      dim3(1600),  dim3(256), 0, stream, y1b, w2b, ws + OFF_T2, y2b);
  hipLaunchKernelGGL(k_proj_in,  dim3(1600),  dim3(256), 0, stream, y2b, inwb, inb, xproj);
  hipLaunchKernelGGL(k_dwln,     dim3(25600), dim3(256), 0, stream, y2b, ws + OFF_DWT, dwb, lng, lnb, dwo);
  hipLaunchKernelGGL(k_offmask,  dim3(2700),  dim3(256), 0, stream, dwo, ws + OFF_WCAT, ws + OFF_WCATB, raw);
  hipLaunchKernelGGL(k_dcn,      dim3(25600), dim3(256), 0, stream, xproj, raw, zb);
  hipLaunchKernelGGL(k_proj_out, dim3(1600),  dim3(256), 0, stream, zb, outwb, ws + OFF_T3P, x, out);
}

// Round 4
// 576.687 us; speedup vs baseline: 2.1779x; 1.1101x over previous
//
#include <hip/hip_runtime.h>
#include <cmath>

// Problem dims
#define TN 4
#define TC1 256
#define TCH 128
#define TC2 256
#define TH 80
#define TW 80
#define THP 82
#define TWP 84
#define NPIX (TN*TH*TW)   // 25600

// Workspace layout (float offsets). Total = 17,356,288 floats = 69.4 MB.
#define OFF_WBF   0         // bf16 wbf[co][tap*256+ci], s1-folded: 294912 shorts
#define OFF_W2B   294912    // bf16 [co][ci=128], s2-folded: 32768 shorts
#define OFF_INWB  327680    // bf16 [co][ci=256]: 65536 shorts
#define OFF_OUTWB 393216    // bf16 [co][ci=256], s3-folded: 65536 shorts
#define OFF_DWT   458752    // fp32 [tap][c] 2304
#define OFF_WCAT  461056    // fp32 [j<27][c] 6912
#define OFF_WCATB 467968    // 27
#define OFF_T1    468128    // 128
#define OFF_T2    468512    // 256
#define OFF_T3P   469024    // 256  (= out_b*s3 + b3 - m3*s3)
#define OFF_XPAD  469504    // bf16 NHWC padded x [4][82][84][256] shorts
#define OFF_Y1    7525888   // bf16 y1 [25600][128] shorts (region 3.27M floats)
#define OFF_Y2    10802688  // region 6,553,600 floats -> end 17,356,288
// aliases (dead-before-reuse by stream order):
#define OFF_Y1P   OFF_Y2    // fp32 cv1 partials [2][25600][128] = 6,553,600 floats (y2 not yet written)
#define OFF_DW    OFF_XPAD  // fp32 dw/LN/GELU output (xpad dead after cv1)
#define OFF_RAW   OFF_Y1    // fp32 27/pixel (y1 dead after cv2)
#define OFF_Z     OFF_Y2    // bf16 DCN output (y2 dead after proj_in/dwln)
// y2 bf16 lives at OFF_Y2 (overwrites cv1 partials, which die at y1red)

typedef __attribute__((ext_vector_type(8))) short bf16x8;
typedef __attribute__((ext_vector_type(4))) float f32x4;

__device__ __forceinline__ float siluf(float v) { return v / (1.f + expf(-v)); }
__device__ __forceinline__ short rnbf(float f) {
  unsigned u = __float_as_uint(f);
  unsigned r = (u + 0x7fffu + ((u >> 16) & 1u)) >> 16;
  return (short)r;
}
__device__ __forceinline__ float bf2f(short s) {
  return __uint_as_float(((unsigned)(unsigned short)s) << 16);
}

// ---------------- prep: weight transposes + BN constant folding ----------------
__global__ __launch_bounds__(256) void k_prep(
    const float* __restrict__ w1, const float* __restrict__ g1, const float* __restrict__ b1,
    const float* __restrict__ m1, const float* __restrict__ v1,
    const float* __restrict__ w2, const float* __restrict__ g2, const float* __restrict__ b2,
    const float* __restrict__ m2, const float* __restrict__ v2,
    const float* __restrict__ dww, const float* __restrict__ offw, const float* __restrict__ offb,
    const float* __restrict__ mskw, const float* __restrict__ mskb,
    const float* __restrict__ inw, const float* __restrict__ outw, const float* __restrict__ outb,
    const float* __restrict__ g3, const float* __restrict__ b3,
    const float* __restrict__ m3, const float* __restrict__ v3,
    float* __restrict__ ws)
{
  int i = blockIdx.x * 256 + threadIdx.x;
  if (i < 294912) {                 // wbf[co][(ky*3+kx)*256+ci] = w1[co][ci][ky][kx] * s1[co]
    int co = i / 2304; int r = i - co * 2304;
    int tap = r >> 8; int ci = r & 255; int ky = tap / 3; int kx = tap - ky * 3;
    float s = g1[co] * __frsqrt_rn(v1[co] + 1e-5f);
    ((short*)(ws + OFF_WBF))[i] = rnbf(w1[((co * TC1 + ci) * 3 + ky) * 3 + kx] * s);
    return;
  }
  i -= 294912;
  if (i < 32768) {                  // w2b[co][ci] = w2[co][ci] * s2[co]
    int co = i >> 7; int ci = i & 127;
    float s = g2[co] * __frsqrt_rn(v2[co] + 1e-5f);
    ((short*)(ws + OFF_W2B))[i] = rnbf(w2[co * TCH + ci] * s);
    return;
  }
  i -= 32768;
  if (i < 65536) {                  // inwb[co][ci]
    int co = i >> 8; int ci = i & 255;
    ((short*)(ws + OFF_INWB))[i] = rnbf(inw[co * TC2 + ci]);
    return;
  }
  i -= 65536;
  if (i < 65536) {                  // outwb[co][ci] = outw[co][ci] * s3[co]
    int co = i >> 8; int ci = i & 255;
    float s = g3[co] * __frsqrt_rn(v3[co] + 1e-5f);
    ((short*)(ws + OFF_OUTWB))[i] = rnbf(outw[co * TC2 + ci] * s);
    return;
  }
  i -= 65536;
  if (i < 2304) { int c = i & 255; int j = i >> 8; ws[OFF_DWT + i] = dww[c * 9 + j]; return; }
  i -= 2304;
  if (i < 6912) {
    int c = i & 255; int j = i >> 8;
    ws[OFF_WCAT + i] = (j < 18) ? offw[j * 256 + c] : mskw[(j - 18) * 256 + c];
    return;
  }
  i -= 6912;
  if (i < 27) { ws[OFF_WCATB + i] = (i < 18) ? offb[i] : mskb[i - 18]; return; }
  i -= 27;
  if (i < 128) { float s = g1[i] / sqrtf(v1[i] + 1e-5f); ws[OFF_T1 + i] = b1[i] - m1[i] * s; return; }
  i -= 128;
  if (i < 256) { float s = g2[i] / sqrtf(v2[i] + 1e-5f); ws[OFF_T2 + i] = b2[i] - m2[i] * s; return; }
  i -= 256;
  if (i < 256) { float s = g3[i] / sqrtf(v3[i] + 1e-5f); ws[OFF_T3P + i] = outb[i] * s + b3[i] - m3[i] * s; return; }
}

// ---------------- x -> bf16 NHWC padded [4][82][84][256], zero halo ----------------
__global__ __launch_bounds__(256) void k_padx(const float* __restrict__ x, short* __restrict__ xpn)
{
  __shared__ short lds[80 * 33];
  int b = blockIdx.x;
  int cc = b & 7; int hp = (b >> 3) % THP; int n = b / (THP * 8);
  int c0 = cc * 32;
  int t = threadIdx.x;
  int h = hp - 1;
  if (h >= 0 && h < TH) {
    for (int f = t; f < 80 * 32; f += 256) {
      int ci = f / 80; int w = f - ci * 80;
      lds[w * 33 + ci] = rnbf(x[((n * TC1 + c0 + ci) * TH + h) * TW + w]);
    }
  }
  __syncthreads();
  bool hv = (h >= 0 && h < TH);
  short* op = xpn + ((n * THP + hp) * TWP) * TC2 + c0;
  for (int g = t; g < TWP * 32; g += 256) {
    int ci = g & 31; int wp = g >> 5;
    short v = 0;
    if (hv && wp >= 1 && wp <= TW) v = lds[(wp - 1) * 33 + ci];
    op[wp * TC2 + ci] = v;
  }
}

// ---------------- cv1: bf16 MFMA implicit-GEMM, K-split x2, fp32 partials ----------------
// grid 800 = 5wt * 10ht(8 rows) * 4n * 2ch * 2ks; wave = 2 rows x 16 px, 64 co, 8 accs
__global__ __launch_bounds__(256) void k_cv1(const short* __restrict__ xpn, const short* __restrict__ wbf,
                                             float* __restrict__ y1p)
{
  int b = blockIdx.x;
  int wt = b % 5; b /= 5; int ht = b % 10; b /= 10; int n = b & 3; b >>= 2;
  int ch = b & 1; int ks = b >> 1;
  int co0 = ch * 64, w0 = wt * 16;
  int tid = threadIdx.x;
  int wave = tid >> 6, lane = tid & 63;
  int ln = lane & 15, q = lane >> 4;
  int row0 = ht * 8 + wave * 2;
  int tap0 = ks ? 4 : 0, tap1 = ks ? 9 : 4;

  f32x4 acc[4][2];
#pragma unroll
  for (int mt = 0; mt < 4; ++mt)
#pragma unroll
    for (int pp = 0; pp < 2; ++pp) acc[mt][pp] = (f32x4){0.f, 0.f, 0.f, 0.f};

  const short* wb = wbf + (co0 + ln) * 2304 + q * 8;

  for (int tap = tap0; tap < tap1; ++tap) {
    int ky = tap / 3, kx = tap - ky * 3;
    const short* xb0 = xpn + (((n * THP + row0 + ky) * TWP) + (w0 + ln + kx)) * TC2 + q * 8;
    const short* xb1 = xb0 + TWP * TC2;
    const short* wtp = wb + tap * 256;

    bf16x8 c0f = *(const bf16x8*)(xb0);
    bf16x8 c1f = *(const bf16x8*)(xb1);
    bf16x8 c2f = *(const bf16x8*)(wtp + 0 * 16 * 2304);
    bf16x8 c3f = *(const bf16x8*)(wtp + 1 * 16 * 2304);
    bf16x8 c4f = *(const bf16x8*)(wtp + 2 * 16 * 2304);
    bf16x8 c5f = *(const bf16x8*)(wtp + 3 * 16 * 2304);

#pragma unroll
    for (int kk = 0; kk < 256; kk += 32) {
      bf16x8 n0f, n1f, n2f, n3f, n4f, n5f;
      const bool more = (kk + 32 < 256);
      if (more) {
        n0f = *(const bf16x8*)(xb0 + kk + 32);
        n1f = *(const bf16x8*)(xb1 + kk + 32);
        n2f = *(const bf16x8*)(wtp + 0 * 16 * 2304 + kk + 32);
        n3f = *(const bf16x8*)(wtp + 1 * 16 * 2304 + kk + 32);
        n4f = *(const bf16x8*)(wtp + 2 * 16 * 2304 + kk + 32);
        n5f = *(const bf16x8*)(wtp + 3 * 16 * 2304 + kk + 32);
      }
      acc[0][0] = __builtin_amdgcn_mfma_f32_16x16x32_bf16(c2f, c0f, acc[0][0], 0, 0, 0);
      acc[0][1] = __builtin_amdgcn_mfma_f32_16x16x32_bf16(c2f, c1f, acc[0][1], 0, 0, 0);
      acc[1][0] = __builtin_amdgcn_mfma_f32_16x16x32_bf16(c3f, c0f, acc[1][0], 0, 0, 0);
      acc[1][1] = __builtin_amdgcn_mfma_f32_16x16x32_bf16(c3f, c1f, acc[1][1], 0, 0, 0);
      acc[2][0] = __builtin_amdgcn_mfma_f32_16x16x32_bf16(c4f, c0f, acc[2][0], 0, 0, 0);
      acc[2][1] = __builtin_amdgcn_mfma_f32_16x16x32_bf16(c4f, c1f, acc[2][1], 0, 0, 0);
      acc[3][0] = __builtin_amdgcn_mfma_f32_16x16x32_bf16(c5f, c0f, acc[3][0], 0, 0, 0);
      acc[3][1] = __builtin_amdgcn_mfma_f32_16x16x32_bf16(c5f, c1f, acc[3][1], 0, 0, 0);
      if (more) { c0f = n0f; c1f = n1f; c2f = n2f; c3f = n3f; c4f = n4f; c5f = n5f; }
    }
  }

  int pix0 = (n * TH + row0) * TW + (w0 + ln);
  float* yp = y1p + ks * (NPIX * TCH);
#pragma unroll
  for (int mt = 0; mt < 4; ++mt)
#pragma unroll
    for (int pp = 0; pp < 2; ++pp)
      *(f32x4*)(yp + (pix0 + pp * TW) * TCH + co0 + mt * 16 + q * 4) = acc[mt][pp];
}

// ---------------- y1 reduce: silu(pa+pb+t1) -> bf16 NHWC ----------------
__global__ __launch_bounds__(256) void k_y1red(const float* __restrict__ y1p, const float* __restrict__ t1v,
                                               short* __restrict__ y1b)
{
  int i = blockIdx.x * 256 + threadIdx.x;   // 819200 = 25600*128/4
  int co4 = (i & 31) * 4;
  int pix = i >> 5;
  float4 a = *(const float4*)(y1p + pix * TCH + co4);
  float4 bq = *(const float4*)(y1p + NPIX * TCH + pix * TCH + co4);
  float4 t = *(const float4*)(t1v + co4);
  short4 o;
  o.x = rnbf(siluf(a.x + bq.x + t.x));
  o.y = rnbf(siluf(a.y + bq.y + t.y));
  o.z = rnbf(siluf(a.z + bq.z + t.z));
  o.w = rnbf(siluf(a.w + bq.w + t.w));
  *(short4*)(y1b + pix * TCH + co4) = o;
}

// ---------------- cv2: bf16 MFMA GEMM 128->256 + BN + SiLU -> y2 bf16 NHWC ----------------
// grid 800: block = 256 co (4 waves) x 32 px; wave = 64 co x 32 px
__global__ __launch_bounds__(256) void k_cv2(const short* __restrict__ y1b, const short* __restrict__ w2b,
                                             const float* __restrict__ t2v, short* __restrict__ y2b)
{
  int px0 = blockIdx.x * 32;
  int tid = threadIdx.x;
  int wave = tid >> 6, lane = tid & 63;
  int ln = lane & 15, q = lane >> 4;
  int co0 = wave * 64;
  int pix0 = px0 + ln;

  f32x4 acc[4][2];
#pragma unroll
  for (int mt = 0; mt < 4; ++mt)
#pragma unroll
    for (int pp = 0; pp < 2; ++pp) acc[mt][pp] = (f32x4){0.f, 0.f, 0.f, 0.f};

  const short* xb0 = y1b + pix0 * TCH + q * 8;
  const short* xb1 = xb0 + 16 * TCH;
  const short* wb = w2b + (co0 + ln) * TCH + q * 8;

  bf16x8 c0f = *(const bf16x8*)(xb0);
  bf16x8 c1f = *(const bf16x8*)(xb1);
  bf16x8 c2f = *(const bf16x8*)(wb + 0 * 16 * TCH);
  bf16x8 c3f = *(const bf16x8*)(wb + 1 * 16 * TCH);
  bf16x8 c4f = *(const bf16x8*)(wb + 2 * 16 * TCH);
  bf16x8 c5f = *(const bf16x8*)(wb + 3 * 16 * TCH);

#pragma unroll
  for (int kk = 0; kk < TCH; kk += 32) {
    bf16x8 n0f, n1f, n2f, n3f, n4f, n5f;
    const bool more = (kk + 32 < TCH);
    if (more) {
      n0f = *(const bf16x8*)(xb0 + kk + 32);
      n1f = *(const bf16x8*)(xb1 + kk + 32);
      n2f = *(const bf16x8*)(wb + 0 * 16 * TCH + kk + 32);
      n3f = *(const bf16x8*)(wb + 1 * 16 * TCH + kk + 32);
      n4f = *(const bf16x8*)(wb + 2 * 16 * TCH + kk + 32);
      n5f = *(const bf16x8*)(wb + 3 * 16 * TCH + kk + 32);
    }
    acc[0][0] = __builtin_amdgcn_mfma_f32_16x16x32_bf16(c2f, c0f, acc[0][0], 0, 0, 0);
    acc[0][1] = __builtin_amdgcn_mfma_f32_16x16x32_bf16(c2f, c1f, acc[0][1], 0, 0, 0);
    acc[1][0] = __builtin_amdgcn_mfma_f32_16x16x32_bf16(c3f, c0f, acc[1][0], 0, 0, 0);
    acc[1][1] = __builtin_amdgcn_mfma_f32_16x16x32_bf16(c3f, c1f, acc[1][1], 0, 0, 0);
    acc[2][0] = __builtin_amdgcn_mfma_f32_16x16x32_bf16(c4f, c0f, acc[2][0], 0, 0, 0);
    acc[2][1] = __builtin_amdgcn_mfma_f32_16x16x32_bf16(c4f, c1f, acc[2][1], 0, 0, 0);
    acc[3][0] = __builtin_amdgcn_mfma_f32_16x16x32_bf16(c5f, c0f, acc[3][0], 0, 0, 0);
    acc[3][1] = __builtin_amdgcn_mfma_f32_16x16x32_bf16(c5f, c1f, acc[3][1], 0, 0, 0);
    if (more) { c0f = n0f; c1f = n1f; c2f = n2f; c3f = n3f; c4f = n4f; c5f = n5f; }
  }

#pragma unroll
  for (int mt = 0; mt < 4; ++mt) {
    int co = co0 + mt * 16 + q * 4;
#pragma unroll
    for (int pp = 0; pp < 2; ++pp) {
      short4 p;
      p.x = rnbf(siluf(acc[mt][pp][0] + t2v[co]));
      p.y = rnbf(siluf(acc[mt][pp][1] + t2v[co + 1]));
      p.z = rnbf(siluf(acc[mt][pp][2] + t2v[co + 2]));
      p.w = rnbf(siluf(acc[mt][pp][3] + t2v[co + 3]));
      *(short4*)(y2b + (pix0 + pp * 16) * TC2 + co) = p;
    }
  }
}

// ---------------- input_proj: bf16 MFMA GEMM 256->256 + bias -> xproj bf16 NHWC ----------------
__global__ __launch_bounds__(256) void k_proj_in(const short* __restrict__ y2b, const short* __restrict__ inwb,
                                                 const float* __restrict__ inb, short* __restrict__ xproj)
{
  int px0 = blockIdx.x * 32;
  int tid = threadIdx.x;
  int wave = tid >> 6, lane = tid & 63;
  int ln = lane & 15, q = lane >> 4;
  int co0 = wave * 64;
  int pix0 = px0 + ln;

  f32x4 acc[4][2];
#pragma unroll
  for (int mt = 0; mt < 4; ++mt)
#pragma unroll
    for (int pp = 0; pp < 2; ++pp) acc[mt][pp] = (f32x4){0.f, 0.f, 0.f, 0.f};

  const short* xb0 = y2b + pix0 * TC2 + q * 8;
  const short* xb1 = xb0 + 16 * TC2;
  const short* wb = inwb + (co0 + ln) * TC2 + q * 8;

  bf16x8 c0f = *(const bf16x8*)(xb0);
  bf16x8 c1f = *(const bf16x8*)(xb1);
  bf16x8 c2f = *(const bf16x8*)(wb + 0 * 16 * TC2);
  bf16x8 c3f = *(const bf16x8*)(wb + 1 * 16 * TC2);
  bf16x8 c4f = *(const bf16x8*)(wb + 2 * 16 * TC2);
  bf16x8 c5f = *(const bf16x8*)(wb + 3 * 16 * TC2);

#pragma unroll
  for (int kk = 0; kk < TC2; kk += 32) {
    bf16x8 n0f, n1f, n2f, n3f, n4f, n5f;
    const bool more = (kk + 32 < TC2);
    if (more) {
      n0f = *(const bf16x8*)(xb0 + kk + 32);
      n1f = *(const bf16x8*)(xb1 + kk + 32);
      n2f = *(const bf16x8*)(wb + 0 * 16 * TC2 + kk + 32);
      n3f = *(const bf16x8*)(wb + 1 * 16 * TC2 + kk + 32);
      n4f = *(const bf16x8*)(wb + 2 * 16 * TC2 + kk + 32);
      n5f = *(const bf16x8*)(wb + 3 * 16 * TC2 + kk + 32);
    }
    acc[0][0] = __builtin_amdgcn_mfma_f32_16x16x32_bf16(c2f, c0f, acc[0][0], 0, 0, 0);
    acc[0][1] = __builtin_amdgcn_mfma_f32_16x16x32_bf16(c2f, c1f, acc[0][1], 0, 0, 0);
    acc[1][0] = __builtin_amdgcn_mfma_f32_16x16x32_bf16(c3f, c0f, acc[1][0], 0, 0, 0);
    acc[1][1] = __builtin_amdgcn_mfma_f32_16x16x32_bf16(c3f, c1f, acc[1][1], 0, 0, 0);
    acc[2][0] = __builtin_amdgcn_mfma_f32_16x16x32_bf16(c4f, c0f, acc[2][0], 0, 0, 0);
    acc[2][1] = __builtin_amdgcn_mfma_f32_16x16x32_bf16(c4f, c1f, acc[2][1], 0, 0, 0);
    acc[3][0] = __builtin_amdgcn_mfma_f32_16x16x32_bf16(c5f, c0f, acc[3][0], 0, 0, 0);
    acc[3][1] = __builtin_amdgcn_mfma_f32_16x16x32_bf16(c5f, c1f, acc[3][1], 0, 0, 0);
    if (more) { c0f = n0f; c1f = n1f; c2f = n2f; c3f = n3f; c4f = n4f; c5f = n5f; }
  }

#pragma unroll
  for (int mt = 0; mt < 4; ++mt) {
    int co = co0 + mt * 16 + q * 4;
#pragma unroll
    for (int pp = 0; pp < 2; ++pp) {
      short4 p;
      p.x = rnbf(acc[mt][pp][0] + inb[co]);
      p.y = rnbf(acc[mt][pp][1] + inb[co + 1]);
      p.z = rnbf(acc[mt][pp][2] + inb[co + 2]);
      p.w = rnbf(acc[mt][pp][3] + inb[co + 3]);
      *(short4*)(xproj + (pix0 + pp * 16) * TC2 + co) = p;
    }
  }
}

// ---------------- depthwise 3x3 + bias + LayerNorm + GELU (block per pixel) ----------------
__global__ __launch_bounds__(256) void k_dwln(const short* __restrict__ y2b, const float* __restrict__ dwt,
                                              const float* __restrict__ dwb, const float* __restrict__ lng,
                                              const float* __restrict__ lnb, float* __restrict__ dwo)
{
  int pix = blockIdx.x;
  int c = threadIdx.x;
  int w = pix % TW; int h = (pix / TW) % TH; int n = pix / (TH * TW);
  float v = dwb[c];
#pragma unroll
  for (int dy = 0; dy < 3; ++dy) {
    int hh = h + dy - 1;
    if (hh < 0 || hh >= TH) continue;
#pragma unroll
    for (int dx = 0; dx < 3; ++dx) {
      int ww = w + dx - 1;
      if (ww < 0 || ww >= TW) continue;
      v += bf2f(y2b[((n * TH + hh) * TW + ww) * TC2 + c]) * dwt[(dy * 3 + dx) * TC2 + c];
    }
  }
  float sv = v, sq = v * v;
#pragma unroll
  for (int o = 32; o > 0; o >>= 1) { sv += __shfl_xor(sv, o); sq += __shfl_xor(sq, o); }
  __shared__ float red[8];
  int wid = c >> 6;
  if ((c & 63) == 0) { red[wid] = sv; red[4 + wid] = sq; }
  __syncthreads();
  float ts = red[0] + red[1] + red[2] + red[3];
  float tq = red[4] + red[5] + red[6] + red[7];
  float mu = ts * (1.f / 256.f);
  float var = tq * (1.f / 256.f) - mu * mu;
  float nv = (v - mu) / sqrtf(var + 1e-6f);
  nv = nv * lng[c] + lnb[c];
  float g = 0.5f * nv * (1.f + erff(nv * 0.70710678118654752f));
  dwo[pix * TC2 + c] = g;
}

// ---------------- offset/mask logits: raw27[pix][27] ----------------
__global__ __launch_bounds__(256) void k_offmask(const float* __restrict__ dw, const float* __restrict__ wcat,
                                                 const float* __restrict__ wcatb, float* __restrict__ raw)
{
  int g = blockIdx.x * 256 + threadIdx.x;
  if (g >= NPIX * 27) return;
  int j = g % 27, pix = g / 27;
  const float4* a = (const float4*)(dw + pix * TC2);
  const float4* wv = (const float4*)(wcat + j * TC2);
  float acc = 0.f;
#pragma unroll 4
  for (int i = 0; i < 64; ++i) {
    float4 xx = a[i], yy = wv[i];
    acc += xx.x * yy.x + xx.y * yy.y + xx.z * yy.z + xx.w * yy.w;
  }
  raw[g] = acc + wcatb[j];
}

// ---------------- DCN core: softmax(mask) + bilinear gather (block per pixel) ----------------
__device__ __forceinline__ float dcn_sample(const short* __restrict__ xb, int yi, int xi, float wt)
{
  bool valid = (xi >= 1) & (xi <= TW) & (yi >= 1) & (yi <= TH);
  int idx = valid ? (((yi - 1) * TW + (xi - 1)) * TC2) : 0;
  float wv = valid ? wt : 0.f;
  return wv * bf2f(xb[idx]);
}

__global__ __launch_bounds__(256) void k_dcn(const short* __restrict__ xproj, const float* __restrict__ raw,
                                             short* __restrict__ z)
{
  int pix = blockIdx.x;
  int c = threadIdx.x;
  int w = pix % TW; int h = (pix / TW) % TH; int n = pix / (TH * TW);
  const float* r = raw + pix * 27;
  float mx = r[18];
#pragma unroll
  for (int k = 1; k < 9; ++k) mx = fmaxf(mx, r[18 + k]);
  float e[9]; float sum = 0.f;
#pragma unroll
  for (int k = 0; k < 9; ++k) { float ee = expf(r[18 + k] - mx); e[k] = ee; sum += ee; }
  float inv = 1.f / sum;

  float acc = 0.f;
  const short* xb = xproj + n * (TH * TW * TC2) + c;
#pragma unroll
  for (int k = 0; k < 9; ++k) {
    float px = (float)(w + k / 3) + r[2 * k];
    float py = (float)(h + k % 3) + r[2 * k + 1];
    float x0f = floorf(px), y0f = floorf(py);
    float lw = px - x0f, lh = py - y0f;
    int x0 = (int)x0f, y0 = (int)y0f;
    float mk = e[k] * inv;
    float w00 = mk * (1.f - lh) * (1.f - lw);
    float w01 = mk * (1.f - lh) * lw;
    float w10 = mk * lh * (1.f - lw);
    float w11 = mk * lh * lw;
    acc += dcn_sample(xb, y0,     x0,     w00);
    acc += dcn_sample(xb, y0,     x0 + 1, w01);
    acc += dcn_sample(xb, y0 + 1, x0,     w10);
    acc += dcn_sample(xb, y0 + 1, x0 + 1, w11);
  }
  z[pix * TC2 + c] = rnbf(acc);
}

// ---------------- output_proj (MFMA) + BN + SiLU + residual -> d_out NCHW fp32 ----------------
__global__ __launch_bounds__(256) void k_proj_out(const short* __restrict__ zb, const short* __restrict__ outwb,
                                                  const float* __restrict__ t3p,
                                                  const float* __restrict__ x, float* __restrict__ out)
{
  int px0 = blockIdx.x * 32;
  int tid = threadIdx.x;
  int wave = tid >> 6, lane = tid & 63;
  int ln = lane & 15, q = lane >> 4;
  int co0 = wave * 64;
  int pix0 = px0 + ln;

  f32x4 acc[4][2];
#pragma unroll
  for (int mt = 0; mt < 4; ++mt)
#pragma unroll
    for (int pp = 0; pp < 2; ++pp) acc[mt][pp] = (f32x4){0.f, 0.f, 0.f, 0.f};

  const short* xb0 = zb + pix0 * TC2 + q * 8;
  const short* xb1 = xb0 + 16 * TC2;
  const short* wb = outwb + (co0 + ln) * TC2 + q * 8;

  bf16x8 c0f = *(const bf16x8*)(xb0);
  bf16x8 c1f = *(const bf16x8*)(xb1);
  bf16x8 c2f = *(const bf16x8*)(wb + 0 * 16 * TC2);
  bf16x8 c3f = *(const bf16x8*)(wb + 1 * 16 * TC2);
  bf16x8 c4f = *(const bf16x8*)(wb + 2 * 16 * TC2);
  bf16x8 c5f = *(const bf16x8*)(wb + 3 * 16 * TC2);

#pragma unroll
  for (int kk = 0; kk < TC2; kk += 32) {
    bf16x8 n0f, n1f, n2f, n3f, n4f, n5f;
    const bool more = (kk + 32 < TC2);
    if (more) {
      n0f = *(const bf16x8*)(xb0 + kk + 32);
      n1f = *(const bf16x8*)(xb1 + kk + 32);
      n2f = *(const bf16x8*)(wb + 0 * 16 * TC2 + kk + 32);
      n3f = *(const bf16x8*)(wb + 1 * 16 * TC2 + kk + 32);
      n4f = *(const bf16x8*)(wb + 2 * 16 * TC2 + kk + 32);
      n5f = *(const bf16x8*)(wb + 3 * 16 * TC2 + kk + 32);
    }
    acc[0][0] = __builtin_amdgcn_mfma_f32_16x16x32_bf16(c2f, c0f, acc[0][0], 0, 0, 0);
    acc[0][1] = __builtin_amdgcn_mfma_f32_16x16x32_bf16(c2f, c1f, acc[0][1], 0, 0, 0);
    acc[1][0] = __builtin_amdgcn_mfma_f32_16x16x32_bf16(c3f, c0f, acc[1][0], 0, 0, 0);
    acc[1][1] = __builtin_amdgcn_mfma_f32_16x16x32_bf16(c3f, c1f, acc[1][1], 0, 0, 0);
    acc[2][0] = __builtin_amdgcn_mfma_f32_16x16x32_bf16(c4f, c0f, acc[2][0], 0, 0, 0);
    acc[2][1] = __builtin_amdgcn_mfma_f32_16x16x32_bf16(c4f, c1f, acc[2][1], 0, 0, 0);
    acc[3][0] = __builtin_amdgcn_mfma_f32_16x16x32_bf16(c5f, c0f, acc[3][0], 0, 0, 0);
    acc[3][1] = __builtin_amdgcn_mfma_f32_16x16x32_bf16(c5f, c1f, acc[3][1], 0, 0, 0);
    if (more) { c0f = n0f; c1f = n1f; c2f = n2f; c3f = n3f; c4f = n4f; c5f = n5f; }
  }

#pragma unroll
  for (int mt = 0; mt < 4; ++mt) {
#pragma unroll
    for (int pp = 0; pp < 2; ++pp) {
      int pix = pix0 + pp * 16;
      int n = pix / (TH * TW);
      int hw = pix - n * (TH * TW);
#pragma unroll
      for (int r = 0; r < 4; ++r) {
        int co = co0 + mt * 16 + q * 4 + r;
        int addr = (n * TC2 + co) * (TH * TW) + hw;
        out[addr] = x[addr] + siluf(acc[mt][pp][r] + t3p[co]);
      }
    }
  }
}

extern "C" void kernel_launch(void* const* d_in, const int* in_sizes, int n_in,
                              void* d_out, int out_size, void* d_ws, size_t ws_size,
                              hipStream_t stream)
{
  const float* x    = (const float*)d_in[0];
  const float* w1   = (const float*)d_in[1];
  const float* g1   = (const float*)d_in[2];
  const float* b1   = (const float*)d_in[3];
  const float* m1   = (const float*)d_in[4];
  const float* v1   = (const float*)d_in[5];
  const float* w2   = (const float*)d_in[6];
  const float* g2   = (const float*)d_in[7];
  const float* b2   = (const float*)d_in[8];
  const float* m2   = (const float*)d_in[9];
  const float* v2   = (const float*)d_in[10];
  const float* dww  = (const float*)d_in[11];
  const float* dwb  = (const float*)d_in[12];
  const float* lng  = (const float*)d_in[13];
  const float* lnb  = (const float*)d_in[14];
  const float* offw = (const float*)d_in[15];
  const float* offb = (const float*)d_in[16];
  const float* mskw = (const float*)d_in[17];
  const float* mskb = (const float*)d_in[18];
  const float* inw  = (const float*)d_in[19];
  const float* inb  = (const float*)d_in[20];
  const float* outw = (const float*)d_in[21];
  const float* outb = (const float*)d_in[22];
  const float* g3   = (const float*)d_in[23];
  const float* b3   = (const float*)d_in[24];
  const float* m3   = (const float*)d_in[25];
  const float* v3   = (const float*)d_in[26];

  float* ws  = (float*)d_ws;
  float* out = (float*)d_out;

  short* xpn   = (short*)(ws + OFF_XPAD);
  short* wbf   = (short*)(ws + OFF_WBF);
  short* w2b   = (short*)(ws + OFF_W2B);
  short* inwb  = (short*)(ws + OFF_INWB);
  short* outwb = (short*)(ws + OFF_OUTWB);
  float* y1p   = ws + OFF_Y1P;           // fp32 partials (aliases y2 region, dead before cv2)
  short* y1b   = (short*)(ws + OFF_Y1);
  short* y2b   = (short*)(ws + OFF_Y2);  // overwrites y1p after y1red
  float* dwo   = ws + OFF_DW;            // aliases xpad (dead after cv1)
  float* raw   = ws + OFF_RAW;           // aliases y1  (dead after cv2)
  short* zb    = (short*)(ws + OFF_Z);   // aliases y2  (dead after proj_in/dwln)
  short* xproj = (short*)d_out;          // d_out doubles as bf16 x_proj scratch

  hipLaunchKernelGGL(k_prep, dim3(1831), dim3(256), 0, stream,
                     w1, g1, b1, m1, v1, w2, g2, b2, m2, v2,
                     dww, offw, offb, mskw, mskb, inw, outw, outb, g3, b3, m3, v3, ws);
  hipLaunchKernelGGL(k_padx,     dim3(TN * THP * 8), dim3(256), 0, stream, x, xpn);
  hipLaunchKernelGGL(k_cv1,      dim3(800),   dim3(256), 0, stream, xpn, wbf, y1p);
  hipLaunchKernelGGL(k_y1red,    dim3(3200),  dim3(256), 0, stream, y1p, ws + OFF_T1, y1b);
  hipLaunchKernelGGL(k_cv2,      dim3(800),   dim3(256), 0, stream, y1b, w2b, ws + OFF_T2, y2b);
  hipLaunchKernelGGL(k_proj_in,  dim3(800),   dim3(256), 0, stream, y2b, inwb, inb, xproj);
  hipLaunchKernelGGL(k_dwln,     dim3(25600), dim3(256), 0, stream, y2b, ws + OFF_DWT, dwb, lng, lnb, dwo);
  hipLaunchKernelGGL(k_offmask,  dim3(2700),  dim3(256), 0, stream, dwo, ws + OFF_WCAT, ws + OFF_WCATB, raw);
  hipLaunchKernelGGL(k_dcn,      dim3(25600), dim3(256), 0, stream, xproj, raw, zb);
  hipLaunchKernelGGL(k_proj_out, dim3(800),   dim3(256), 0, stream, zb, outwb, ws + OFF_T3P, x, out);
}

// Round 5
// 489.622 us; speedup vs baseline: 2.5652x; 1.1778x over previous
//
#include <hip/hip_runtime.h>
#include <cmath>

// Problem dims
#define TN 4
#define TC1 256
#define TCH 128
#define TC2 256
#define TH 80
#define TW 80
#define THP 82
#define TWP 84
#define NPIX (TN*TH*TW)   // 25600

// Workspace layout (float offsets). Total = 17,356,288 floats = 69.4 MB.
#define OFF_WBF   0         // bf16 wbf[co][tap*256+ci], s1-folded: 294912 shorts
#define OFF_W2B   294912    // bf16 [co][ci=128], s2-folded: 32768 shorts
#define OFF_INWB  327680    // bf16 [co][ci=256]: 65536 shorts
#define OFF_OUTWB 393216    // bf16 [co][ci=256], s3-folded: 65536 shorts
#define OFF_DWT   458752    // fp32 [tap][c] 2304
#define OFF_WCAT  461056    // fp32 [j<27][c] 6912
#define OFF_WCATB 467968    // 27
#define OFF_T1    468128    // 128
#define OFF_T2    468512    // 256
#define OFF_T3P   469024    // 256  (= out_b*s3 + b3 - m3*s3)
#define OFF_XPAD  469504    // bf16 NHWC padded x [4][82][84][256] shorts
#define OFF_Y1    7525888   // bf16 y1 [25600][128] shorts (region 3.27M floats)
#define OFF_Y2    10802688  // region 6,553,600 floats -> end 17,356,288
// aliases (dead-before-reuse by stream order):
#define OFF_Y1P   OFF_Y2    // fp32 cv1 partials [2][25600][128] (y2 not yet written)
#define OFF_DW    OFF_XPAD  // fp32 dw/LN/GELU output (xpad dead after cv1)
#define OFF_RAW   OFF_Y1    // fp32 27/pixel (y1 dead after cv2)
#define OFF_Z     OFF_Y2    // bf16 DCN output (y2 dead after proj_in/dwln)

typedef __attribute__((ext_vector_type(8))) short bf16x8;
typedef __attribute__((ext_vector_type(4))) float f32x4;

__device__ __forceinline__ float siluf(float v) { return v / (1.f + expf(-v)); }
__device__ __forceinline__ short rnbf(float f) {
  unsigned u = __float_as_uint(f);
  unsigned r = (u + 0x7fffu + ((u >> 16) & 1u)) >> 16;
  return (short)r;
}
__device__ __forceinline__ float bf2f(short s) {
  return __uint_as_float(((unsigned)(unsigned short)s) << 16);
}

// ---------------- prep: weight transposes + BN constant folding ----------------
__global__ __launch_bounds__(256) void k_prep(
    const float* __restrict__ w1, const float* __restrict__ g1, const float* __restrict__ b1,
    const float* __restrict__ m1, const float* __restrict__ v1,
    const float* __restrict__ w2, const float* __restrict__ g2, const float* __restrict__ b2,
    const float* __restrict__ m2, const float* __restrict__ v2,
    const float* __restrict__ dww, const float* __restrict__ offw, const float* __restrict__ offb,
    const float* __restrict__ mskw, const float* __restrict__ mskb,
    const float* __restrict__ inw, const float* __restrict__ outw, const float* __restrict__ outb,
    const float* __restrict__ g3, const float* __restrict__ b3,
    const float* __restrict__ m3, const float* __restrict__ v3,
    float* __restrict__ ws)
{
  int i = blockIdx.x * 256 + threadIdx.x;
  if (i < 294912) {                 // wbf[co][(ky*3+kx)*256+ci] = w1[co][ci][ky][kx] * s1[co]
    int co = i / 2304; int r = i - co * 2304;
    int tap = r >> 8; int ci = r & 255; int ky = tap / 3; int kx = tap - ky * 3;
    float s = g1[co] * __frsqrt_rn(v1[co] + 1e-5f);
    ((short*)(ws + OFF_WBF))[i] = rnbf(w1[((co * TC1 + ci) * 3 + ky) * 3 + kx] * s);
    return;
  }
  i -= 294912;
  if (i < 32768) {                  // w2b[co][ci] = w2[co][ci] * s2[co]
    int co = i >> 7; int ci = i & 127;
    float s = g2[co] * __frsqrt_rn(v2[co] + 1e-5f);
    ((short*)(ws + OFF_W2B))[i] = rnbf(w2[co * TCH + ci] * s);
    return;
  }
  i -= 32768;
  if (i < 65536) {                  // inwb[co][ci]
    int co = i >> 8; int ci = i & 255;
    ((short*)(ws + OFF_INWB))[i] = rnbf(inw[co * TC2 + ci]);
    return;
  }
  i -= 65536;
  if (i < 65536) {                  // outwb[co][ci] = outw[co][ci] * s3[co]
    int co = i >> 8; int ci = i & 255;
    float s = g3[co] * __frsqrt_rn(v3[co] + 1e-5f);
    ((short*)(ws + OFF_OUTWB))[i] = rnbf(outw[co * TC2 + ci] * s);
    return;
  }
  i -= 65536;
  if (i < 2304) { int c = i & 255; int j = i >> 8; ws[OFF_DWT + i] = dww[c * 9 + j]; return; }
  i -= 2304;
  if (i < 6912) {
    int c = i & 255; int j = i >> 8;
    ws[OFF_WCAT + i] = (j < 18) ? offw[j * 256 + c] : mskw[(j - 18) * 256 + c];
    return;
  }
  i -= 6912;
  if (i < 27) { ws[OFF_WCATB + i] = (i < 18) ? offb[i] : mskb[i - 18]; return; }
  i -= 27;
  if (i < 128) { float s = g1[i] / sqrtf(v1[i] + 1e-5f); ws[OFF_T1 + i] = b1[i] - m1[i] * s; return; }
  i -= 128;
  if (i < 256) { float s = g2[i] / sqrtf(v2[i] + 1e-5f); ws[OFF_T2 + i] = b2[i] - m2[i] * s; return; }
  i -= 256;
  if (i < 256) { float s = g3[i] / sqrtf(v3[i] + 1e-5f); ws[OFF_T3P + i] = outb[i] * s + b3[i] - m3[i] * s; return; }
}

// ---------------- x -> bf16 NHWC padded [4][82][84][256], zero halo ----------------
__global__ __launch_bounds__(256) void k_padx(const float* __restrict__ x, short* __restrict__ xpn)
{
  __shared__ short lds[80 * 33];
  int b = blockIdx.x;
  int cc = b & 7; int hp = (b >> 3) % THP; int n = b / (THP * 8);
  int c0 = cc * 32;
  int t = threadIdx.x;
  int h = hp - 1;
  if (h >= 0 && h < TH) {
    for (int f = t; f < 80 * 32; f += 256) {
      int ci = f / 80; int w = f - ci * 80;
      lds[w * 33 + ci] = rnbf(x[((n * TC1 + c0 + ci) * TH + h) * TW + w]);
    }
  }
  __syncthreads();
  bool hv = (h >= 0 && h < TH);
  short* op = xpn + ((n * THP + hp) * TWP) * TC2 + c0;
  for (int g = t; g < TWP * 32; g += 256) {
    int ci = g & 31; int wp = g >> 5;
    short v = 0;
    if (hv && wp >= 1 && wp <= TW) v = lds[(wp - 1) * 33 + ci];
    op[wp * TC2 + ci] = v;
  }
}

// ---------------- cv1: bf16 MFMA implicit-GEMM, K-split x2, fp32 partials ----------------
__global__ __launch_bounds__(256) void k_cv1(const short* __restrict__ xpn, const short* __restrict__ wbf,
                                             float* __restrict__ y1p)
{
  int b = blockIdx.x;
  int wt = b % 5; b /= 5; int ht = b % 10; b /= 10; int n = b & 3; b >>= 2;
  int ch = b & 1; int ks = b >> 1;
  int co0 = ch * 64, w0 = wt * 16;
  int tid = threadIdx.x;
  int wave = tid >> 6, lane = tid & 63;
  int ln = lane & 15, q = lane >> 4;
  int row0 = ht * 8 + wave * 2;
  int tap0 = ks ? 4 : 0, tap1 = ks ? 9 : 4;

  f32x4 acc[4][2];
#pragma unroll
  for (int mt = 0; mt < 4; ++mt)
#pragma unroll
    for (int pp = 0; pp < 2; ++pp) acc[mt][pp] = (f32x4){0.f, 0.f, 0.f, 0.f};

  const short* wb = wbf + (co0 + ln) * 2304 + q * 8;

  for (int tap = tap0; tap < tap1; ++tap) {
    int ky = tap / 3, kx = tap - ky * 3;
    const short* xb0 = xpn + (((n * THP + row0 + ky) * TWP) + (w0 + ln + kx)) * TC2 + q * 8;
    const short* xb1 = xb0 + TWP * TC2;
    const short* wtp = wb + tap * 256;

    bf16x8 c0f = *(const bf16x8*)(xb0);
    bf16x8 c1f = *(const bf16x8*)(xb1);
    bf16x8 c2f = *(const bf16x8*)(wtp + 0 * 16 * 2304);
    bf16x8 c3f = *(const bf16x8*)(wtp + 1 * 16 * 2304);
    bf16x8 c4f = *(const bf16x8*)(wtp + 2 * 16 * 2304);
    bf16x8 c5f = *(const bf16x8*)(wtp + 3 * 16 * 2304);

#pragma unroll
    for (int kk = 0; kk < 256; kk += 32) {
      bf16x8 n0f, n1f, n2f, n3f, n4f, n5f;
      const bool more = (kk + 32 < 256);
      if (more) {
        n0f = *(const bf16x8*)(xb0 + kk + 32);
        n1f = *(const bf16x8*)(xb1 + kk + 32);
        n2f = *(const bf16x8*)(wtp + 0 * 16 * 2304 + kk + 32);
        n3f = *(const bf16x8*)(wtp + 1 * 16 * 2304 + kk + 32);
        n4f = *(const bf16x8*)(wtp + 2 * 16 * 2304 + kk + 32);
        n5f = *(const bf16x8*)(wtp + 3 * 16 * 2304 + kk + 32);
      }
      acc[0][0] = __builtin_amdgcn_mfma_f32_16x16x32_bf16(c2f, c0f, acc[0][0], 0, 0, 0);
      acc[0][1] = __builtin_amdgcn_mfma_f32_16x16x32_bf16(c2f, c1f, acc[0][1], 0, 0, 0);
      acc[1][0] = __builtin_amdgcn_mfma_f32_16x16x32_bf16(c3f, c0f, acc[1][0], 0, 0, 0);
      acc[1][1] = __builtin_amdgcn_mfma_f32_16x16x32_bf16(c3f, c1f, acc[1][1], 0, 0, 0);
      acc[2][0] = __builtin_amdgcn_mfma_f32_16x16x32_bf16(c4f, c0f, acc[2][0], 0, 0, 0);
      acc[2][1] = __builtin_amdgcn_mfma_f32_16x16x32_bf16(c4f, c1f, acc[2][1], 0, 0, 0);
      acc[3][0] = __builtin_amdgcn_mfma_f32_16x16x32_bf16(c5f, c0f, acc[3][0], 0, 0, 0);
      acc[3][1] = __builtin_amdgcn_mfma_f32_16x16x32_bf16(c5f, c1f, acc[3][1], 0, 0, 0);
      if (more) { c0f = n0f; c1f = n1f; c2f = n2f; c3f = n3f; c4f = n4f; c5f = n5f; }
    }
  }

  int pix0 = (n * TH + row0) * TW + (w0 + ln);
  float* yp = y1p + ks * (NPIX * TCH);
#pragma unroll
  for (int mt = 0; mt < 4; ++mt)
#pragma unroll
    for (int pp = 0; pp < 2; ++pp)
      *(f32x4*)(yp + (pix0 + pp * TW) * TCH + co0 + mt * 16 + q * 4) = acc[mt][pp];
}

// ---------------- y1 reduce: silu(pa+pb+t1) -> bf16 NHWC ----------------
__global__ __launch_bounds__(256) void k_y1red(const float* __restrict__ y1p, const float* __restrict__ t1v,
                                               short* __restrict__ y1b)
{
  int i = blockIdx.x * 256 + threadIdx.x;   // 819200 = 25600*128/4
  int co4 = (i & 31) * 4;
  int pix = i >> 5;
  float4 a = *(const float4*)(y1p + pix * TCH + co4);
  float4 bq = *(const float4*)(y1p + NPIX * TCH + pix * TCH + co4);
  float4 t = *(const float4*)(t1v + co4);
  short4 o;
  o.x = rnbf(siluf(a.x + bq.x + t.x));
  o.y = rnbf(siluf(a.y + bq.y + t.y));
  o.z = rnbf(siluf(a.z + bq.z + t.z));
  o.w = rnbf(siluf(a.w + bq.w + t.w));
  *(short4*)(y1b + pix * TCH + co4) = o;
}

// ---------------- cv2: bf16 MFMA GEMM 128->256 + BN + SiLU -> y2 bf16 NHWC ----------------
__global__ __launch_bounds__(256) void k_cv2(const short* __restrict__ y1b, const short* __restrict__ w2b,
                                             const float* __restrict__ t2v, short* __restrict__ y2b)
{
  int px0 = blockIdx.x * 32;
  int tid = threadIdx.x;
  int wave = tid >> 6, lane = tid & 63;
  int ln = lane & 15, q = lane >> 4;
  int co0 = wave * 64;
  int pix0 = px0 + ln;

  f32x4 acc[4][2];
#pragma unroll
  for (int mt = 0; mt < 4; ++mt)
#pragma unroll
    for (int pp = 0; pp < 2; ++pp) acc[mt][pp] = (f32x4){0.f, 0.f, 0.f, 0.f};

  const short* xb0 = y1b + pix0 * TCH + q * 8;
  const short* xb1 = xb0 + 16 * TCH;
  const short* wb = w2b + (co0 + ln) * TCH + q * 8;

  bf16x8 c0f = *(const bf16x8*)(xb0);
  bf16x8 c1f = *(const bf16x8*)(xb1);
  bf16x8 c2f = *(const bf16x8*)(wb + 0 * 16 * TCH);
  bf16x8 c3f = *(const bf16x8*)(wb + 1 * 16 * TCH);
  bf16x8 c4f = *(const bf16x8*)(wb + 2 * 16 * TCH);
  bf16x8 c5f = *(const bf16x8*)(wb + 3 * 16 * TCH);

#pragma unroll
  for (int kk = 0; kk < TCH; kk += 32) {
    bf16x8 n0f, n1f, n2f, n3f, n4f, n5f;
    const bool more = (kk + 32 < TCH);
    if (more) {
      n0f = *(const bf16x8*)(xb0 + kk + 32);
      n1f = *(const bf16x8*)(xb1 + kk + 32);
      n2f = *(const bf16x8*)(wb + 0 * 16 * TCH + kk + 32);
      n3f = *(const bf16x8*)(wb + 1 * 16 * TCH + kk + 32);
      n4f = *(const bf16x8*)(wb + 2 * 16 * TCH + kk + 32);
      n5f = *(const bf16x8*)(wb + 3 * 16 * TCH + kk + 32);
    }
    acc[0][0] = __builtin_amdgcn_mfma_f32_16x16x32_bf16(c2f, c0f, acc[0][0], 0, 0, 0);
    acc[0][1] = __builtin_amdgcn_mfma_f32_16x16x32_bf16(c2f, c1f, acc[0][1], 0, 0, 0);
    acc[1][0] = __builtin_amdgcn_mfma_f32_16x16x32_bf16(c3f, c0f, acc[1][0], 0, 0, 0);
    acc[1][1] = __builtin_amdgcn_mfma_f32_16x16x32_bf16(c3f, c1f, acc[1][1], 0, 0, 0);
    acc[2][0] = __builtin_amdgcn_mfma_f32_16x16x32_bf16(c4f, c0f, acc[2][0], 0, 0, 0);
    acc[2][1] = __builtin_amdgcn_mfma_f32_16x16x32_bf16(c4f, c1f, acc[2][1], 0, 0, 0);
    acc[3][0] = __builtin_amdgcn_mfma_f32_16x16x32_bf16(c5f, c0f, acc[3][0], 0, 0, 0);
    acc[3][1] = __builtin_amdgcn_mfma_f32_16x16x32_bf16(c5f, c1f, acc[3][1], 0, 0, 0);
    if (more) { c0f = n0f; c1f = n1f; c2f = n2f; c3f = n3f; c4f = n4f; c5f = n5f; }
  }

#pragma unroll
  for (int mt = 0; mt < 4; ++mt) {
    int co = co0 + mt * 16 + q * 4;
#pragma unroll
    for (int pp = 0; pp < 2; ++pp) {
      short4 p;
      p.x = rnbf(siluf(acc[mt][pp][0] + t2v[co]));
      p.y = rnbf(siluf(acc[mt][pp][1] + t2v[co + 1]));
      p.z = rnbf(siluf(acc[mt][pp][2] + t2v[co + 2]));
      p.w = rnbf(siluf(acc[mt][pp][3] + t2v[co + 3]));
      *(short4*)(y2b + (pix0 + pp * 16) * TC2 + co) = p;
    }
  }
}

// ---------------- input_proj: bf16 MFMA GEMM 256->256 + bias -> xproj bf16 NHWC ----------------
__global__ __launch_bounds__(256) void k_proj_in(const short* __restrict__ y2b, const short* __restrict__ inwb,
                                                 const float* __restrict__ inb, short* __restrict__ xproj)
{
  int px0 = blockIdx.x * 32;
  int tid = threadIdx.x;
  int wave = tid >> 6, lane = tid & 63;
  int ln = lane & 15, q = lane >> 4;
  int co0 = wave * 64;
  int pix0 = px0 + ln;

  f32x4 acc[4][2];
#pragma unroll
  for (int mt = 0; mt < 4; ++mt)
#pragma unroll
    for (int pp = 0; pp < 2; ++pp) acc[mt][pp] = (f32x4){0.f, 0.f, 0.f, 0.f};

  const short* xb0 = y2b + pix0 * TC2 + q * 8;
  const short* xb1 = xb0 + 16 * TC2;
  const short* wb = inwb + (co0 + ln) * TC2 + q * 8;

  bf16x8 c0f = *(const bf16x8*)(xb0);
  bf16x8 c1f = *(const bf16x8*)(xb1);
  bf16x8 c2f = *(const bf16x8*)(wb + 0 * 16 * TC2);
  bf16x8 c3f = *(const bf16x8*)(wb + 1 * 16 * TC2);
  bf16x8 c4f = *(const bf16x8*)(wb + 2 * 16 * TC2);
  bf16x8 c5f = *(const bf16x8*)(wb + 3 * 16 * TC2);

#pragma unroll
  for (int kk = 0; kk < TC2; kk += 32) {
    bf16x8 n0f, n1f, n2f, n3f, n4f, n5f;
    const bool more = (kk + 32 < TC2);
    if (more) {
      n0f = *(const bf16x8*)(xb0 + kk + 32);
      n1f = *(const bf16x8*)(xb1 + kk + 32);
      n2f = *(const bf16x8*)(wb + 0 * 16 * TC2 + kk + 32);
      n3f = *(const bf16x8*)(wb + 1 * 16 * TC2 + kk + 32);
      n4f = *(const bf16x8*)(wb + 2 * 16 * TC2 + kk + 32);
      n5f = *(const bf16x8*)(wb + 3 * 16 * TC2 + kk + 32);
    }
    acc[0][0] = __builtin_amdgcn_mfma_f32_16x16x32_bf16(c2f, c0f, acc[0][0], 0, 0, 0);
    acc[0][1] = __builtin_amdgcn_mfma_f32_16x16x32_bf16(c2f, c1f, acc[0][1], 0, 0, 0);
    acc[1][0] = __builtin_amdgcn_mfma_f32_16x16x32_bf16(c3f, c0f, acc[1][0], 0, 0, 0);
    acc[1][1] = __builtin_amdgcn_mfma_f32_16x16x32_bf16(c3f, c1f, acc[1][1], 0, 0, 0);
    acc[2][0] = __builtin_amdgcn_mfma_f32_16x16x32_bf16(c4f, c0f, acc[2][0], 0, 0, 0);
    acc[2][1] = __builtin_amdgcn_mfma_f32_16x16x32_bf16(c4f, c1f, acc[2][1], 0, 0, 0);
    acc[3][0] = __builtin_amdgcn_mfma_f32_16x16x32_bf16(c5f, c0f, acc[3][0], 0, 0, 0);
    acc[3][1] = __builtin_amdgcn_mfma_f32_16x16x32_bf16(c5f, c1f, acc[3][1], 0, 0, 0);
    if (more) { c0f = n0f; c1f = n1f; c2f = n2f; c3f = n3f; c4f = n4f; c5f = n5f; }
  }

#pragma unroll
  for (int mt = 0; mt < 4; ++mt) {
    int co = co0 + mt * 16 + q * 4;
#pragma unroll
    for (int pp = 0; pp < 2; ++pp) {
      short4 p;
      p.x = rnbf(acc[mt][pp][0] + inb[co]);
      p.y = rnbf(acc[mt][pp][1] + inb[co + 1]);
      p.z = rnbf(acc[mt][pp][2] + inb[co + 2]);
      p.w = rnbf(acc[mt][pp][3] + inb[co + 3]);
      *(short4*)(xproj + (pix0 + pp * 16) * TC2 + co) = p;
    }
  }
}

// ---------------- depthwise 3x3 + bias + LayerNorm + GELU (block per pixel) ----------------
__global__ __launch_bounds__(256) void k_dwln(const short* __restrict__ y2b, const float* __restrict__ dwt,
                                              const float* __restrict__ dwb, const float* __restrict__ lng,
                                              const float* __restrict__ lnb, float* __restrict__ dwo)
{
  int pix = blockIdx.x;
  int c = threadIdx.x;
  int w = pix % TW; int h = (pix / TW) % TH; int n = pix / (TH * TW);
  float v = dwb[c];
#pragma unroll
  for (int dy = 0; dy < 3; ++dy) {
    int hh = h + dy - 1;
    if (hh < 0 || hh >= TH) continue;
#pragma unroll
    for (int dx = 0; dx < 3; ++dx) {
      int ww = w + dx - 1;
      if (ww < 0 || ww >= TW) continue;
      v += bf2f(y2b[((n * TH + hh) * TW + ww) * TC2 + c]) * dwt[(dy * 3 + dx) * TC2 + c];
    }
  }
  float sv = v, sq = v * v;
#pragma unroll
  for (int o = 32; o > 0; o >>= 1) { sv += __shfl_xor(sv, o); sq += __shfl_xor(sq, o); }
  __shared__ float red[8];
  int wid = c >> 6;
  if ((c & 63) == 0) { red[wid] = sv; red[4 + wid] = sq; }
  __syncthreads();
  float ts = red[0] + red[1] + red[2] + red[3];
  float tq = red[4] + red[5] + red[6] + red[7];
  float mu = ts * (1.f / 256.f);
  float var = tq * (1.f / 256.f) - mu * mu;
  float nv = (v - mu) / sqrtf(var + 1e-6f);
  nv = nv * lng[c] + lnb[c];
  float g = 0.5f * nv * (1.f + erff(nv * 0.70710678118654752f));
  dwo[pix * TC2 + c] = g;
}

// ---------------- offset/mask logits: raw27[pix][27] ----------------
__global__ __launch_bounds__(256) void k_offmask(const float* __restrict__ dw, const float* __restrict__ wcat,
                                                 const float* __restrict__ wcatb, float* __restrict__ raw)
{
  int g = blockIdx.x * 256 + threadIdx.x;
  if (g >= NPIX * 27) return;
  int j = g % 27, pix = g / 27;
  const float4* a = (const float4*)(dw + pix * TC2);
  const float4* wv = (const float4*)(wcat + j * TC2);
  float acc = 0.f;
#pragma unroll 4
  for (int i = 0; i < 64; ++i) {
    float4 xx = a[i], yy = wv[i];
    acc += xx.x * yy.x + xx.y * yy.y + xx.z * yy.z + xx.w * yy.w;
  }
  raw[g] = acc + wcatb[j];
}

// ---------------- DCN core: wave-per-pixel, LDS-precomputed taps ----------------
// grid 6400 = 25600/4 pixels; 4 waves/block, one pixel per wave, 4 channels/lane
__global__ __launch_bounds__(256) void k_dcn(const short* __restrict__ xproj, const float* __restrict__ raw,
                                             short* __restrict__ z)
{
  __shared__ int2 sp[4][36];   // per-wave: (idx, weight-bits) per (sample k, bilinear tap)
  int tid = threadIdx.x;
  int wave = tid >> 6, lane = tid & 63;
  int pix = blockIdx.x * 4 + wave;
  int w = pix % TW; int h = (pix / TW) % TH; int n = pix / (TH * TW);
  const float* r = raw + pix * 27;

  if (lane < 36) {
    int k = lane >> 2, tap = lane & 3;
    int tx = tap & 1, ty = tap >> 1;
    // softmax over 9 mask logits (redundant across the 36 setup lanes only)
    float mx = r[18];
#pragma unroll
    for (int kk = 1; kk < 9; ++kk) mx = fmaxf(mx, r[18 + kk]);
    float sum = 0.f, ek = 0.f;
#pragma unroll
    for (int kk = 0; kk < 9; ++kk) {
      float ee = expf(r[18 + kk] - mx);
      sum += ee;
      if (kk == k) ek = ee;
    }
    float mk = ek / sum;
    // padded-coordinate sample position
    float px = (float)(w + k / 3) + r[2 * k];
    float py = (float)(h + k % 3) + r[2 * k + 1];
    float x0f = floorf(px), y0f = floorf(py);
    float lw = px - x0f, lh = py - y0f;
    int x0 = (int)x0f + tx, y0 = (int)y0f + ty;
    float wt = mk * (tx ? lw : 1.f - lw) * (ty ? lh : 1.f - lh);
    bool valid = (x0 >= 1) & (x0 <= TW) & (y0 >= 1) & (y0 <= TH);
    int2 pr;
    pr.x = valid ? (((y0 - 1) * TW + (x0 - 1)) * TC2) : 0;
    pr.y = valid ? __float_as_int(wt) : 0;
    sp[wave][lane] = pr;
  }
  __syncthreads();

  int c0 = lane * 4;
  const short* xb = xproj + n * (TH * TW * TC2) + c0;
  float a0 = 0.f, a1 = 0.f, a2 = 0.f, a3 = 0.f;
#pragma unroll
  for (int t = 0; t < 36; ++t) {
    int2 pr = sp[wave][t];
    float wt = __int_as_float(pr.y);
    short4 v = *(const short4*)(xb + pr.x);
    a0 += wt * bf2f(v.x);
    a1 += wt * bf2f(v.y);
    a2 += wt * bf2f(v.z);
    a3 += wt * bf2f(v.w);
  }
  short4 o;
  o.x = rnbf(a0); o.y = rnbf(a1); o.z = rnbf(a2); o.w = rnbf(a3);
  *(short4*)(z + pix * TC2 + c0) = o;
}

// ---------------- output_proj (MFMA) + BN + SiLU + residual -> d_out NCHW fp32 ----------------
__global__ __launch_bounds__(256) void k_proj_out(const short* __restrict__ zb, const short* __restrict__ outwb,
                                                  const float* __restrict__ t3p,
                                                  const float* __restrict__ x, float* __restrict__ out)
{
  int px0 = blockIdx.x * 32;
  int tid = threadIdx.x;
  int wave = tid >> 6, lane = tid & 63;
  int ln = lane & 15, q = lane >> 4;
  int co0 = wave * 64;
  int pix0 = px0 + ln;

  f32x4 acc[4][2];
#pragma unroll
  for (int mt = 0; mt < 4; ++mt)
#pragma unroll
    for (int pp = 0; pp < 2; ++pp) acc[mt][pp] = (f32x4){0.f, 0.f, 0.f, 0.f};

  const short* xb0 = zb + pix0 * TC2 + q * 8;
  const short* xb1 = xb0 + 16 * TC2;
  const short* wb = outwb + (co0 + ln) * TC2 + q * 8;

  bf16x8 c0f = *(const bf16x8*)(xb0);
  bf16x8 c1f = *(const bf16x8*)(xb1);
  bf16x8 c2f = *(const bf16x8*)(wb + 0 * 16 * TC2);
  bf16x8 c3f = *(const bf16x8*)(wb + 1 * 16 * TC2);
  bf16x8 c4f = *(const bf16x8*)(wb + 2 * 16 * TC2);
  bf16x8 c5f = *(const bf16x8*)(wb + 3 * 16 * TC2);

#pragma unroll
  for (int kk = 0; kk < TC2; kk += 32) {
    bf16x8 n0f, n1f, n2f, n3f, n4f, n5f;
    const bool more = (kk + 32 < TC2);
    if (more) {
      n0f = *(const bf16x8*)(xb0 + kk + 32);
      n1f = *(const bf16x8*)(xb1 + kk + 32);
      n2f = *(const bf16x8*)(wb + 0 * 16 * TC2 + kk + 32);
      n3f = *(const bf16x8*)(wb + 1 * 16 * TC2 + kk + 32);
      n4f = *(const bf16x8*)(wb + 2 * 16 * TC2 + kk + 32);
      n5f = *(const bf16x8*)(wb + 3 * 16 * TC2 + kk + 32);
    }
    acc[0][0] = __builtin_amdgcn_mfma_f32_16x16x32_bf16(c2f, c0f, acc[0][0], 0, 0, 0);
    acc[0][1] = __builtin_amdgcn_mfma_f32_16x16x32_bf16(c2f, c1f, acc[0][1], 0, 0, 0);
    acc[1][0] = __builtin_amdgcn_mfma_f32_16x16x32_bf16(c3f, c0f, acc[1][0], 0, 0, 0);
    acc[1][1] = __builtin_amdgcn_mfma_f32_16x16x32_bf16(c3f, c1f, acc[1][1], 0, 0, 0);
    acc[2][0] = __builtin_amdgcn_mfma_f32_16x16x32_bf16(c4f, c0f, acc[2][0], 0, 0, 0);
    acc[2][1] = __builtin_amdgcn_mfma_f32_16x16x32_bf16(c4f, c1f, acc[2][1], 0, 0, 0);
    acc[3][0] = __builtin_amdgcn_mfma_f32_16x16x32_bf16(c5f, c0f, acc[3][0], 0, 0, 0);
    acc[3][1] = __builtin_amdgcn_mfma_f32_16x16x32_bf16(c5f, c1f, acc[3][1], 0, 0, 0);
    if (more) { c0f = n0f; c1f = n1f; c2f = n2f; c3f = n3f; c4f = n4f; c5f = n5f; }
  }

#pragma unroll
  for (int mt = 0; mt < 4; ++mt) {
#pragma unroll
    for (int pp = 0; pp < 2; ++pp) {
      int pix = pix0 + pp * 16;
      int n = pix / (TH * TW);
      int hw = pix - n * (TH * TW);
#pragma unroll
      for (int r = 0; r < 4; ++r) {
        int co = co0 + mt * 16 + q * 4 + r;
        int addr = (n * TC2 + co) * (TH * TW) + hw;
        out[addr] = x[addr] + siluf(acc[mt][pp][r] + t3p[co]);
      }
    }
  }
}

extern "C" void kernel_launch(void* const* d_in, const int* in_sizes, int n_in,
                              void* d_out, int out_size, void* d_ws, size_t ws_size,
                              hipStream_t stream)
{
  const float* x    = (const float*)d_in[0];
  const float* w1   = (const float*)d_in[1];
  const float* g1   = (const float*)d_in[2];
  const float* b1   = (const float*)d_in[3];
  const float* m1   = (const float*)d_in[4];
  const float* v1   = (const float*)d_in[5];
  const float* w2   = (const float*)d_in[6];
  const float* g2   = (const float*)d_in[7];
  const float* b2   = (const float*)d_in[8];
  const float* m2   = (const float*)d_in[9];
  const float* v2   = (const float*)d_in[10];
  const float* dww  = (const float*)d_in[11];
  const float* dwb  = (const float*)d_in[12];
  const float* lng  = (const float*)d_in[13];
  const float* lnb  = (const float*)d_in[14];
  const float* offw = (const float*)d_in[15];
  const float* offb = (const float*)d_in[16];
  const float* mskw = (const float*)d_in[17];
  const float* mskb = (const float*)d_in[18];
  const float* inw  = (const float*)d_in[19];
  const float* inb  = (const float*)d_in[20];
  const float* outw = (const float*)d_in[21];
  const float* outb = (const float*)d_in[22];
  const float* g3   = (const float*)d_in[23];
  const float* b3   = (const float*)d_in[24];
  const float* m3   = (const float*)d_in[25];
  const float* v3   = (const float*)d_in[26];

  float* ws  = (float*)d_ws;
  float* out = (float*)d_out;

  short* xpn   = (short*)(ws + OFF_XPAD);
  short* wbf   = (short*)(ws + OFF_WBF);
  short* w2b   = (short*)(ws + OFF_W2B);
  short* inwb  = (short*)(ws + OFF_INWB);
  short* outwb = (short*)(ws + OFF_OUTWB);
  float* y1p   = ws + OFF_Y1P;
  short* y1b   = (short*)(ws + OFF_Y1);
  short* y2b   = (short*)(ws + OFF_Y2);
  float* dwo   = ws + OFF_DW;
  float* raw   = ws + OFF_RAW;
  short* zb    = (short*)(ws + OFF_Z);
  short* xproj = (short*)d_out;

  hipLaunchKernelGGL(k_prep, dim3(1831), dim3(256), 0, stream,
                     w1, g1, b1, m1, v1, w2, g2, b2, m2, v2,
                     dww, offw, offb, mskw, mskb, inw, outw, outb, g3, b3, m3, v3, ws);
  hipLaunchKernelGGL(k_padx,     dim3(TN * THP * 8), dim3(256), 0, stream, x, xpn);
  hipLaunchKernelGGL(k_cv1,      dim3(800),   dim3(256), 0, stream, xpn, wbf, y1p);
  hipLaunchKernelGGL(k_y1red,    dim3(3200),  dim3(256), 0, stream, y1p, ws + OFF_T1, y1b);
  hipLaunchKernelGGL(k_cv2,      dim3(800),   dim3(256), 0, stream, y1b, w2b, ws + OFF_T2, y2b);
  hipLaunchKernelGGL(k_proj_in,  dim3(800),   dim3(256), 0, stream, y2b, inwb, inb, xproj);
  hipLaunchKernelGGL(k_dwln,     dim3(25600), dim3(256), 0, stream, y2b, ws + OFF_DWT, dwb, lng, lnb, dwo);
  hipLaunchKernelGGL(k_offmask,  dim3(2700),  dim3(256), 0, stream, dwo, ws + OFF_WCAT, ws + OFF_WCATB, raw);
  hipLaunchKernelGGL(k_dcn,      dim3(6400),  dim3(256), 0, stream, xproj, raw, zb);
  hipLaunchKernelGGL(k_proj_out, dim3(800),   dim3(256), 0, stream, zb, outwb, ws + OFF_T3P, x, out);
}

// Round 6
// 377.814 us; speedup vs baseline: 3.3243x; 1.2959x over previous
//
#include <hip/hip_runtime.h>
#include <cmath>

// Problem dims
#define TN 4
#define TC1 256
#define TCH 128
#define TC2 256
#define TH 80
#define TW 80
#define THP 82
#define TWP 84
#define NPIX (TN*TH*TW)   // 25600

// Workspace layout (float offsets). Total = 17,356,288 floats = 69.4 MB.
#define OFF_WBF   0         // bf16 wbf[co][tap*256+ci], s1-folded: 294912 shorts
#define OFF_W2B   294912    // bf16 [co][ci=128], s2-folded: 32768 shorts
#define OFF_INWB  327680    // bf16 [co][ci=256]: 65536 shorts
#define OFF_OUTWB 393216    // bf16 [co][ci=256], s3-folded: 65536 shorts
#define OFF_DWT   458752    // fp32 [tap][c] 2304
#define OFF_WCAT  461056    // bf16 [j<32][c=256] 8192 shorts (rows 27-31 zero)
#define OFF_WCATB 467968    // fp32 27
#define OFF_T1    468128    // 128
#define OFF_T2    468512    // 256
#define OFF_T3P   469024    // 256  (= out_b*s3 + b3 - m3*s3)
#define OFF_XPAD  469504    // bf16 NHWC padded x [4][82][84][256] shorts
#define OFF_Y1    7525888   // bf16 y1 [25600][128] shorts (region 3.27M floats)
#define OFF_Y2    10802688  // region 6,553,600 floats -> end 17,356,288
// aliases (dead-before-reuse by stream order):
#define OFF_Y1P   OFF_Y2    // fp32 cv1 partials [2][25600][128] (y2 not yet written)
#define OFF_DW    OFF_XPAD  // bf16 dw/LN/GELU output (xpad dead after cv1)
#define OFF_RAW   OFF_Y1    // fp32 27/pixel (y1 dead after cv2)
#define OFF_Z     OFF_Y2    // bf16 DCN output (y2 dead after proj_in/dwln)

typedef __attribute__((ext_vector_type(8))) short bf16x8;
typedef __attribute__((ext_vector_type(4))) float f32x4;

__device__ __forceinline__ float siluf(float v) { return v / (1.f + expf(-v)); }
__device__ __forceinline__ short rnbf(float f) {
  unsigned u = __float_as_uint(f);
  unsigned r = (u + 0x7fffu + ((u >> 16) & 1u)) >> 16;
  return (short)r;
}
__device__ __forceinline__ float bf2f(short s) {
  return __uint_as_float(((unsigned)(unsigned short)s) << 16);
}

// ---------------- prep: weight transposes + BN constant folding ----------------
__global__ __launch_bounds__(256) void k_prep(
    const float* __restrict__ w1, const float* __restrict__ g1, const float* __restrict__ b1,
    const float* __restrict__ m1, const float* __restrict__ v1,
    const float* __restrict__ w2, const float* __restrict__ g2, const float* __restrict__ b2,
    const float* __restrict__ m2, const float* __restrict__ v2,
    const float* __restrict__ dww, const float* __restrict__ offw, const float* __restrict__ offb,
    const float* __restrict__ mskw, const float* __restrict__ mskb,
    const float* __restrict__ inw, const float* __restrict__ outw, const float* __restrict__ outb,
    const float* __restrict__ g3, const float* __restrict__ b3,
    const float* __restrict__ m3, const float* __restrict__ v3,
    float* __restrict__ ws)
{
  int i = blockIdx.x * 256 + threadIdx.x;
  if (i < 294912) {                 // wbf[co][(ky*3+kx)*256+ci] = w1[co][ci][ky][kx] * s1[co]
    int co = i / 2304; int r = i - co * 2304;
    int tap = r >> 8; int ci = r & 255; int ky = tap / 3; int kx = tap - ky * 3;
    float s = g1[co] * __frsqrt_rn(v1[co] + 1e-5f);
    ((short*)(ws + OFF_WBF))[i] = rnbf(w1[((co * TC1 + ci) * 3 + ky) * 3 + kx] * s);
    return;
  }
  i -= 294912;
  if (i < 32768) {                  // w2b[co][ci] = w2[co][ci] * s2[co]
    int co = i >> 7; int ci = i & 127;
    float s = g2[co] * __frsqrt_rn(v2[co] + 1e-5f);
    ((short*)(ws + OFF_W2B))[i] = rnbf(w2[co * TCH + ci] * s);
    return;
  }
  i -= 32768;
  if (i < 65536) {                  // inwb[co][ci]
    int co = i >> 8; int ci = i & 255;
    ((short*)(ws + OFF_INWB))[i] = rnbf(inw[co * TC2 + ci]);
    return;
  }
  i -= 65536;
  if (i < 65536) {                  // outwb[co][ci] = outw[co][ci] * s3[co]
    int co = i >> 8; int ci = i & 255;
    float s = g3[co] * __frsqrt_rn(v3[co] + 1e-5f);
    ((short*)(ws + OFF_OUTWB))[i] = rnbf(outw[co * TC2 + ci] * s);
    return;
  }
  i -= 65536;
  if (i < 2304) { int c = i & 255; int j = i >> 8; ws[OFF_DWT + i] = dww[c * 9 + j]; return; }
  i -= 2304;
  if (i < 8192) {                   // wcat bf16 [32][256], rows 27-31 zero
    int c = i & 255; int j = i >> 8;
    float v = 0.f;
    if (j < 18) v = offw[j * 256 + c];
    else if (j < 27) v = mskw[(j - 18) * 256 + c];
    ((short*)(ws + OFF_WCAT))[i] = rnbf(v);
    return;
  }
  i -= 8192;
  if (i < 27) { ws[OFF_WCATB + i] = (i < 18) ? offb[i] : mskb[i - 18]; return; }
  i -= 27;
  if (i < 128) { float s = g1[i] / sqrtf(v1[i] + 1e-5f); ws[OFF_T1 + i] = b1[i] - m1[i] * s; return; }
  i -= 128;
  if (i < 256) { float s = g2[i] / sqrtf(v2[i] + 1e-5f); ws[OFF_T2 + i] = b2[i] - m2[i] * s; return; }
  i -= 256;
  if (i < 256) { float s = g3[i] / sqrtf(v3[i] + 1e-5f); ws[OFF_T3P + i] = outb[i] * s + b3[i] - m3[i] * s; return; }
}

// ---------------- x -> bf16 NHWC padded [4][82][84][256], zero halo ----------------
__global__ __launch_bounds__(256) void k_padx(const float* __restrict__ x, short* __restrict__ xpn)
{
  __shared__ short lds[80 * 33];
  int b = blockIdx.x;
  int cc = b & 7; int hp = (b >> 3) % THP; int n = b / (THP * 8);
  int c0 = cc * 32;
  int t = threadIdx.x;
  int h = hp - 1;
  if (h >= 0 && h < TH) {
    for (int f = t; f < 80 * 32; f += 256) {
      int ci = f / 80; int w = f - ci * 80;
      lds[w * 33 + ci] = rnbf(x[((n * TC1 + c0 + ci) * TH + h) * TW + w]);
    }
  }
  __syncthreads();
  bool hv = (h >= 0 && h < TH);
  short* op = xpn + ((n * THP + hp) * TWP) * TC2 + c0;
  for (int g = t; g < TWP * 32; g += 256) {
    int ci = g & 31; int wp = g >> 5;
    short v = 0;
    if (hv && wp >= 1 && wp <= TW) v = lds[(wp - 1) * 33 + ci];
    op[wp * TC2 + ci] = v;
  }
}

// ---------------- cv1: bf16 MFMA implicit-GEMM, K-split x2, fp32 partials ----------------
__global__ __launch_bounds__(256) void k_cv1(const short* __restrict__ xpn, const short* __restrict__ wbf,
                                             float* __restrict__ y1p)
{
  int b = blockIdx.x;
  int wt = b % 5; b /= 5; int ht = b % 10; b /= 10; int n = b & 3; b >>= 2;
  int ch = b & 1; int ks = b >> 1;
  int co0 = ch * 64, w0 = wt * 16;
  int tid = threadIdx.x;
  int wave = tid >> 6, lane = tid & 63;
  int ln = lane & 15, q = lane >> 4;
  int row0 = ht * 8 + wave * 2;
  int tap0 = ks ? 4 : 0, tap1 = ks ? 9 : 4;

  f32x4 acc[4][2];
#pragma unroll
  for (int mt = 0; mt < 4; ++mt)
#pragma unroll
    for (int pp = 0; pp < 2; ++pp) acc[mt][pp] = (f32x4){0.f, 0.f, 0.f, 0.f};

  const short* wb = wbf + (co0 + ln) * 2304 + q * 8;

  for (int tap = tap0; tap < tap1; ++tap) {
    int ky = tap / 3, kx = tap - ky * 3;
    const short* xb0 = xpn + (((n * THP + row0 + ky) * TWP) + (w0 + ln + kx)) * TC2 + q * 8;
    const short* xb1 = xb0 + TWP * TC2;
    const short* wtp = wb + tap * 256;

    bf16x8 c0f = *(const bf16x8*)(xb0);
    bf16x8 c1f = *(const bf16x8*)(xb1);
    bf16x8 c2f = *(const bf16x8*)(wtp + 0 * 16 * 2304);
    bf16x8 c3f = *(const bf16x8*)(wtp + 1 * 16 * 2304);
    bf16x8 c4f = *(const bf16x8*)(wtp + 2 * 16 * 2304);
    bf16x8 c5f = *(const bf16x8*)(wtp + 3 * 16 * 2304);

#pragma unroll
    for (int kk = 0; kk < 256; kk += 32) {
      bf16x8 n0f, n1f, n2f, n3f, n4f, n5f;
      const bool more = (kk + 32 < 256);
      if (more) {
        n0f = *(const bf16x8*)(xb0 + kk + 32);
        n1f = *(const bf16x8*)(xb1 + kk + 32);
        n2f = *(const bf16x8*)(wtp + 0 * 16 * 2304 + kk + 32);
        n3f = *(const bf16x8*)(wtp + 1 * 16 * 2304 + kk + 32);
        n4f = *(const bf16x8*)(wtp + 2 * 16 * 2304 + kk + 32);
        n5f = *(const bf16x8*)(wtp + 3 * 16 * 2304 + kk + 32);
      }
      acc[0][0] = __builtin_amdgcn_mfma_f32_16x16x32_bf16(c2f, c0f, acc[0][0], 0, 0, 0);
      acc[0][1] = __builtin_amdgcn_mfma_f32_16x16x32_bf16(c2f, c1f, acc[0][1], 0, 0, 0);
      acc[1][0] = __builtin_amdgcn_mfma_f32_16x16x32_bf16(c3f, c0f, acc[1][0], 0, 0, 0);
      acc[1][1] = __builtin_amdgcn_mfma_f32_16x16x32_bf16(c3f, c1f, acc[1][1], 0, 0, 0);
      acc[2][0] = __builtin_amdgcn_mfma_f32_16x16x32_bf16(c4f, c0f, acc[2][0], 0, 0, 0);
      acc[2][1] = __builtin_amdgcn_mfma_f32_16x16x32_bf16(c4f, c1f, acc[2][1], 0, 0, 0);
      acc[3][0] = __builtin_amdgcn_mfma_f32_16x16x32_bf16(c5f, c0f, acc[3][0], 0, 0, 0);
      acc[3][1] = __builtin_amdgcn_mfma_f32_16x16x32_bf16(c5f, c1f, acc[3][1], 0, 0, 0);
      if (more) { c0f = n0f; c1f = n1f; c2f = n2f; c3f = n3f; c4f = n4f; c5f = n5f; }
    }
  }

  int pix0 = (n * TH + row0) * TW + (w0 + ln);
  float* yp = y1p + ks * (NPIX * TCH);
#pragma unroll
  for (int mt = 0; mt < 4; ++mt)
#pragma unroll
    for (int pp = 0; pp < 2; ++pp)
      *(f32x4*)(yp + (pix0 + pp * TW) * TCH + co0 + mt * 16 + q * 4) = acc[mt][pp];
}

// ---------------- y1 reduce: silu(pa+pb+t1) -> bf16 NHWC ----------------
__global__ __launch_bounds__(256) void k_y1red(const float* __restrict__ y1p, const float* __restrict__ t1v,
                                               short* __restrict__ y1b)
{
  int i = blockIdx.x * 256 + threadIdx.x;   // 819200 = 25600*128/4
  int co4 = (i & 31) * 4;
  int pix = i >> 5;
  float4 a = *(const float4*)(y1p + pix * TCH + co4);
  float4 bq = *(const float4*)(y1p + NPIX * TCH + pix * TCH + co4);
  float4 t = *(const float4*)(t1v + co4);
  short4 o;
  o.x = rnbf(siluf(a.x + bq.x + t.x));
  o.y = rnbf(siluf(a.y + bq.y + t.y));
  o.z = rnbf(siluf(a.z + bq.z + t.z));
  o.w = rnbf(siluf(a.w + bq.w + t.w));
  *(short4*)(y1b + pix * TCH + co4) = o;
}

// ---------------- cv2: bf16 MFMA GEMM 128->256 + BN + SiLU -> y2 bf16 NHWC ----------------
__global__ __launch_bounds__(256) void k_cv2(const short* __restrict__ y1b, const short* __restrict__ w2b,
                                             const float* __restrict__ t2v, short* __restrict__ y2b)
{
  int px0 = blockIdx.x * 32;
  int tid = threadIdx.x;
  int wave = tid >> 6, lane = tid & 63;
  int ln = lane & 15, q = lane >> 4;
  int co0 = wave * 64;
  int pix0 = px0 + ln;

  f32x4 acc[4][2];
#pragma unroll
  for (int mt = 0; mt < 4; ++mt)
#pragma unroll
    for (int pp = 0; pp < 2; ++pp) acc[mt][pp] = (f32x4){0.f, 0.f, 0.f, 0.f};

  const short* xb0 = y1b + pix0 * TCH + q * 8;
  const short* xb1 = xb0 + 16 * TCH;
  const short* wb = w2b + (co0 + ln) * TCH + q * 8;

  bf16x8 c0f = *(const bf16x8*)(xb0);
  bf16x8 c1f = *(const bf16x8*)(xb1);
  bf16x8 c2f = *(const bf16x8*)(wb + 0 * 16 * TCH);
  bf16x8 c3f = *(const bf16x8*)(wb + 1 * 16 * TCH);
  bf16x8 c4f = *(const bf16x8*)(wb + 2 * 16 * TCH);
  bf16x8 c5f = *(const bf16x8*)(wb + 3 * 16 * TCH);

#pragma unroll
  for (int kk = 0; kk < TCH; kk += 32) {
    bf16x8 n0f, n1f, n2f, n3f, n4f, n5f;
    const bool more = (kk + 32 < TCH);
    if (more) {
      n0f = *(const bf16x8*)(xb0 + kk + 32);
      n1f = *(const bf16x8*)(xb1 + kk + 32);
      n2f = *(const bf16x8*)(wb + 0 * 16 * TCH + kk + 32);
      n3f = *(const bf16x8*)(wb + 1 * 16 * TCH + kk + 32);
      n4f = *(const bf16x8*)(wb + 2 * 16 * TCH + kk + 32);
      n5f = *(const bf16x8*)(wb + 3 * 16 * TCH + kk + 32);
    }
    acc[0][0] = __builtin_amdgcn_mfma_f32_16x16x32_bf16(c2f, c0f, acc[0][0], 0, 0, 0);
    acc[0][1] = __builtin_amdgcn_mfma_f32_16x16x32_bf16(c2f, c1f, acc[0][1], 0, 0, 0);
    acc[1][0] = __builtin_amdgcn_mfma_f32_16x16x32_bf16(c3f, c0f, acc[1][0], 0, 0, 0);
    acc[1][1] = __builtin_amdgcn_mfma_f32_16x16x32_bf16(c3f, c1f, acc[1][1], 0, 0, 0);
    acc[2][0] = __builtin_amdgcn_mfma_f32_16x16x32_bf16(c4f, c0f, acc[2][0], 0, 0, 0);
    acc[2][1] = __builtin_amdgcn_mfma_f32_16x16x32_bf16(c4f, c1f, acc[2][1], 0, 0, 0);
    acc[3][0] = __builtin_amdgcn_mfma_f32_16x16x32_bf16(c5f, c0f, acc[3][0], 0, 0, 0);
    acc[3][1] = __builtin_amdgcn_mfma_f32_16x16x32_bf16(c5f, c1f, acc[3][1], 0, 0, 0);
    if (more) { c0f = n0f; c1f = n1f; c2f = n2f; c3f = n3f; c4f = n4f; c5f = n5f; }
  }

#pragma unroll
  for (int mt = 0; mt < 4; ++mt) {
    int co = co0 + mt * 16 + q * 4;
#pragma unroll
    for (int pp = 0; pp < 2; ++pp) {
      short4 p;
      p.x = rnbf(siluf(acc[mt][pp][0] + t2v[co]));
      p.y = rnbf(siluf(acc[mt][pp][1] + t2v[co + 1]));
      p.z = rnbf(siluf(acc[mt][pp][2] + t2v[co + 2]));
      p.w = rnbf(siluf(acc[mt][pp][3] + t2v[co + 3]));
      *(short4*)(y2b + (pix0 + pp * 16) * TC2 + co) = p;
    }
  }
}

// ---------------- input_proj: bf16 MFMA GEMM 256->256 + bias -> xproj bf16 NHWC ----------------
__global__ __launch_bounds__(256) void k_proj_in(const short* __restrict__ y2b, const short* __restrict__ inwb,
                                                 const float* __restrict__ inb, short* __restrict__ xproj)
{
  int px0 = blockIdx.x * 32;
  int tid = threadIdx.x;
  int wave = tid >> 6, lane = tid & 63;
  int ln = lane & 15, q = lane >> 4;
  int co0 = wave * 64;
  int pix0 = px0 + ln;

  f32x4 acc[4][2];
#pragma unroll
  for (int mt = 0; mt < 4; ++mt)
#pragma unroll
    for (int pp = 0; pp < 2; ++pp) acc[mt][pp] = (f32x4){0.f, 0.f, 0.f, 0.f};

  const short* xb0 = y2b + pix0 * TC2 + q * 8;
  const short* xb1 = xb0 + 16 * TC2;
  const short* wb = inwb + (co0 + ln) * TC2 + q * 8;

  bf16x8 c0f = *(const bf16x8*)(xb0);
  bf16x8 c1f = *(const bf16x8*)(xb1);
  bf16x8 c2f = *(const bf16x8*)(wb + 0 * 16 * TC2);
  bf16x8 c3f = *(const bf16x8*)(wb + 1 * 16 * TC2);
  bf16x8 c4f = *(const bf16x8*)(wb + 2 * 16 * TC2);
  bf16x8 c5f = *(const bf16x8*)(wb + 3 * 16 * TC2);

#pragma unroll
  for (int kk = 0; kk < TC2; kk += 32) {
    bf16x8 n0f, n1f, n2f, n3f, n4f, n5f;
    const bool more = (kk + 32 < TC2);
    if (more) {
      n0f = *(const bf16x8*)(xb0 + kk + 32);
      n1f = *(const bf16x8*)(xb1 + kk + 32);
      n2f = *(const bf16x8*)(wb + 0 * 16 * TC2 + kk + 32);
      n3f = *(const bf16x8*)(wb + 1 * 16 * TC2 + kk + 32);
      n4f = *(const bf16x8*)(wb + 2 * 16 * TC2 + kk + 32);
      n5f = *(const bf16x8*)(wb + 3 * 16 * TC2 + kk + 32);
    }
    acc[0][0] = __builtin_amdgcn_mfma_f32_16x16x32_bf16(c2f, c0f, acc[0][0], 0, 0, 0);
    acc[0][1] = __builtin_amdgcn_mfma_f32_16x16x32_bf16(c2f, c1f, acc[0][1], 0, 0, 0);
    acc[1][0] = __builtin_amdgcn_mfma_f32_16x16x32_bf16(c3f, c0f, acc[1][0], 0, 0, 0);
    acc[1][1] = __builtin_amdgcn_mfma_f32_16x16x32_bf16(c3f, c1f, acc[1][1], 0, 0, 0);
    acc[2][0] = __builtin_amdgcn_mfma_f32_16x16x32_bf16(c4f, c0f, acc[2][0], 0, 0, 0);
    acc[2][1] = __builtin_amdgcn_mfma_f32_16x16x32_bf16(c4f, c1f, acc[2][1], 0, 0, 0);
    acc[3][0] = __builtin_amdgcn_mfma_f32_16x16x32_bf16(c5f, c0f, acc[3][0], 0, 0, 0);
    acc[3][1] = __builtin_amdgcn_mfma_f32_16x16x32_bf16(c5f, c1f, acc[3][1], 0, 0, 0);
    if (more) { c0f = n0f; c1f = n1f; c2f = n2f; c3f = n3f; c4f = n4f; c5f = n5f; }
  }

#pragma unroll
  for (int mt = 0; mt < 4; ++mt) {
    int co = co0 + mt * 16 + q * 4;
#pragma unroll
    for (int pp = 0; pp < 2; ++pp) {
      short4 p;
      p.x = rnbf(acc[mt][pp][0] + inb[co]);
      p.y = rnbf(acc[mt][pp][1] + inb[co + 1]);
      p.z = rnbf(acc[mt][pp][2] + inb[co + 2]);
      p.w = rnbf(acc[mt][pp][3] + inb[co + 3]);
      *(short4*)(xproj + (pix0 + pp * 16) * TC2 + co) = p;
    }
  }
}

// ---------------- depthwise 3x3 + bias + LayerNorm + GELU: wave-per-pixel -> bf16 ----------------
// grid 6400 = 25600/4; 4 waves/block, lane owns 4 channels
__global__ __launch_bounds__(256) void k_dwln(const short* __restrict__ y2b, const float* __restrict__ dwt,
                                              const float* __restrict__ dwb, const float* __restrict__ lng,
                                              const float* __restrict__ lnb, short* __restrict__ dwo)
{
  int tid = threadIdx.x;
  int wave = tid >> 6, lane = tid & 63;
  int pix = blockIdx.x * 4 + wave;
  int w = pix % TW; int h = (pix / TW) % TH; int n = pix / (TH * TW);
  int c0 = lane * 4;

  float4 bb = *(const float4*)(dwb + c0);
  float v0 = bb.x, v1 = bb.y, v2 = bb.z, v3 = bb.w;
#pragma unroll
  for (int dy = 0; dy < 3; ++dy) {
    int hh = h + dy - 1;
    if (hh < 0 || hh >= TH) continue;       // wave-uniform branch
#pragma unroll
    for (int dx = 0; dx < 3; ++dx) {
      int ww = w + dx - 1;
      if (ww < 0 || ww >= TW) continue;
      short4 yv = *(const short4*)(y2b + ((n * TH + hh) * TW + ww) * TC2 + c0);
      float4 wv = *(const float4*)(dwt + (dy * 3 + dx) * TC2 + c0);
      v0 += bf2f(yv.x) * wv.x;
      v1 += bf2f(yv.y) * wv.y;
      v2 += bf2f(yv.z) * wv.z;
      v3 += bf2f(yv.w) * wv.w;
    }
  }
  float sv = v0 + v1 + v2 + v3;
  float sq = v0 * v0 + v1 * v1 + v2 * v2 + v3 * v3;
#pragma unroll
  for (int o = 32; o > 0; o >>= 1) { sv += __shfl_xor(sv, o); sq += __shfl_xor(sq, o); }
  float mu = sv * (1.f / 256.f);
  float var = sq * (1.f / 256.f) - mu * mu;
  float rs = 1.f / sqrtf(var + 1e-6f);
  float4 gv = *(const float4*)(lng + c0);
  float4 bv = *(const float4*)(lnb + c0);
  float n0 = (v0 - mu) * rs * gv.x + bv.x;
  float n1 = (v1 - mu) * rs * gv.y + bv.y;
  float n2 = (v2 - mu) * rs * gv.z + bv.z;
  float n3 = (v3 - mu) * rs * gv.w + bv.w;
  const float is2 = 0.70710678118654752f;
  short4 o4;
  o4.x = rnbf(0.5f * n0 * (1.f + erff(n0 * is2)));
  o4.y = rnbf(0.5f * n1 * (1.f + erff(n1 * is2)));
  o4.z = rnbf(0.5f * n2 * (1.f + erff(n2 * is2)));
  o4.w = rnbf(0.5f * n3 * (1.f + erff(n3 * is2)));
  *(short4*)(dwo + pix * TC2 + c0) = o4;
}

// ---------------- offset/mask logits via MFMA: raw[pix][27] = dw @ wcat^T + b ----------------
// grid 400: 4 waves x 16 pix = 64 pix/block; wave computes 16 pix x 32 j (j>=27 discarded)
__global__ __launch_bounds__(256) void k_offmask(const short* __restrict__ dwo, const short* __restrict__ wcatb16,
                                                 const float* __restrict__ wcatb, float* __restrict__ raw)
{
  int tid = threadIdx.x;
  int wave = tid >> 6, lane = tid & 63;
  int ln = lane & 15, q = lane >> 4;
  int pix0 = blockIdx.x * 64 + wave * 16;

  f32x4 acc0 = {0.f, 0.f, 0.f, 0.f};
  f32x4 acc1 = acc0;

  const short* a0p = wcatb16 + ln * 256 + q * 8;
  const short* a1p = wcatb16 + (16 + ln) * 256 + q * 8;
  const short* bp  = dwo + (pix0 + ln) * 256 + q * 8;
#pragma unroll
  for (int kk = 0; kk < 256; kk += 32) {
    bf16x8 bf = *(const bf16x8*)(bp + kk);
    bf16x8 a0 = *(const bf16x8*)(a0p + kk);
    bf16x8 a1 = *(const bf16x8*)(a1p + kk);
    acc0 = __builtin_amdgcn_mfma_f32_16x16x32_bf16(a0, bf, acc0, 0, 0, 0);
    acc1 = __builtin_amdgcn_mfma_f32_16x16x32_bf16(a1, bf, acc1, 0, 0, 0);
  }

  int pix = pix0 + ln;
#pragma unroll
  for (int r = 0; r < 4; ++r) {
    int j0 = q * 4 + r;
    raw[pix * 27 + j0] = acc0[r] + wcatb[j0];
    int j1 = 16 + j0;
    if (j1 < 27) raw[pix * 27 + j1] = acc1[r] + wcatb[j1];
  }
}

// ---------------- DCN core: wave-per-pixel, LDS-precomputed taps ----------------
__global__ __launch_bounds__(256) void k_dcn(const short* __restrict__ xproj, const float* __restrict__ raw,
                                             short* __restrict__ z)
{
  __shared__ int2 sp[4][36];
  int tid = threadIdx.x;
  int wave = tid >> 6, lane = tid & 63;
  int pix = blockIdx.x * 4 + wave;
  int w = pix % TW; int h = (pix / TW) % TH; int n = pix / (TH * TW);
  const float* r = raw + pix * 27;

  if (lane < 36) {
    int k = lane >> 2, tap = lane & 3;
    int tx = tap & 1, ty = tap >> 1;
    float mx = r[18];
#pragma unroll
    for (int kk = 1; kk < 9; ++kk) mx = fmaxf(mx, r[18 + kk]);
    float sum = 0.f, ek = 0.f;
#pragma unroll
    for (int kk = 0; kk < 9; ++kk) {
      float ee = expf(r[18 + kk] - mx);
      sum += ee;
      if (kk == k) ek = ee;
    }
    float mk = ek / sum;
    float px = (float)(w + k / 3) + r[2 * k];
    float py = (float)(h + k % 3) + r[2 * k + 1];
    float x0f = floorf(px), y0f = floorf(py);
    float lw = px - x0f, lh = py - y0f;
    int x0 = (int)x0f + tx, y0 = (int)y0f + ty;
    float wt = mk * (tx ? lw : 1.f - lw) * (ty ? lh : 1.f - lh);
    bool valid = (x0 >= 1) & (x0 <= TW) & (y0 >= 1) & (y0 <= TH);
    int2 pr;
    pr.x = valid ? (((y0 - 1) * TW + (x0 - 1)) * TC2) : 0;
    pr.y = valid ? __float_as_int(wt) : 0;
    sp[wave][lane] = pr;
  }
  __syncthreads();

  int c0 = lane * 4;
  const short* xb = xproj + n * (TH * TW * TC2) + c0;
  float a0 = 0.f, a1 = 0.f, a2 = 0.f, a3 = 0.f;
#pragma unroll
  for (int t = 0; t < 36; ++t) {
    int2 pr = sp[wave][t];
    float wt = __int_as_float(pr.y);
    short4 v = *(const short4*)(xb + pr.x);
    a0 += wt * bf2f(v.x);
    a1 += wt * bf2f(v.y);
    a2 += wt * bf2f(v.z);
    a3 += wt * bf2f(v.w);
  }
  short4 o;
  o.x = rnbf(a0); o.y = rnbf(a1); o.z = rnbf(a2); o.w = rnbf(a3);
  *(short4*)(z + pix * TC2 + c0) = o;
}

// ---------------- output_proj (MFMA) + BN + SiLU + residual -> d_out NCHW fp32 ----------------
__global__ __launch_bounds__(256) void k_proj_out(const short* __restrict__ zb, const short* __restrict__ outwb,
                                                  const float* __restrict__ t3p,
                                                  const float* __restrict__ x, float* __restrict__ out)
{
  int px0 = blockIdx.x * 32;
  int tid = threadIdx.x;
  int wave = tid >> 6, lane = tid & 63;
  int ln = lane & 15, q = lane >> 4;
  int co0 = wave * 64;
  int pix0 = px0 + ln;

  f32x4 acc[4][2];
#pragma unroll
  for (int mt = 0; mt < 4; ++mt)
#pragma unroll
    for (int pp = 0; pp < 2; ++pp) acc[mt][pp] = (f32x4){0.f, 0.f, 0.f, 0.f};

  const short* xb0 = zb + pix0 * TC2 + q * 8;
  const short* xb1 = xb0 + 16 * TC2;
  const short* wb = outwb + (co0 + ln) * TC2 + q * 8;

  bf16x8 c0f = *(const bf16x8*)(xb0);
  bf16x8 c1f = *(const bf16x8*)(xb1);
  bf16x8 c2f = *(const bf16x8*)(wb + 0 * 16 * TC2);
  bf16x8 c3f = *(const bf16x8*)(wb + 1 * 16 * TC2);
  bf16x8 c4f = *(const bf16x8*)(wb + 2 * 16 * TC2);
  bf16x8 c5f = *(const bf16x8*)(wb + 3 * 16 * TC2);

#pragma unroll
  for (int kk = 0; kk < TC2; kk += 32) {
    bf16x8 n0f, n1f, n2f, n3f, n4f, n5f;
    const bool more = (kk + 32 < TC2);
    if (more) {
      n0f = *(const bf16x8*)(xb0 + kk + 32);
      n1f = *(const bf16x8*)(xb1 + kk + 32);
      n2f = *(const bf16x8*)(wb + 0 * 16 * TC2 + kk + 32);
      n3f = *(const bf16x8*)(wb + 1 * 16 * TC2 + kk + 32);
      n4f = *(const bf16x8*)(wb + 2 * 16 * TC2 + kk + 32);
      n5f = *(const bf16x8*)(wb + 3 * 16 * TC2 + kk + 32);
    }
    acc[0][0] = __builtin_amdgcn_mfma_f32_16x16x32_bf16(c2f, c0f, acc[0][0], 0, 0, 0);
    acc[0][1] = __builtin_amdgcn_mfma_f32_16x16x32_bf16(c2f, c1f, acc[0][1], 0, 0, 0);
    acc[1][0] = __builtin_amdgcn_mfma_f32_16x16x32_bf16(c3f, c0f, acc[1][0], 0, 0, 0);
    acc[1][1] = __builtin_amdgcn_mfma_f32_16x16x32_bf16(c3f, c1f, acc[1][1], 0, 0, 0);
    acc[2][0] = __builtin_amdgcn_mfma_f32_16x16x32_bf16(c4f, c0f, acc[2][0], 0, 0, 0);
    acc[2][1] = __builtin_amdgcn_mfma_f32_16x16x32_bf16(c4f, c1f, acc[2][1], 0, 0, 0);
    acc[3][0] = __builtin_amdgcn_mfma_f32_16x16x32_bf16(c5f, c0f, acc[3][0], 0, 0, 0);
    acc[3][1] = __builtin_amdgcn_mfma_f32_16x16x32_bf16(c5f, c1f, acc[3][1], 0, 0, 0);
    if (more) { c0f = n0f; c1f = n1f; c2f = n2f; c3f = n3f; c4f = n4f; c5f = n5f; }
  }

#pragma unroll
  for (int mt = 0; mt < 4; ++mt) {
#pragma unroll
    for (int pp = 0; pp < 2; ++pp) {
      int pix = pix0 + pp * 16;
      int n = pix / (TH * TW);
      int hw = pix - n * (TH * TW);
#pragma unroll
      for (int r = 0; r < 4; ++r) {
        int co = co0 + mt * 16 + q * 4 + r;
        int addr = (n * TC2 + co) * (TH * TW) + hw;
        out[addr] = x[addr] + siluf(acc[mt][pp][r] + t3p[co]);
      }
    }
  }
}

extern "C" void kernel_launch(void* const* d_in, const int* in_sizes, int n_in,
                              void* d_out, int out_size, void* d_ws, size_t ws_size,
                              hipStream_t stream)
{
  const float* x    = (const float*)d_in[0];
  const float* w1   = (const float*)d_in[1];
  const float* g1   = (const float*)d_in[2];
  const float* b1   = (const float*)d_in[3];
  const float* m1   = (const float*)d_in[4];
  const float* v1   = (const float*)d_in[5];
  const float* w2   = (const float*)d_in[6];
  const float* g2   = (const float*)d_in[7];
  const float* b2   = (const float*)d_in[8];
  const float* m2   = (const float*)d_in[9];
  const float* v2   = (const float*)d_in[10];
  const float* dww  = (const float*)d_in[11];
  const float* dwb  = (const float*)d_in[12];
  const float* lng  = (const float*)d_in[13];
  const float* lnb  = (const float*)d_in[14];
  const float* offw = (const float*)d_in[15];
  const float* offb = (const float*)d_in[16];
  const float* mskw = (const float*)d_in[17];
  const float* mskb = (const float*)d_in[18];
  const float* inw  = (const float*)d_in[19];
  const float* inb  = (const float*)d_in[20];
  const float* outw = (const float*)d_in[21];
  const float* outb = (const float*)d_in[22];
  const float* g3   = (const float*)d_in[23];
  const float* b3   = (const float*)d_in[24];
  const float* m3   = (const float*)d_in[25];
  const float* v3   = (const float*)d_in[26];

  float* ws  = (float*)d_ws;
  float* out = (float*)d_out;

  short* xpn    = (short*)(ws + OFF_XPAD);
  short* wbf    = (short*)(ws + OFF_WBF);
  short* w2b    = (short*)(ws + OFF_W2B);
  short* inwb   = (short*)(ws + OFF_INWB);
  short* outwb  = (short*)(ws + OFF_OUTWB);
  short* wcat16 = (short*)(ws + OFF_WCAT);
  float* y1p    = ws + OFF_Y1P;
  short* y1b    = (short*)(ws + OFF_Y1);
  short* y2b    = (short*)(ws + OFF_Y2);
  short* dwo    = (short*)(ws + OFF_DW);   // bf16 now
  float* raw    = ws + OFF_RAW;
  short* zb     = (short*)(ws + OFF_Z);
  short* xproj  = (short*)d_out;

  hipLaunchKernelGGL(k_prep, dim3(1836), dim3(256), 0, stream,
                     w1, g1, b1, m1, v1, w2, g2, b2, m2, v2,
                     dww, offw, offb, mskw, mskb, inw, outw, outb, g3, b3, m3, v3, ws);
  hipLaunchKernelGGL(k_padx,     dim3(TN * THP * 8), dim3(256), 0, stream, x, xpn);
  hipLaunchKernelGGL(k_cv1,      dim3(800),   dim3(256), 0, stream, xpn, wbf, y1p);
  hipLaunchKernelGGL(k_y1red,    dim3(3200),  dim3(256), 0, stream, y1p, ws + OFF_T1, y1b);
  hipLaunchKernelGGL(k_cv2,      dim3(800),   dim3(256), 0, stream, y1b, w2b, ws + OFF_T2, y2b);
  hipLaunchKernelGGL(k_proj_in,  dim3(800),   dim3(256), 0, stream, y2b, inwb, inb, xproj);
  hipLaunchKernelGGL(k_dwln,     dim3(6400),  dim3(256), 0, stream, y2b, ws + OFF_DWT, dwb, lng, lnb, dwo);
  hipLaunchKernelGGL(k_offmask,  dim3(400),   dim3(256), 0, stream, dwo, wcat16, ws + OFF_WCATB, raw);
  hipLaunchKernelGGL(k_dcn,      dim3(6400),  dim3(256), 0, stream, xproj, raw, zb);
  hipLaunchKernelGGL(k_proj_out, dim3(800),   dim3(256), 0, stream, zb, outwb, ws + OFF_T3P, x, out);
}

// Round 7
// 309.250 us; speedup vs baseline: 4.0614x; 1.2217x over previous
//
#include <hip/hip_runtime.h>
#include <cmath>

// Problem dims
#define TN 4
#define TC1 256
#define TCH 128
#define TC2 256
#define TH 80
#define TW 80
#define THP 82
#define TWP 84
#define NPIX (TN*TH*TW)   // 25600

// Workspace layout (float offsets). Total = 17,356,288 floats = 69.4 MB.
#define OFF_WBF   0         // bf16 wbf[co][tap*256+ci], s1-folded: 294912 shorts
#define OFF_W2B   294912    // bf16 [co][ci=128], s2-folded: 32768 shorts
#define OFF_INWB  327680    // bf16 [co][ci=256]: 65536 shorts
#define OFF_OUTWB 393216    // bf16 [co][ci=256], s3-folded: 65536 shorts
#define OFF_DWT   458752    // fp32 [tap][c] 2304
#define OFF_WCAT  461056    // bf16 [j<32][c=256] 8192 shorts
#define OFF_WCATB 467968    // fp32 27
#define OFF_T1    468128    // 128
#define OFF_T2    468512    // 256
#define OFF_T3P   469024    // 256
#define OFF_XPAD  469504    // bf16 NHWC padded x: 7,056,384 shorts = 3,528,192 floats -> ends 3,997,696
#define OFF_Y1B   3997696   // bf16 y1 [25600][128]: 1,638,400 floats -> ends 5,636,096
#define OFF_Y1P   7525888   // fp32 cv1 partials [3][25600][128] = 9,830,400 floats -> ends 17,356,288
// aliases (liveness chain, in stream order):
//  cv1: reads xpad -> writes y1p[3]
//  y1red: reads y1p -> writes y1b            (xpad dead after cv1)
//  cv2: reads y1b -> writes y2b @ OFF_Y2N    (y1p dead after y1red)
//  proj_in: reads y2b -> xproj (d_out)
//  dwln: reads y2b -> dwo @ OFF_DWN          (xpad region dead)
//  offmask: reads dwo -> raw @ OFF_RAWN      (tail of dead y1p region)
//  dcn: reads xproj, raw -> zb @ OFF_ZN
//  proj_out: reads zb, x -> d_out
#define OFF_Y2N   7525888   // bf16 y2 [25600][256]: 3,276,800 floats -> ends 10,802,688
#define OFF_DWN   469504    // bf16 dw [25600][256]: 3,276,800 floats -> ends 3,746,304 (< OFF_Y1B ok)
#define OFF_RAWN  10802688  // fp32 raw [25600][27]: 691,200 floats -> ends 11,493,888
#define OFF_ZN    11493888  // bf16 z [25600][256]: 3,276,800 floats -> ends 14,770,688

typedef __attribute__((ext_vector_type(8))) short bf16x8;
typedef __attribute__((ext_vector_type(4))) float f32x4;

__device__ __forceinline__ float siluf(float v) { return v / (1.f + expf(-v)); }
__device__ __forceinline__ short rnbf(float f) {
  unsigned u = __float_as_uint(f);
  unsigned r = (u + 0x7fffu + ((u >> 16) & 1u)) >> 16;
  return (short)r;
}
__device__ __forceinline__ float bf2f(short s) {
  return __uint_as_float(((unsigned)(unsigned short)s) << 16);
}

// ---------------- prep: weight transposes + BN constant folding ----------------
__global__ __launch_bounds__(256) void k_prep(
    const float* __restrict__ w1, const float* __restrict__ g1, const float* __restrict__ b1,
    const float* __restrict__ m1, const float* __restrict__ v1,
    const float* __restrict__ w2, const float* __restrict__ g2, const float* __restrict__ b2,
    const float* __restrict__ m2, const float* __restrict__ v2,
    const float* __restrict__ dww, const float* __restrict__ offw, const float* __restrict__ offb,
    const float* __restrict__ mskw, const float* __restrict__ mskb,
    const float* __restrict__ inw, const float* __restrict__ outw, const float* __restrict__ outb,
    const float* __restrict__ g3, const float* __restrict__ b3,
    const float* __restrict__ m3, const float* __restrict__ v3,
    float* __restrict__ ws)
{
  int i = blockIdx.x * 256 + threadIdx.x;
  if (i < 294912) {                 // wbf[co][(ky*3+kx)*256+ci] = w1[co][ci][ky][kx] * s1[co]
    int co = i / 2304; int r = i - co * 2304;
    int tap = r >> 8; int ci = r & 255; int ky = tap / 3; int kx = tap - ky * 3;
    float s = g1[co] * __frsqrt_rn(v1[co] + 1e-5f);
    ((short*)(ws + OFF_WBF))[i] = rnbf(w1[((co * TC1 + ci) * 3 + ky) * 3 + kx] * s);
    return;
  }
  i -= 294912;
  if (i < 32768) {
    int co = i >> 7; int ci = i & 127;
    float s = g2[co] * __frsqrt_rn(v2[co] + 1e-5f);
    ((short*)(ws + OFF_W2B))[i] = rnbf(w2[co * TCH + ci] * s);
    return;
  }
  i -= 32768;
  if (i < 65536) {
    int co = i >> 8; int ci = i & 255;
    ((short*)(ws + OFF_INWB))[i] = rnbf(inw[co * TC2 + ci]);
    return;
  }
  i -= 65536;
  if (i < 65536) {
    int co = i >> 8; int ci = i & 255;
    float s = g3[co] * __frsqrt_rn(v3[co] + 1e-5f);
    ((short*)(ws + OFF_OUTWB))[i] = rnbf(outw[co * TC2 + ci] * s);
    return;
  }
  i -= 65536;
  if (i < 2304) { int c = i & 255; int j = i >> 8; ws[OFF_DWT + i] = dww[c * 9 + j]; return; }
  i -= 2304;
  if (i < 8192) {
    int c = i & 255; int j = i >> 8;
    float v = 0.f;
    if (j < 18) v = offw[j * 256 + c];
    else if (j < 27) v = mskw[(j - 18) * 256 + c];
    ((short*)(ws + OFF_WCAT))[i] = rnbf(v);
    return;
  }
  i -= 8192;
  if (i < 27) { ws[OFF_WCATB + i] = (i < 18) ? offb[i] : mskb[i - 18]; return; }
  i -= 27;
  if (i < 128) { float s = g1[i] / sqrtf(v1[i] + 1e-5f); ws[OFF_T1 + i] = b1[i] - m1[i] * s; return; }
  i -= 128;
  if (i < 256) { float s = g2[i] / sqrtf(v2[i] + 1e-5f); ws[OFF_T2 + i] = b2[i] - m2[i] * s; return; }
  i -= 256;
  if (i < 256) { float s = g3[i] / sqrtf(v3[i] + 1e-5f); ws[OFF_T3P + i] = outb[i] * s + b3[i] - m3[i] * s; return; }
}

// ---------------- x -> bf16 NHWC padded [4][82][84][256], zero halo ----------------
__global__ __launch_bounds__(256) void k_padx(const float* __restrict__ x, short* __restrict__ xpn)
{
  __shared__ short lds[80 * 33];
  int b = blockIdx.x;
  int cc = b & 7; int hp = (b >> 3) % THP; int n = b / (THP * 8);
  int c0 = cc * 32;
  int t = threadIdx.x;
  int h = hp - 1;
  if (h >= 0 && h < TH) {
    for (int f = t; f < 80 * 32; f += 256) {
      int ci = f / 80; int w = f - ci * 80;
      lds[w * 33 + ci] = rnbf(x[((n * TC1 + c0 + ci) * TH + h) * TW + w]);
    }
  }
  __syncthreads();
  bool hv = (h >= 0 && h < TH);
  short* op = xpn + ((n * THP + hp) * TWP) * TC2 + c0;
  for (int g = t; g < TWP * 32; g += 256) {
    int ci = g & 31; int wp = g >> 5;
    short v = 0;
    if (hv && wp >= 1 && wp <= TW) v = lds[(wp - 1) * 33 + ci];
    op[wp * TC2 + ci] = v;
  }
}

// ---------------- cv1: LDS double-buffered bf16 MFMA implicit-GEMM ----------------
// grid 600 = 5wt * 10ht * 4n * 3ks; block tile 128co x 128px (8 rows x 16 cols), K = 3 taps x 256 ci.
// 4 waves, wave = 64co x 64px (16 accs). Per 32-ci chunk: stage 16KB to LDS (dbuf), 8 ds_read_b128 : 16 MFMA.
#define A_STR 40   // shorts per 32-ci LDS row (32 + 8 pad -> 80B: 16B-aligned, 2-way banks = free)
__global__ __launch_bounds__(256) void k_cv1(const short* __restrict__ xpn, const short* __restrict__ wbf,
                                             float* __restrict__ y1p)
{
  __shared__ short As[2][128 * A_STR];
  __shared__ short Bs[2][128 * A_STR];

  int b = blockIdx.x;
  int wt = b % 5; b /= 5; int ht = b % 10; b /= 10; int n = b & 3; int ks = b >> 2;
  int w0 = wt * 16, h0 = ht * 8;
  int tap0 = ks * 3;

  int tid = threadIdx.x;
  int wave = tid >> 6, lane = tid & 63;
  int ln = lane & 15, q = lane >> 4;
  int cohalf = (wave & 1) * 64;
  int pxhalf = (wave >> 1) * 64;

  // staging mapping: thread t handles row t>>1 (co for A, px for B), 32B half (t&1)
  int srow = tid >> 1;
  int ssub = (tid & 1) * 16;           // shorts
  int hr = srow >> 4, wc = srow & 15;
  const short* arow = wbf + srow * 2304 + ssub;                              // + tap*256 + ci0
  const short* brow = xpn + ((n * THP + h0 + hr) * TWP + (w0 + wc)) * 256 + ssub;  // + (ky*TWP+kx)*256 + ci0

  f32x4 acc[4][4];
#pragma unroll
  for (int i = 0; i < 4; ++i)
#pragma unroll
    for (int j = 0; j < 4; ++j) acc[i][j] = (f32x4){0.f, 0.f, 0.f, 0.f};

  bf16x8 ra0, ra1, rb0, rb1;

  auto grab = [&](int c) {
    int rt = c >> 3;                   // 0..2 within split
    int atap = tap0 + rt;
    int ci0 = (c & 7) * 32;
    int ky = atap / 3, kx = atap - ky * 3;
    const short* ap = arow + atap * 256 + ci0;
    const short* bp = brow + (ky * TWP + kx) * 256 + ci0;
    ra0 = *(const bf16x8*)(ap);
    ra1 = *(const bf16x8*)(ap + 8);
    rb0 = *(const bf16x8*)(bp);
    rb1 = *(const bf16x8*)(bp + 8);
  };
  auto put = [&](int buf) {
    int o = srow * A_STR + ssub;
    *(bf16x8*)(&As[buf][o])     = ra0;
    *(bf16x8*)(&As[buf][o + 8]) = ra1;
    *(bf16x8*)(&Bs[buf][o])     = rb0;
    *(bf16x8*)(&Bs[buf][o + 8]) = rb1;
  };
  auto comp = [&](int buf) {
    bf16x8 af[4], bfv[4];
#pragma unroll
    for (int mt = 0; mt < 4; ++mt)
      af[mt] = *(const bf16x8*)(&As[buf][(cohalf + mt * 16 + ln) * A_STR + q * 8]);
#pragma unroll
    for (int nt = 0; nt < 4; ++nt)
      bfv[nt] = *(const bf16x8*)(&Bs[buf][(pxhalf + nt * 16 + ln) * A_STR + q * 8]);
#pragma unroll
    for (int mt = 0; mt < 4; ++mt)
#pragma unroll
      for (int nt = 0; nt < 4; ++nt)
        acc[mt][nt] = __builtin_amdgcn_mfma_f32_16x16x32_bf16(af[mt], bfv[nt], acc[mt][nt], 0, 0, 0);
  };

  grab(0);
  put(0);
  __syncthreads();
  for (int c = 0; c < 24; ++c) {
    if (c < 23) grab(c + 1);           // global loads in flight during compute
    comp(c & 1);
    if (c < 23) {
      __syncthreads();                 // all waves done reading buf (c+1)&1 from 2 chunks ago
      put((c + 1) & 1);
      __syncthreads();
    }
  }

  float* yp = y1p + ks * (NPIX * TCH);
#pragma unroll
  for (int mt = 0; mt < 4; ++mt)
#pragma unroll
    for (int nt = 0; nt < 4; ++nt) {
      int p = pxhalf + nt * 16 + ln;
      int pr = p >> 4, pc = p & 15;
      int pix = (n * TH + h0 + pr) * TW + (w0 + pc);
      int co = cohalf + mt * 16 + q * 4;
      *(f32x4*)(yp + pix * TCH + co) = acc[mt][nt];
    }
}

// ---------------- y1 reduce: silu(p0+p1+p2+t1) -> bf16 NHWC ----------------
__global__ __launch_bounds__(256) void k_y1red(const float* __restrict__ y1p, const float* __restrict__ t1v,
                                               short* __restrict__ y1b)
{
  int i = blockIdx.x * 256 + threadIdx.x;   // 819200 = 25600*128/4
  int co4 = (i & 31) * 4;
  int pix = i >> 5;
  float4 a = *(const float4*)(y1p + pix * TCH + co4);
  float4 bq = *(const float4*)(y1p + NPIX * TCH + pix * TCH + co4);
  float4 cq = *(const float4*)(y1p + 2 * NPIX * TCH + pix * TCH + co4);
  float4 t = *(const float4*)(t1v + co4);
  short4 o;
  o.x = rnbf(siluf(a.x + bq.x + cq.x + t.x));
  o.y = rnbf(siluf(a.y + bq.y + cq.y + t.y));
  o.z = rnbf(siluf(a.z + bq.z + cq.z + t.z));
  o.w = rnbf(siluf(a.w + bq.w + cq.w + t.w));
  *(short4*)(y1b + pix * TCH + co4) = o;
}

// ---------------- cv2: bf16 MFMA GEMM 128->256 + BN + SiLU -> y2 bf16 NHWC ----------------
__global__ __launch_bounds__(256) void k_cv2(const short* __restrict__ y1b, const short* __restrict__ w2b,
                                             const float* __restrict__ t2v, short* __restrict__ y2b)
{
  int px0 = blockIdx.x * 32;
  int tid = threadIdx.x;
  int wave = tid >> 6, lane = tid & 63;
  int ln = lane & 15, q = lane >> 4;
  int co0 = wave * 64;
  int pix0 = px0 + ln;

  f32x4 acc[4][2];
#pragma unroll
  for (int mt = 0; mt < 4; ++mt)
#pragma unroll
    for (int pp = 0; pp < 2; ++pp) acc[mt][pp] = (f32x4){0.f, 0.f, 0.f, 0.f};

  const short* xb0 = y1b + pix0 * TCH + q * 8;
  const short* xb1 = xb0 + 16 * TCH;
  const short* wb = w2b + (co0 + ln) * TCH + q * 8;

  bf16x8 c0f = *(const bf16x8*)(xb0);
  bf16x8 c1f = *(const bf16x8*)(xb1);
  bf16x8 c2f = *(const bf16x8*)(wb + 0 * 16 * TCH);
  bf16x8 c3f = *(const bf16x8*)(wb + 1 * 16 * TCH);
  bf16x8 c4f = *(const bf16x8*)(wb + 2 * 16 * TCH);
  bf16x8 c5f = *(const bf16x8*)(wb + 3 * 16 * TCH);

#pragma unroll
  for (int kk = 0; kk < TCH; kk += 32) {
    bf16x8 n0f, n1f, n2f, n3f, n4f, n5f;
    const bool more = (kk + 32 < TCH);
    if (more) {
      n0f = *(const bf16x8*)(xb0 + kk + 32);
      n1f = *(const bf16x8*)(xb1 + kk + 32);
      n2f = *(const bf16x8*)(wb + 0 * 16 * TCH + kk + 32);
      n3f = *(const bf16x8*)(wb + 1 * 16 * TCH + kk + 32);
      n4f = *(const bf16x8*)(wb + 2 * 16 * TCH + kk + 32);
      n5f = *(const bf16x8*)(wb + 3 * 16 * TCH + kk + 32);
    }
    acc[0][0] = __builtin_amdgcn_mfma_f32_16x16x32_bf16(c2f, c0f, acc[0][0], 0, 0, 0);
    acc[0][1] = __builtin_amdgcn_mfma_f32_16x16x32_bf16(c2f, c1f, acc[0][1], 0, 0, 0);
    acc[1][0] = __builtin_amdgcn_mfma_f32_16x16x32_bf16(c3f, c0f, acc[1][0], 0, 0, 0);
    acc[1][1] = __builtin_amdgcn_mfma_f32_16x16x32_bf16(c3f, c1f, acc[1][1], 0, 0, 0);
    acc[2][0] = __builtin_amdgcn_mfma_f32_16x16x32_bf16(c4f, c0f, acc[2][0], 0, 0, 0);
    acc[2][1] = __builtin_amdgcn_mfma_f32_16x16x32_bf16(c4f, c1f, acc[2][1], 0, 0, 0);
    acc[3][0] = __builtin_amdgcn_mfma_f32_16x16x32_bf16(c5f, c0f, acc[3][0], 0, 0, 0);
    acc[3][1] = __builtin_amdgcn_mfma_f32_16x16x32_bf16(c5f, c1f, acc[3][1], 0, 0, 0);
    if (more) { c0f = n0f; c1f = n1f; c2f = n2f; c3f = n3f; c4f = n4f; c5f = n5f; }
  }

#pragma unroll
  for (int mt = 0; mt < 4; ++mt) {
    int co = co0 + mt * 16 + q * 4;
#pragma unroll
    for (int pp = 0; pp < 2; ++pp) {
      short4 p;
      p.x = rnbf(siluf(acc[mt][pp][0] + t2v[co]));
      p.y = rnbf(siluf(acc[mt][pp][1] + t2v[co + 1]));
      p.z = rnbf(siluf(acc[mt][pp][2] + t2v[co + 2]));
      p.w = rnbf(siluf(acc[mt][pp][3] + t2v[co + 3]));
      *(short4*)(y2b + (pix0 + pp * 16) * TC2 + co) = p;
    }
  }
}

// ---------------- input_proj: bf16 MFMA GEMM 256->256 + bias -> xproj bf16 NHWC ----------------
__global__ __launch_bounds__(256) void k_proj_in(const short* __restrict__ y2b, const short* __restrict__ inwb,
                                                 const float* __restrict__ inb, short* __restrict__ xproj)
{
  int px0 = blockIdx.x * 32;
  int tid = threadIdx.x;
  int wave = tid >> 6, lane = tid & 63;
  int ln = lane & 15, q = lane >> 4;
  int co0 = wave * 64;
  int pix0 = px0 + ln;

  f32x4 acc[4][2];
#pragma unroll
  for (int mt = 0; mt < 4; ++mt)
#pragma unroll
    for (int pp = 0; pp < 2; ++pp) acc[mt][pp] = (f32x4){0.f, 0.f, 0.f, 0.f};

  const short* xb0 = y2b + pix0 * TC2 + q * 8;
  const short* xb1 = xb0 + 16 * TC2;
  const short* wb = inwb + (co0 + ln) * TC2 + q * 8;

  bf16x8 c0f = *(const bf16x8*)(xb0);
  bf16x8 c1f = *(const bf16x8*)(xb1);
  bf16x8 c2f = *(const bf16x8*)(wb + 0 * 16 * TC2);
  bf16x8 c3f = *(const bf16x8*)(wb + 1 * 16 * TC2);
  bf16x8 c4f = *(const bf16x8*)(wb + 2 * 16 * TC2);
  bf16x8 c5f = *(const bf16x8*)(wb + 3 * 16 * TC2);

#pragma unroll
  for (int kk = 0; kk < TC2; kk += 32) {
    bf16x8 n0f, n1f, n2f, n3f, n4f, n5f;
    const bool more = (kk + 32 < TC2);
    if (more) {
      n0f = *(const bf16x8*)(xb0 + kk + 32);
      n1f = *(const bf16x8*)(xb1 + kk + 32);
      n2f = *(const bf16x8*)(wb + 0 * 16 * TC2 + kk + 32);
      n3f = *(const bf16x8*)(wb + 1 * 16 * TC2 + kk + 32);
      n4f = *(const bf16x8*)(wb + 2 * 16 * TC2 + kk + 32);
      n5f = *(const bf16x8*)(wb + 3 * 16 * TC2 + kk + 32);
    }
    acc[0][0] = __builtin_amdgcn_mfma_f32_16x16x32_bf16(c2f, c0f, acc[0][0], 0, 0, 0);
    acc[0][1] = __builtin_amdgcn_mfma_f32_16x16x32_bf16(c2f, c1f, acc[0][1], 0, 0, 0);
    acc[1][0] = __builtin_amdgcn_mfma_f32_16x16x32_bf16(c3f, c0f, acc[1][0], 0, 0, 0);
    acc[1][1] = __builtin_amdgcn_mfma_f32_16x16x32_bf16(c3f, c1f, acc[1][1], 0, 0, 0);
    acc[2][0] = __builtin_amdgcn_mfma_f32_16x16x32_bf16(c4f, c0f, acc[2][0], 0, 0, 0);
    acc[2][1] = __builtin_amdgcn_mfma_f32_16x16x32_bf16(c4f, c1f, acc[2][1], 0, 0, 0);
    acc[3][0] = __builtin_amdgcn_mfma_f32_16x16x32_bf16(c5f, c0f, acc[3][0], 0, 0, 0);
    acc[3][1] = __builtin_amdgcn_mfma_f32_16x16x32_bf16(c5f, c1f, acc[3][1], 0, 0, 0);
    if (more) { c0f = n0f; c1f = n1f; c2f = n2f; c3f = n3f; c4f = n4f; c5f = n5f; }
  }

#pragma unroll
  for (int mt = 0; mt < 4; ++mt) {
    int co = co0 + mt * 16 + q * 4;
#pragma unroll
    for (int pp = 0; pp < 2; ++pp) {
      short4 p;
      p.x = rnbf(acc[mt][pp][0] + inb[co]);
      p.y = rnbf(acc[mt][pp][1] + inb[co + 1]);
      p.z = rnbf(acc[mt][pp][2] + inb[co + 2]);
      p.w = rnbf(acc[mt][pp][3] + inb[co + 3]);
      *(short4*)(xproj + (pix0 + pp * 16) * TC2 + co) = p;
    }
  }
}

// ---------------- depthwise 3x3 + bias + LayerNorm + GELU: wave-per-pixel -> bf16 ----------------
__global__ __launch_bounds__(256) void k_dwln(const short* __restrict__ y2b, const float* __restrict__ dwt,
                                              const float* __restrict__ dwb, const float* __restrict__ lng,
                                              const float* __restrict__ lnb, short* __restrict__ dwo)
{
  int tid = threadIdx.x;
  int wave = tid >> 6, lane = tid & 63;
  int pix = blockIdx.x * 4 + wave;
  int w = pix % TW; int h = (pix / TW) % TH; int n = pix / (TH * TW);
  int c0 = lane * 4;

  float4 bb = *(const float4*)(dwb + c0);
  float v0 = bb.x, v1 = bb.y, v2 = bb.z, v3 = bb.w;
#pragma unroll
  for (int dy = 0; dy < 3; ++dy) {
    int hh = h + dy - 1;
    if (hh < 0 || hh >= TH) continue;
#pragma unroll
    for (int dx = 0; dx < 3; ++dx) {
      int ww = w + dx - 1;
      if (ww < 0 || ww >= TW) continue;
      short4 yv = *(const short4*)(y2b + ((n * TH + hh) * TW + ww) * TC2 + c0);
      float4 wv = *(const float4*)(dwt + (dy * 3 + dx) * TC2 + c0);
      v0 += bf2f(yv.x) * wv.x;
      v1 += bf2f(yv.y) * wv.y;
      v2 += bf2f(yv.z) * wv.z;
      v3 += bf2f(yv.w) * wv.w;
    }
  }
  float sv = v0 + v1 + v2 + v3;
  float sq = v0 * v0 + v1 * v1 + v2 * v2 + v3 * v3;
#pragma unroll
  for (int o = 32; o > 0; o >>= 1) { sv += __shfl_xor(sv, o); sq += __shfl_xor(sq, o); }
  float mu = sv * (1.f / 256.f);
  float var = sq * (1.f / 256.f) - mu * mu;
  float rs = 1.f / sqrtf(var + 1e-6f);
  float4 gv = *(const float4*)(lng + c0);
  float4 bv = *(const float4*)(lnb + c0);
  float n0 = (v0 - mu) * rs * gv.x + bv.x;
  float n1 = (v1 - mu) * rs * gv.y + bv.y;
  float n2 = (v2 - mu) * rs * gv.z + bv.z;
  float n3 = (v3 - mu) * rs * gv.w + bv.w;
  const float is2 = 0.70710678118654752f;
  short4 o4;
  o4.x = rnbf(0.5f * n0 * (1.f + erff(n0 * is2)));
  o4.y = rnbf(0.5f * n1 * (1.f + erff(n1 * is2)));
  o4.z = rnbf(0.5f * n2 * (1.f + erff(n2 * is2)));
  o4.w = rnbf(0.5f * n3 * (1.f + erff(n3 * is2)));
  *(short4*)(dwo + pix * TC2 + c0) = o4;
}

// ---------------- offset/mask logits via MFMA: raw[pix][27] = dw @ wcat^T + b ----------------
__global__ __launch_bounds__(256) void k_offmask(const short* __restrict__ dwo, const short* __restrict__ wcatb16,
                                                 const float* __restrict__ wcatb, float* __restrict__ raw)
{
  int tid = threadIdx.x;
  int wave = tid >> 6, lane = tid & 63;
  int ln = lane & 15, q = lane >> 4;
  int pix0 = blockIdx.x * 64 + wave * 16;

  f32x4 acc0 = {0.f, 0.f, 0.f, 0.f};
  f32x4 acc1 = acc0;

  const short* a0p = wcatb16 + ln * 256 + q * 8;
  const short* a1p = wcatb16 + (16 + ln) * 256 + q * 8;
  const short* bp  = dwo + (pix0 + ln) * 256 + q * 8;
#pragma unroll
  for (int kk = 0; kk < 256; kk += 32) {
    bf16x8 bf = *(const bf16x8*)(bp + kk);
    bf16x8 a0 = *(const bf16x8*)(a0p + kk);
    bf16x8 a1 = *(const bf16x8*)(a1p + kk);
    acc0 = __builtin_amdgcn_mfma_f32_16x16x32_bf16(a0, bf, acc0, 0, 0, 0);
    acc1 = __builtin_amdgcn_mfma_f32_16x16x32_bf16(a1, bf, acc1, 0, 0, 0);
  }

  int pix = pix0 + ln;
#pragma unroll
  for (int r = 0; r < 4; ++r) {
    int j0 = q * 4 + r;
    raw[pix * 27 + j0] = acc0[r] + wcatb[j0];
    int j1 = 16 + j0;
    if (j1 < 27) raw[pix * 27 + j1] = acc1[r] + wcatb[j1];
  }
}

// ---------------- DCN core: wave-per-pixel, LDS-precomputed taps ----------------
__global__ __launch_bounds__(256) void k_dcn(const short* __restrict__ xproj, const float* __restrict__ raw,
                                             short* __restrict__ z)
{
  __shared__ int2 sp[4][36];
  int tid = threadIdx.x;
  int wave = tid >> 6, lane = tid & 63;
  int pix = blockIdx.x * 4 + wave;
  int w = pix % TW; int h = (pix / TW) % TH; int n = pix / (TH * TW);
  const float* r = raw + pix * 27;

  if (lane < 36) {
    int k = lane >> 2, tap = lane & 3;
    int tx = tap & 1, ty = tap >> 1;
    float mx = r[18];
#pragma unroll
    for (int kk = 1; kk < 9; ++kk) mx = fmaxf(mx, r[18 + kk]);
    float sum = 0.f, ek = 0.f;
#pragma unroll
    for (int kk = 0; kk < 9; ++kk) {
      float ee = expf(r[18 + kk] - mx);
      sum += ee;
      if (kk == k) ek = ee;
    }
    float mk = ek / sum;
    float px = (float)(w + k / 3) + r[2 * k];
    float py = (float)(h + k % 3) + r[2 * k + 1];
    float x0f = floorf(px), y0f = floorf(py);
    float lw = px - x0f, lh = py - y0f;
    int x0 = (int)x0f + tx, y0 = (int)y0f + ty;
    float wt = mk * (tx ? lw : 1.f - lw) * (ty ? lh : 1.f - lh);
    bool valid = (x0 >= 1) & (x0 <= TW) & (y0 >= 1) & (y0 <= TH);
    int2 pr;
    pr.x = valid ? (((y0 - 1) * TW + (x0 - 1)) * TC2) : 0;
    pr.y = valid ? __float_as_int(wt) : 0;
    sp[wave][lane] = pr;
  }
  __syncthreads();

  int c0 = lane * 4;
  const short* xb = xproj + n * (TH * TW * TC2) + c0;
  float a0 = 0.f, a1 = 0.f, a2 = 0.f, a3 = 0.f;
#pragma unroll
  for (int t = 0; t < 36; ++t) {
    int2 pr = sp[wave][t];
    float wt = __int_as_float(pr.y);
    short4 v = *(const short4*)(xb + pr.x);
    a0 += wt * bf2f(v.x);
    a1 += wt * bf2f(v.y);
    a2 += wt * bf2f(v.z);
    a3 += wt * bf2f(v.w);
  }
  short4 o;
  o.x = rnbf(a0); o.y = rnbf(a1); o.z = rnbf(a2); o.w = rnbf(a3);
  *(short4*)(z + pix * TC2 + c0) = o;
}

// ---------------- output_proj (MFMA) + BN + SiLU + residual -> d_out NCHW fp32 ----------------
__global__ __launch_bounds__(256) void k_proj_out(const short* __restrict__ zb, const short* __restrict__ outwb,
                                                  const float* __restrict__ t3p,
                                                  const float* __restrict__ x, float* __restrict__ out)
{
  int px0 = blockIdx.x * 32;
  int tid = threadIdx.x;
  int wave = tid >> 6, lane = tid & 63;
  int ln = lane & 15, q = lane >> 4;
  int co0 = wave * 64;
  int pix0 = px0 + ln;

  f32x4 acc[4][2];
#pragma unroll
  for (int mt = 0; mt < 4; ++mt)
#pragma unroll
    for (int pp = 0; pp < 2; ++pp) acc[mt][pp] = (f32x4){0.f, 0.f, 0.f, 0.f};

  const short* xb0 = zb + pix0 * TC2 + q * 8;
  const short* xb1 = xb0 + 16 * TC2;
  const short* wb = outwb + (co0 + ln) * TC2 + q * 8;

  bf16x8 c0f = *(const bf16x8*)(xb0);
  bf16x8 c1f = *(const bf16x8*)(xb1);
  bf16x8 c2f = *(const bf16x8*)(wb + 0 * 16 * TC2);
  bf16x8 c3f = *(const bf16x8*)(wb + 1 * 16 * TC2);
  bf16x8 c4f = *(const bf16x8*)(wb + 2 * 16 * TC2);
  bf16x8 c5f = *(const bf16x8*)(wb + 3 * 16 * TC2);

#pragma unroll
  for (int kk = 0; kk < TC2; kk += 32) {
    bf16x8 n0f, n1f, n2f, n3f, n4f, n5f;
    const bool more = (kk + 32 < TC2);
    if (more) {
      n0f = *(const bf16x8*)(xb0 + kk + 32);
      n1f = *(const bf16x8*)(xb1 + kk + 32);
      n2f = *(const bf16x8*)(wb + 0 * 16 * TC2 + kk + 32);
      n3f = *(const bf16x8*)(wb + 1 * 16 * TC2 + kk + 32);
      n4f = *(const bf16x8*)(wb + 2 * 16 * TC2 + kk + 32);
      n5f = *(const bf16x8*)(wb + 3 * 16 * TC2 + kk + 32);
    }
    acc[0][0] = __builtin_amdgcn_mfma_f32_16x16x32_bf16(c2f, c0f, acc[0][0], 0, 0, 0);
    acc[0][1] = __builtin_amdgcn_mfma_f32_16x16x32_bf16(c2f, c1f, acc[0][1], 0, 0, 0);
    acc[1][0] = __builtin_amdgcn_mfma_f32_16x16x32_bf16(c3f, c0f, acc[1][0], 0, 0, 0);
    acc[1][1] = __builtin_amdgcn_mfma_f32_16x16x32_bf16(c3f, c1f, acc[1][1], 0, 0, 0);
    acc[2][0] = __builtin_amdgcn_mfma_f32_16x16x32_bf16(c4f, c0f, acc[2][0], 0, 0, 0);
    acc[2][1] = __builtin_amdgcn_mfma_f32_16x16x32_bf16(c4f, c1f, acc[2][1], 0, 0, 0);
    acc[3][0] = __builtin_amdgcn_mfma_f32_16x16x32_bf16(c5f, c0f, acc[3][0], 0, 0, 0);
    acc[3][1] = __builtin_amdgcn_mfma_f32_16x16x32_bf16(c5f, c1f, acc[3][1], 0, 0, 0);
    if (more) { c0f = n0f; c1f = n1f; c2f = n2f; c3f = n3f; c4f = n4f; c5f = n5f; }
  }

#pragma unroll
  for (int mt = 0; mt < 4; ++mt) {
#pragma unroll
    for (int pp = 0; pp < 2; ++pp) {
      int pix = pix0 + pp * 16;
      int n = pix / (TH * TW);
      int hw = pix - n * (TH * TW);
#pragma unroll
      for (int r = 0; r < 4; ++r) {
        int co = co0 + mt * 16 + q * 4 + r;
        int addr = (n * TC2 + co) * (TH * TW) + hw;
        out[addr] = x[addr] + siluf(acc[mt][pp][r] + t3p[co]);
      }
    }
  }
}

extern "C" void kernel_launch(void* const* d_in, const int* in_sizes, int n_in,
                              void* d_out, int out_size, void* d_ws, size_t ws_size,
                              hipStream_t stream)
{
  const float* x    = (const float*)d_in[0];
  const float* w1   = (const float*)d_in[1];
  const float* g1   = (const float*)d_in[2];
  const float* b1   = (const float*)d_in[3];
  const float* m1   = (const float*)d_in[4];
  const float* v1   = (const float*)d_in[5];
  const float* w2   = (const float*)d_in[6];
  const float* g2   = (const float*)d_in[7];
  const float* b2   = (const float*)d_in[8];
  const float* m2   = (const float*)d_in[9];
  const float* v2   = (const float*)d_in[10];
  const float* dww  = (const float*)d_in[11];
  const float* dwb  = (const float*)d_in[12];
  const float* lng  = (const float*)d_in[13];
  const float* lnb  = (const float*)d_in[14];
  const float* offw = (const float*)d_in[15];
  const float* offb = (const float*)d_in[16];
  const float* mskw = (const float*)d_in[17];
  const float* mskb = (const float*)d_in[18];
  const float* inw  = (const float*)d_in[19];
  const float* inb  = (const float*)d_in[20];
  const float* outw = (const float*)d_in[21];
  const float* outb = (const float*)d_in[22];
  const float* g3   = (const float*)d_in[23];
  const float* b3   = (const float*)d_in[24];
  const float* m3   = (const float*)d_in[25];
  const float* v3   = (const float*)d_in[26];

  float* ws  = (float*)d_ws;
  float* out = (float*)d_out;

  short* xpn    = (short*)(ws + OFF_XPAD);
  short* wbf    = (short*)(ws + OFF_WBF);
  short* w2b    = (short*)(ws + OFF_W2B);
  short* inwb   = (short*)(ws + OFF_INWB);
  short* outwb  = (short*)(ws + OFF_OUTWB);
  short* wcat16 = (short*)(ws + OFF_WCAT);
  float* y1p    = ws + OFF_Y1P;            // fp32 partials x3
  short* y1b    = (short*)(ws + OFF_Y1B);
  short* y2b    = (short*)(ws + OFF_Y2N);  // overwrites dead partials
  short* dwo    = (short*)(ws + OFF_DWN);  // overwrites dead xpad
  float* raw    = ws + OFF_RAWN;
  short* zb     = (short*)(ws + OFF_ZN);
  short* xproj  = (short*)d_out;

  hipLaunchKernelGGL(k_prep, dim3(1836), dim3(256), 0, stream,
                     w1, g1, b1, m1, v1, w2, g2, b2, m2, v2,
                     dww, offw, offb, mskw, mskb, inw, outw, outb, g3, b3, m3, v3, ws);
  hipLaunchKernelGGL(k_padx,     dim3(TN * THP * 8), dim3(256), 0, stream, x, xpn);
  hipLaunchKernelGGL(k_cv1,      dim3(600),   dim3(256), 0, stream, xpn, wbf, y1p);
  hipLaunchKernelGGL(k_y1red,    dim3(3200),  dim3(256), 0, stream, y1p, ws + OFF_T1, y1b);
  hipLaunchKernelGGL(k_cv2,      dim3(800),   dim3(256), 0, stream, y1b, w2b, ws + OFF_T2, y2b);
  hipLaunchKernelGGL(k_proj_in,  dim3(800),   dim3(256), 0, stream, y2b, inwb, inb, xproj);
  hipLaunchKernelGGL(k_dwln,     dim3(6400),  dim3(256), 0, stream, y2b, ws + OFF_DWT, dwb, lng, lnb, dwo);
  hipLaunchKernelGGL(k_offmask,  dim3(400),   dim3(256), 0, stream, dwo, wcat16, ws + OFF_WCATB, raw);
  hipLaunchKernelGGL(k_dcn,      dim3(6400),  dim3(256), 0, stream, xproj, raw, zb);
  hipLaunchKernelGGL(k_proj_out, dim3(800),   dim3(256), 0, stream, zb, outwb, ws + OFF_T3P, x, out);
}

// Round 8
// 294.406 us; speedup vs baseline: 4.2661x; 1.0504x over previous
//
#include <hip/hip_runtime.h>
#include <cmath>

// Problem dims
#define TN 4
#define TC1 256
#define TCH 128
#define TC2 256
#define TH 80
#define TW 80
#define THP 82
#define TWP 84
#define NPIX (TN*TH*TW)   // 25600

// Workspace layout (float offsets). Total = 17,356,288 floats = 69.4 MB.
#define OFF_WBF   0         // bf16 wbf[co][tap*256+ci], s1-folded: 294912 shorts
#define OFF_W2B   294912    // bf16 [co][ci=128], s2-folded: 32768 shorts
#define OFF_INWB  327680    // bf16 [co][ci=256]: 65536 shorts
#define OFF_OUTWB 393216    // bf16 [co][ci=256], s3-folded: 65536 shorts
#define OFF_DWT   458752    // fp32 [tap][c] 2304
#define OFF_WCAT  461056    // bf16 [j<32][c=256] 8192 shorts
#define OFF_WCATB 467968    // fp32 27
#define OFF_T1    468128    // 128
#define OFF_T2    468512    // 256
#define OFF_T3P   469024    // 256
#define OFF_XPAD  469504    // bf16 NHWC padded x: ends 3,997,696
#define OFF_Y1B   3997696   // bf16 y1 [25600][128]: ends 5,636,096
#define OFF_Y1P   7525888   // fp32 cv1 partials [3][25600][128]: ends 17,356,288
// aliases (liveness chain, stream order): see R6 comments — unchanged.
#define OFF_Y2N   7525888   // bf16 y2 [25600][256] (partials dead after y1red)
#define OFF_DWN   469504    // bf16 dw [25600][256] (xpad dead after cv1)
#define OFF_RAWN  10802688  // fp32 raw [25600][27]
#define OFF_ZN    11493888  // bf16 z [25600][256]

typedef __attribute__((ext_vector_type(8))) short bf16x8;
typedef __attribute__((ext_vector_type(4))) float f32x4;

__device__ __forceinline__ float siluf(float v) { return v / (1.f + expf(-v)); }
__device__ __forceinline__ short rnbf(float f) {
  unsigned u = __float_as_uint(f);
  unsigned r = (u + 0x7fffu + ((u >> 16) & 1u)) >> 16;
  return (short)r;
}
__device__ __forceinline__ float bf2f(short s) {
  return __uint_as_float(((unsigned)(unsigned short)s) << 16);
}

// ---------------- prep: weight transposes + BN constant folding ----------------
__global__ __launch_bounds__(256) void k_prep(
    const float* __restrict__ w1, const float* __restrict__ g1, const float* __restrict__ b1,
    const float* __restrict__ m1, const float* __restrict__ v1,
    const float* __restrict__ w2, const float* __restrict__ g2, const float* __restrict__ b2,
    const float* __restrict__ m2, const float* __restrict__ v2,
    const float* __restrict__ dww, const float* __restrict__ offw, const float* __restrict__ offb,
    const float* __restrict__ mskw, const float* __restrict__ mskb,
    const float* __restrict__ inw, const float* __restrict__ outw, const float* __restrict__ outb,
    const float* __restrict__ g3, const float* __restrict__ b3,
    const float* __restrict__ m3, const float* __restrict__ v3,
    float* __restrict__ ws)
{
  int i = blockIdx.x * 256 + threadIdx.x;
  if (i < 294912) {
    int co = i / 2304; int r = i - co * 2304;
    int tap = r >> 8; int ci = r & 255; int ky = tap / 3; int kx = tap - ky * 3;
    float s = g1[co] * __frsqrt_rn(v1[co] + 1e-5f);
    ((short*)(ws + OFF_WBF))[i] = rnbf(w1[((co * TC1 + ci) * 3 + ky) * 3 + kx] * s);
    return;
  }
  i -= 294912;
  if (i < 32768) {
    int co = i >> 7; int ci = i & 127;
    float s = g2[co] * __frsqrt_rn(v2[co] + 1e-5f);
    ((short*)(ws + OFF_W2B))[i] = rnbf(w2[co * TCH + ci] * s);
    return;
  }
  i -= 32768;
  if (i < 65536) {
    int co = i >> 8; int ci = i & 255;
    ((short*)(ws + OFF_INWB))[i] = rnbf(inw[co * TC2 + ci]);
    return;
  }
  i -= 65536;
  if (i < 65536) {
    int co = i >> 8; int ci = i & 255;
    float s = g3[co] * __frsqrt_rn(v3[co] + 1e-5f);
    ((short*)(ws + OFF_OUTWB))[i] = rnbf(outw[co * TC2 + ci] * s);
    return;
  }
  i -= 65536;
  if (i < 2304) { int c = i & 255; int j = i >> 8; ws[OFF_DWT + i] = dww[c * 9 + j]; return; }
  i -= 2304;
  if (i < 8192) {
    int c = i & 255; int j = i >> 8;
    float v = 0.f;
    if (j < 18) v = offw[j * 256 + c];
    else if (j < 27) v = mskw[(j - 18) * 256 + c];
    ((short*)(ws + OFF_WCAT))[i] = rnbf(v);
    return;
  }
  i -= 8192;
  if (i < 27) { ws[OFF_WCATB + i] = (i < 18) ? offb[i] : mskb[i - 18]; return; }
  i -= 27;
  if (i < 128) { float s = g1[i] / sqrtf(v1[i] + 1e-5f); ws[OFF_T1 + i] = b1[i] - m1[i] * s; return; }
  i -= 128;
  if (i < 256) { float s = g2[i] / sqrtf(v2[i] + 1e-5f); ws[OFF_T2 + i] = b2[i] - m2[i] * s; return; }
  i -= 256;
  if (i < 256) { float s = g3[i] / sqrtf(v3[i] + 1e-5f); ws[OFF_T3P + i] = outb[i] * s + b3[i] - m3[i] * s; return; }
}

// ---------------- x -> bf16 NHWC padded [4][82][84][256], zero halo ----------------
__global__ __launch_bounds__(256) void k_padx(const float* __restrict__ x, short* __restrict__ xpn)
{
  __shared__ short lds[80 * 33];
  int b = blockIdx.x;
  int cc = b & 7; int hp = (b >> 3) % THP; int n = b / (THP * 8);
  int c0 = cc * 32;
  int t = threadIdx.x;
  int h = hp - 1;
  if (h >= 0 && h < TH) {
    for (int f = t; f < 80 * 32; f += 256) {
      int ci = f / 80; int w = f - ci * 80;
      lds[w * 33 + ci] = rnbf(x[((n * TC1 + c0 + ci) * TH + h) * TW + w]);
    }
  }
  __syncthreads();
  bool hv = (h >= 0 && h < TH);
  short* op = xpn + ((n * THP + hp) * TWP) * TC2 + c0;
  for (int g = t; g < TWP * 32; g += 256) {
    int ci = g & 31; int wp = g >> 5;
    short v = 0;
    if (hv && wp >= 1 && wp <= TW) v = lds[(wp - 1) * 33 + ci];
    op[wp * TC2 + ci] = v;
  }
}

// ---------------- cv1: LDS double-buffered bf16 MFMA implicit-GEMM (unchanged from R6) ----------------
#define A_STR 40
__global__ __launch_bounds__(256) void k_cv1(const short* __restrict__ xpn, const short* __restrict__ wbf,
                                             float* __restrict__ y1p)
{
  __shared__ short As[2][128 * A_STR];
  __shared__ short Bs[2][128 * A_STR];

  int b = blockIdx.x;
  int wt = b % 5; b /= 5; int ht = b % 10; b /= 10; int n = b & 3; int ks = b >> 2;
  int w0 = wt * 16, h0 = ht * 8;
  int tap0 = ks * 3;

  int tid = threadIdx.x;
  int wave = tid >> 6, lane = tid & 63;
  int ln = lane & 15, q = lane >> 4;
  int cohalf = (wave & 1) * 64;
  int pxhalf = (wave >> 1) * 64;

  int srow = tid >> 1;
  int ssub = (tid & 1) * 16;
  int hr = srow >> 4, wc = srow & 15;
  const short* arow = wbf + srow * 2304 + ssub;
  const short* brow = xpn + ((n * THP + h0 + hr) * TWP + (w0 + wc)) * 256 + ssub;

  f32x4 acc[4][4];
#pragma unroll
  for (int i = 0; i < 4; ++i)
#pragma unroll
    for (int j = 0; j < 4; ++j) acc[i][j] = (f32x4){0.f, 0.f, 0.f, 0.f};

  bf16x8 ra0, ra1, rb0, rb1;

  auto grab = [&](int c) {
    int rt = c >> 3;
    int atap = tap0 + rt;
    int ci0 = (c & 7) * 32;
    int ky = atap / 3, kx = atap - ky * 3;
    const short* ap = arow + atap * 256 + ci0;
    const short* bp = brow + (ky * TWP + kx) * 256 + ci0;
    ra0 = *(const bf16x8*)(ap);
    ra1 = *(const bf16x8*)(ap + 8);
    rb0 = *(const bf16x8*)(bp);
    rb1 = *(const bf16x8*)(bp + 8);
  };
  auto put = [&](int buf) {
    int o = srow * A_STR + ssub;
    *(bf16x8*)(&As[buf][o])     = ra0;
    *(bf16x8*)(&As[buf][o + 8]) = ra1;
    *(bf16x8*)(&Bs[buf][o])     = rb0;
    *(bf16x8*)(&Bs[buf][o + 8]) = rb1;
  };
  auto comp = [&](int buf) {
    bf16x8 af[4], bfv[4];
#pragma unroll
    for (int mt = 0; mt < 4; ++mt)
      af[mt] = *(const bf16x8*)(&As[buf][(cohalf + mt * 16 + ln) * A_STR + q * 8]);
#pragma unroll
    for (int nt = 0; nt < 4; ++nt)
      bfv[nt] = *(const bf16x8*)(&Bs[buf][(pxhalf + nt * 16 + ln) * A_STR + q * 8]);
#pragma unroll
    for (int mt = 0; mt < 4; ++mt)
#pragma unroll
      for (int nt = 0; nt < 4; ++nt)
        acc[mt][nt] = __builtin_amdgcn_mfma_f32_16x16x32_bf16(af[mt], bfv[nt], acc[mt][nt], 0, 0, 0);
  };

  grab(0);
  put(0);
  __syncthreads();
  for (int c = 0; c < 24; ++c) {
    if (c < 23) grab(c + 1);
    comp(c & 1);
    if (c < 23) {
      __syncthreads();
      put((c + 1) & 1);
      __syncthreads();
    }
  }

  float* yp = y1p + ks * (NPIX * TCH);
#pragma unroll
  for (int mt = 0; mt < 4; ++mt)
#pragma unroll
    for (int nt = 0; nt < 4; ++nt) {
      int p = pxhalf + nt * 16 + ln;
      int pr = p >> 4, pc = p & 15;
      int pix = (n * TH + h0 + pr) * TW + (w0 + pc);
      int co = cohalf + mt * 16 + q * 4;
      *(f32x4*)(yp + pix * TCH + co) = acc[mt][nt];
    }
}

// ---------------- y1 reduce: silu(p0+p1+p2+t1) -> bf16 NHWC ----------------
__global__ __launch_bounds__(256) void k_y1red(const float* __restrict__ y1p, const float* __restrict__ t1v,
                                               short* __restrict__ y1b)
{
  int i = blockIdx.x * 256 + threadIdx.x;
  int co4 = (i & 31) * 4;
  int pix = i >> 5;
  float4 a = *(const float4*)(y1p + pix * TCH + co4);
  float4 bq = *(const float4*)(y1p + NPIX * TCH + pix * TCH + co4);
  float4 cq = *(const float4*)(y1p + 2 * NPIX * TCH + pix * TCH + co4);
  float4 t = *(const float4*)(t1v + co4);
  short4 o;
  o.x = rnbf(siluf(a.x + bq.x + cq.x + t.x));
  o.y = rnbf(siluf(a.y + bq.y + cq.y + t.y));
  o.z = rnbf(siluf(a.z + bq.z + cq.z + t.z));
  o.w = rnbf(siluf(a.w + bq.w + cq.w + t.w));
  *(short4*)(y1b + pix * TCH + co4) = o;
}

// ---------------- cv2: LDS-staged bf16 MFMA GEMM 128->256 + BN + SiLU -> y2 bf16 NHWC ----------------
// grid 400 = 200 px-tiles(128) x 2 co-halves(128); 4 waves of 64co x 64px; K=128 (4 chunks of 32)
__global__ __launch_bounds__(256) void k_cv2(const short* __restrict__ y1b, const short* __restrict__ w2b,
                                             const float* __restrict__ t2v, short* __restrict__ y2b)
{
  __shared__ short As[2][128 * A_STR];
  __shared__ short Bs[2][128 * A_STR];

  int b = blockIdx.x;
  int ch = b & 1; int pt = b >> 1;
  int co_base = ch * 128;
  int pix0 = pt * 128;

  int tid = threadIdx.x;
  int wave = tid >> 6, lane = tid & 63;
  int ln = lane & 15, q = lane >> 4;
  int coh = (wave & 1) * 64;
  int pxh = (wave >> 1) * 64;

  int srow = tid >> 1;
  int ssub = (tid & 1) * 16;
  const short* arow = w2b + (co_base + srow) * TCH + ssub;
  const short* brow = y1b + (pix0 + srow) * TCH + ssub;

  f32x4 acc[4][4];
#pragma unroll
  for (int i = 0; i < 4; ++i)
#pragma unroll
    for (int j = 0; j < 4; ++j) acc[i][j] = (f32x4){0.f, 0.f, 0.f, 0.f};

  bf16x8 ra0, ra1, rb0, rb1;
  auto grab = [&](int c) {
    const short* ap = arow + c * 32;
    const short* bp = brow + c * 32;
    ra0 = *(const bf16x8*)(ap);
    ra1 = *(const bf16x8*)(ap + 8);
    rb0 = *(const bf16x8*)(bp);
    rb1 = *(const bf16x8*)(bp + 8);
  };
  auto put = [&](int buf) {
    int o = srow * A_STR + ssub;
    *(bf16x8*)(&As[buf][o])     = ra0;
    *(bf16x8*)(&As[buf][o + 8]) = ra1;
    *(bf16x8*)(&Bs[buf][o])     = rb0;
    *(bf16x8*)(&Bs[buf][o + 8]) = rb1;
  };
  auto comp = [&](int buf) {
    bf16x8 af[4], bfv[4];
#pragma unroll
    for (int mt = 0; mt < 4; ++mt)
      af[mt] = *(const bf16x8*)(&As[buf][(coh + mt * 16 + ln) * A_STR + q * 8]);
#pragma unroll
    for (int nt = 0; nt < 4; ++nt)
      bfv[nt] = *(const bf16x8*)(&Bs[buf][(pxh + nt * 16 + ln) * A_STR + q * 8]);
#pragma unroll
    for (int mt = 0; mt < 4; ++mt)
#pragma unroll
      for (int nt = 0; nt < 4; ++nt)
        acc[mt][nt] = __builtin_amdgcn_mfma_f32_16x16x32_bf16(af[mt], bfv[nt], acc[mt][nt], 0, 0, 0);
  };

  const int NCH = TCH / 32;   // 4
  grab(0);
  put(0);
  __syncthreads();
  for (int c = 0; c < NCH; ++c) {
    if (c < NCH - 1) grab(c + 1);
    comp(c & 1);
    if (c < NCH - 1) {
      __syncthreads();
      put((c + 1) & 1);
      __syncthreads();
    }
  }

#pragma unroll
  for (int mt = 0; mt < 4; ++mt) {
    int co = co_base + coh + mt * 16 + q * 4;
    float t0 = t2v[co], t1 = t2v[co + 1], t2 = t2v[co + 2], t3 = t2v[co + 3];
#pragma unroll
    for (int nt = 0; nt < 4; ++nt) {
      int pix = pix0 + pxh + nt * 16 + ln;
      short4 p;
      p.x = rnbf(siluf(acc[mt][nt][0] + t0));
      p.y = rnbf(siluf(acc[mt][nt][1] + t1));
      p.z = rnbf(siluf(acc[mt][nt][2] + t2));
      p.w = rnbf(siluf(acc[mt][nt][3] + t3));
      *(short4*)(y2b + pix * TC2 + co) = p;
    }
  }
}

// ---------------- input_proj: LDS-staged bf16 MFMA GEMM 256->256 + bias -> xproj ----------------
__global__ __launch_bounds__(256) void k_proj_in(const short* __restrict__ y2b, const short* __restrict__ inwb,
                                                 const float* __restrict__ inb, short* __restrict__ xproj)
{
  __shared__ short As[2][128 * A_STR];
  __shared__ short Bs[2][128 * A_STR];

  int b = blockIdx.x;
  int ch = b & 1; int pt = b >> 1;
  int co_base = ch * 128;
  int pix0 = pt * 128;

  int tid = threadIdx.x;
  int wave = tid >> 6, lane = tid & 63;
  int ln = lane & 15, q = lane >> 4;
  int coh = (wave & 1) * 64;
  int pxh = (wave >> 1) * 64;

  int srow = tid >> 1;
  int ssub = (tid & 1) * 16;
  const short* arow = inwb + (co_base + srow) * TC2 + ssub;
  const short* brow = y2b + (pix0 + srow) * TC2 + ssub;

  f32x4 acc[4][4];
#pragma unroll
  for (int i = 0; i < 4; ++i)
#pragma unroll
    for (int j = 0; j < 4; ++j) acc[i][j] = (f32x4){0.f, 0.f, 0.f, 0.f};

  bf16x8 ra0, ra1, rb0, rb1;
  auto grab = [&](int c) {
    const short* ap = arow + c * 32;
    const short* bp = brow + c * 32;
    ra0 = *(const bf16x8*)(ap);
    ra1 = *(const bf16x8*)(ap + 8);
    rb0 = *(const bf16x8*)(bp);
    rb1 = *(const bf16x8*)(bp + 8);
  };
  auto put = [&](int buf) {
    int o = srow * A_STR + ssub;
    *(bf16x8*)(&As[buf][o])     = ra0;
    *(bf16x8*)(&As[buf][o + 8]) = ra1;
    *(bf16x8*)(&Bs[buf][o])     = rb0;
    *(bf16x8*)(&Bs[buf][o + 8]) = rb1;
  };
  auto comp = [&](int buf) {
    bf16x8 af[4], bfv[4];
#pragma unroll
    for (int mt = 0; mt < 4; ++mt)
      af[mt] = *(const bf16x8*)(&As[buf][(coh + mt * 16 + ln) * A_STR + q * 8]);
#pragma unroll
    for (int nt = 0; nt < 4; ++nt)
      bfv[nt] = *(const bf16x8*)(&Bs[buf][(pxh + nt * 16 + ln) * A_STR + q * 8]);
#pragma unroll
    for (int mt = 0; mt < 4; ++mt)
#pragma unroll
      for (int nt = 0; nt < 4; ++nt)
        acc[mt][nt] = __builtin_amdgcn_mfma_f32_16x16x32_bf16(af[mt], bfv[nt], acc[mt][nt], 0, 0, 0);
  };

  const int NCH = TC2 / 32;   // 8
  grab(0);
  put(0);
  __syncthreads();
  for (int c = 0; c < NCH; ++c) {
    if (c < NCH - 1) grab(c + 1);
    comp(c & 1);
    if (c < NCH - 1) {
      __syncthreads();
      put((c + 1) & 1);
      __syncthreads();
    }
  }

#pragma unroll
  for (int mt = 0; mt < 4; ++mt) {
    int co = co_base + coh + mt * 16 + q * 4;
    float b0 = inb[co], b1 = inb[co + 1], b2 = inb[co + 2], b3 = inb[co + 3];
#pragma unroll
    for (int nt = 0; nt < 4; ++nt) {
      int pix = pix0 + pxh + nt * 16 + ln;
      short4 p;
      p.x = rnbf(acc[mt][nt][0] + b0);
      p.y = rnbf(acc[mt][nt][1] + b1);
      p.z = rnbf(acc[mt][nt][2] + b2);
      p.w = rnbf(acc[mt][nt][3] + b3);
      *(short4*)(xproj + pix * TC2 + co) = p;
    }
  }
}

// ---------------- depthwise 3x3 + bias + LayerNorm + GELU: wave-per-pixel -> bf16 ----------------
__global__ __launch_bounds__(256) void k_dwln(const short* __restrict__ y2b, const float* __restrict__ dwt,
                                              const float* __restrict__ dwb, const float* __restrict__ lng,
                                              const float* __restrict__ lnb, short* __restrict__ dwo)
{
  int tid = threadIdx.x;
  int wave = tid >> 6, lane = tid & 63;
  int pix = blockIdx.x * 4 + wave;
  int w = pix % TW; int h = (pix / TW) % TH; int n = pix / (TH * TW);
  int c0 = lane * 4;

  float4 bb = *(const float4*)(dwb + c0);
  float v0 = bb.x, v1 = bb.y, v2 = bb.z, v3 = bb.w;
#pragma unroll
  for (int dy = 0; dy < 3; ++dy) {
    int hh = h + dy - 1;
    if (hh < 0 || hh >= TH) continue;
#pragma unroll
    for (int dx = 0; dx < 3; ++dx) {
      int ww = w + dx - 1;
      if (ww < 0 || ww >= TW) continue;
      short4 yv = *(const short4*)(y2b + ((n * TH + hh) * TW + ww) * TC2 + c0);
      float4 wv = *(const float4*)(dwt + (dy * 3 + dx) * TC2 + c0);
      v0 += bf2f(yv.x) * wv.x;
      v1 += bf2f(yv.y) * wv.y;
      v2 += bf2f(yv.z) * wv.z;
      v3 += bf2f(yv.w) * wv.w;
    }
  }
  float sv = v0 + v1 + v2 + v3;
  float sq = v0 * v0 + v1 * v1 + v2 * v2 + v3 * v3;
#pragma unroll
  for (int o = 32; o > 0; o >>= 1) { sv += __shfl_xor(sv, o); sq += __shfl_xor(sq, o); }
  float mu = sv * (1.f / 256.f);
  float var = sq * (1.f / 256.f) - mu * mu;
  float rs = 1.f / sqrtf(var + 1e-6f);
  float4 gv = *(const float4*)(lng + c0);
  float4 bv = *(const float4*)(lnb + c0);
  float n0 = (v0 - mu) * rs * gv.x + bv.x;
  float n1 = (v1 - mu) * rs * gv.y + bv.y;
  float n2 = (v2 - mu) * rs * gv.z + bv.z;
  float n3 = (v3 - mu) * rs * gv.w + bv.w;
  const float is2 = 0.70710678118654752f;
  short4 o4;
  o4.x = rnbf(0.5f * n0 * (1.f + erff(n0 * is2)));
  o4.y = rnbf(0.5f * n1 * (1.f + erff(n1 * is2)));
  o4.z = rnbf(0.5f * n2 * (1.f + erff(n2 * is2)));
  o4.w = rnbf(0.5f * n3 * (1.f + erff(n3 * is2)));
  *(short4*)(dwo + pix * TC2 + c0) = o4;
}

// ---------------- offset/mask logits via MFMA: raw[pix][27] = dw @ wcat^T + b ----------------
__global__ __launch_bounds__(256) void k_offmask(const short* __restrict__ dwo, const short* __restrict__ wcatb16,
                                                 const float* __restrict__ wcatb, float* __restrict__ raw)
{
  int tid = threadIdx.x;
  int wave = tid >> 6, lane = tid & 63;
  int ln = lane & 15, q = lane >> 4;
  int pix0 = blockIdx.x * 64 + wave * 16;

  f32x4 acc0 = {0.f, 0.f, 0.f, 0.f};
  f32x4 acc1 = acc0;

  const short* a0p = wcatb16 + ln * 256 + q * 8;
  const short* a1p = wcatb16 + (16 + ln) * 256 + q * 8;
  const short* bp  = dwo + (pix0 + ln) * 256 + q * 8;
#pragma unroll
  for (int kk = 0; kk < 256; kk += 32) {
    bf16x8 bf = *(const bf16x8*)(bp + kk);
    bf16x8 a0 = *(const bf16x8*)(a0p + kk);
    bf16x8 a1 = *(const bf16x8*)(a1p + kk);
    acc0 = __builtin_amdgcn_mfma_f32_16x16x32_bf16(a0, bf, acc0, 0, 0, 0);
    acc1 = __builtin_amdgcn_mfma_f32_16x16x32_bf16(a1, bf, acc1, 0, 0, 0);
  }

  int pix = pix0 + ln;
#pragma unroll
  for (int r = 0; r < 4; ++r) {
    int j0 = q * 4 + r;
    raw[pix * 27 + j0] = acc0[r] + wcatb[j0];
    int j1 = 16 + j0;
    if (j1 < 27) raw[pix * 27 + j1] = acc1[r] + wcatb[j1];
  }
}

// ---------------- DCN core: wave-per-pixel, LDS-precomputed taps ----------------
__global__ __launch_bounds__(256) void k_dcn(const short* __restrict__ xproj, const float* __restrict__ raw,
                                             short* __restrict__ z)
{
  __shared__ int2 sp[4][36];
  int tid = threadIdx.x;
  int wave = tid >> 6, lane = tid & 63;
  int pix = blockIdx.x * 4 + wave;
  int w = pix % TW; int h = (pix / TW) % TH; int n = pix / (TH * TW);
  const float* r = raw + pix * 27;

  if (lane < 36) {
    int k = lane >> 2, tap = lane & 3;
    int tx = tap & 1, ty = tap >> 1;
    float mx = r[18];
#pragma unroll
    for (int kk = 1; kk < 9; ++kk) mx = fmaxf(mx, r[18 + kk]);
    float sum = 0.f, ek = 0.f;
#pragma unroll
    for (int kk = 0; kk < 9; ++kk) {
      float ee = expf(r[18 + kk] - mx);
      sum += ee;
      if (kk == k) ek = ee;
    }
    float mk = ek / sum;
    float px = (float)(w + k / 3) + r[2 * k];
    float py = (float)(h + k % 3) + r[2 * k + 1];
    float x0f = floorf(px), y0f = floorf(py);
    float lw = px - x0f, lh = py - y0f;
    int x0 = (int)x0f + tx, y0 = (int)y0f + ty;
    float wt = mk * (tx ? lw : 1.f - lw) * (ty ? lh : 1.f - lh);
    bool valid = (x0 >= 1) & (x0 <= TW) & (y0 >= 1) & (y0 <= TH);
    int2 pr;
    pr.x = valid ? (((y0 - 1) * TW + (x0 - 1)) * TC2) : 0;
    pr.y = valid ? __float_as_int(wt) : 0;
    sp[wave][lane] = pr;
  }
  __syncthreads();

  int c0 = lane * 4;
  const short* xb = xproj + n * (TH * TW * TC2) + c0;
  float a0 = 0.f, a1 = 0.f, a2 = 0.f, a3 = 0.f;
#pragma unroll
  for (int t = 0; t < 36; ++t) {
    int2 pr = sp[wave][t];
    float wt = __int_as_float(pr.y);
    short4 v = *(const short4*)(xb + pr.x);
    a0 += wt * bf2f(v.x);
    a1 += wt * bf2f(v.y);
    a2 += wt * bf2f(v.z);
    a3 += wt * bf2f(v.w);
  }
  short4 o;
  o.x = rnbf(a0); o.y = rnbf(a1); o.z = rnbf(a2); o.w = rnbf(a3);
  *(short4*)(z + pix * TC2 + c0) = o;
}

// ---------------- output_proj: LDS-staged MFMA + BN + SiLU + residual -> d_out NCHW fp32 ----------------
__global__ __launch_bounds__(256) void k_proj_out(const short* __restrict__ zb, const short* __restrict__ outwb,
                                                  const float* __restrict__ t3p,
                                                  const float* __restrict__ x, float* __restrict__ out)
{
  __shared__ short As[2][128 * A_STR];
  __shared__ short Bs[2][128 * A_STR];

  int b = blockIdx.x;
  int ch = b & 1; int pt = b >> 1;
  int co_base = ch * 128;
  int pix0 = pt * 128;

  int tid = threadIdx.x;
  int wave = tid >> 6, lane = tid & 63;
  int ln = lane & 15, q = lane >> 4;
  int coh = (wave & 1) * 64;
  int pxh = (wave >> 1) * 64;

  int srow = tid >> 1;
  int ssub = (tid & 1) * 16;
  const short* arow = outwb + (co_base + srow) * TC2 + ssub;
  const short* brow = zb + (pix0 + srow) * TC2 + ssub;

  f32x4 acc[4][4];
#pragma unroll
  for (int i = 0; i < 4; ++i)
#pragma unroll
    for (int j = 0; j < 4; ++j) acc[i][j] = (f32x4){0.f, 0.f, 0.f, 0.f};

  bf16x8 ra0, ra1, rb0, rb1;
  auto grab = [&](int c) {
    const short* ap = arow + c * 32;
    const short* bp = brow + c * 32;
    ra0 = *(const bf16x8*)(ap);
    ra1 = *(const bf16x8*)(ap + 8);
    rb0 = *(const bf16x8*)(bp);
    rb1 = *(const bf16x8*)(bp + 8);
  };
  auto put = [&](int buf) {
    int o = srow * A_STR + ssub;
    *(bf16x8*)(&As[buf][o])     = ra0;
    *(bf16x8*)(&As[buf][o + 8]) = ra1;
    *(bf16x8*)(&Bs[buf][o])     = rb0;
    *(bf16x8*)(&Bs[buf][o + 8]) = rb1;
  };
  auto comp = [&](int buf) {
    bf16x8 af[4], bfv[4];
#pragma unroll
    for (int mt = 0; mt < 4; ++mt)
      af[mt] = *(const bf16x8*)(&As[buf][(coh + mt * 16 + ln) * A_STR + q * 8]);
#pragma unroll
    for (int nt = 0; nt < 4; ++nt)
      bfv[nt] = *(const bf16x8*)(&Bs[buf][(pxh + nt * 16 + ln) * A_STR + q * 8]);
#pragma unroll
    for (int mt = 0; mt < 4; ++mt)
#pragma unroll
      for (int nt = 0; nt < 4; ++nt)
        acc[mt][nt] = __builtin_amdgcn_mfma_f32_16x16x32_bf16(af[mt], bfv[nt], acc[mt][nt], 0, 0, 0);
  };

  const int NCH = TC2 / 32;   // 8
  grab(0);
  put(0);
  __syncthreads();
  for (int c = 0; c < NCH; ++c) {
    if (c < NCH - 1) grab(c + 1);
    comp(c & 1);
    if (c < NCH - 1) {
      __syncthreads();
      put((c + 1) & 1);
      __syncthreads();
    }
  }

#pragma unroll
  for (int mt = 0; mt < 4; ++mt) {
    int co = co_base + coh + mt * 16 + q * 4;
#pragma unroll
    for (int nt = 0; nt < 4; ++nt) {
      int pix = pix0 + pxh + nt * 16 + ln;
      int n = pix / (TH * TW);
      int hw = pix - n * (TH * TW);
#pragma unroll
      for (int r = 0; r < 4; ++r) {
        int addr = (n * TC2 + co + r) * (TH * TW) + hw;
        out[addr] = x[addr] + siluf(acc[mt][nt][r] + t3p[co + r]);
      }
    }
  }
}

extern "C" void kernel_launch(void* const* d_in, const int* in_sizes, int n_in,
                              void* d_out, int out_size, void* d_ws, size_t ws_size,
                              hipStream_t stream)
{
  const float* x    = (const float*)d_in[0];
  const float* w1   = (const float*)d_in[1];
  const float* g1   = (const float*)d_in[2];
  const float* b1   = (const float*)d_in[3];
  const float* m1   = (const float*)d_in[4];
  const float* v1   = (const float*)d_in[5];
  const float* w2   = (const float*)d_in[6];
  const float* g2   = (const float*)d_in[7];
  const float* b2   = (const float*)d_in[8];
  const float* m2   = (const float*)d_in[9];
  const float* v2   = (const float*)d_in[10];
  const float* dww  = (const float*)d_in[11];
  const float* dwb  = (const float*)d_in[12];
  const float* lng  = (const float*)d_in[13];
  const float* lnb  = (const float*)d_in[14];
  const float* offw = (const float*)d_in[15];
  const float* offb = (const float*)d_in[16];
  const float* mskw = (const float*)d_in[17];
  const float* mskb = (const float*)d_in[18];
  const float* inw  = (const float*)d_in[19];
  const float* inb  = (const float*)d_in[20];
  const float* outw = (const float*)d_in[21];
  const float* outb = (const float*)d_in[22];
  const float* g3   = (const float*)d_in[23];
  const float* b3   = (const float*)d_in[24];
  const float* m3   = (const float*)d_in[25];
  const float* v3   = (const float*)d_in[26];

  float* ws  = (float*)d_ws;
  float* out = (float*)d_out;

  short* xpn    = (short*)(ws + OFF_XPAD);
  short* wbf    = (short*)(ws + OFF_WBF);
  short* w2b    = (short*)(ws + OFF_W2B);
  short* inwb   = (short*)(ws + OFF_INWB);
  short* outwb  = (short*)(ws + OFF_OUTWB);
  short* wcat16 = (short*)(ws + OFF_WCAT);
  float* y1p    = ws + OFF_Y1P;
  short* y1b    = (short*)(ws + OFF_Y1B);
  short* y2b    = (short*)(ws + OFF_Y2N);
  short* dwo    = (short*)(ws + OFF_DWN);
  float* raw    = ws + OFF_RAWN;
  short* zb     = (short*)(ws + OFF_ZN);
  short* xproj  = (short*)d_out;

  hipLaunchKernelGGL(k_prep, dim3(1836), dim3(256), 0, stream,
                     w1, g1, b1, m1, v1, w2, g2, b2, m2, v2,
                     dww, offw, offb, mskw, mskb, inw, outw, outb, g3, b3, m3, v3, ws);
  hipLaunchKernelGGL(k_padx,     dim3(TN * THP * 8), dim3(256), 0, stream, x, xpn);
  hipLaunchKernelGGL(k_cv1,      dim3(600),   dim3(256), 0, stream, xpn, wbf, y1p);
  hipLaunchKernelGGL(k_y1red,    dim3(3200),  dim3(256), 0, stream, y1p, ws + OFF_T1, y1b);
  hipLaunchKernelGGL(k_cv2,      dim3(400),   dim3(256), 0, stream, y1b, w2b, ws + OFF_T2, y2b);
  hipLaunchKernelGGL(k_proj_in,  dim3(400),   dim3(256), 0, stream, y2b, inwb, inb, xproj);
  hipLaunchKernelGGL(k_dwln,     dim3(6400),  dim3(256), 0, stream, y2b, ws + OFF_DWT, dwb, lng, lnb, dwo);
  hipLaunchKernelGGL(k_offmask,  dim3(400),   dim3(256), 0, stream, dwo, wcat16, ws + OFF_WCATB, raw);
  hipLaunchKernelGGL(k_dcn,      dim3(6400),  dim3(256), 0, stream, xproj, raw, zb);
  hipLaunchKernelGGL(k_proj_out, dim3(400),   dim3(256), 0, stream, zb, outwb, ws + OFF_T3P, x, out);
}

// Round 9
// 273.329 us; speedup vs baseline: 4.5951x; 1.0771x over previous
//
#include <hip/hip_runtime.h>
#include <cmath>

// Problem dims
#define TN 4
#define TC1 256
#define TCH 128
#define TC2 256
#define TH 80
#define TW 80
#define THP 82
#define TWP 84
#define NPIX (TN*TH*TW)   // 25600

// Workspace layout (float offsets). Total = 17,356,288 floats = 69.4 MB.
#define OFF_WBF   0         // bf16 wbf[co][tap*256+ci], s1-folded: 294912 shorts
#define OFF_W2B   294912    // bf16 [co][ci=128], s2-folded: 32768 shorts
#define OFF_INWB  327680    // bf16 [co][ci=256]: 65536 shorts
#define OFF_OUTWB 393216    // bf16 [co][ci=256], s3-folded: 65536 shorts
#define OFF_DWT   458752    // fp32 [tap][c] 2304
#define OFF_WCAT  461056    // bf16 [j<32][c=256] 8192 shorts
#define OFF_WCATB 467968    // fp32 27
#define OFF_T1    468128    // 128
#define OFF_T2    468512    // 256
#define OFF_T3P   469024    // 256
#define OFF_XPAD  469504    // bf16 NHWC padded x: ends 3,997,696
#define OFF_Y1B   3997696   // bf16 y1 [25600][128]: ends 5,636,096
#define OFF_Y1P   7525888   // fp32 cv1 partials [3][25600][128]: ends 17,356,288
// aliases (liveness chain, stream order) — unchanged from R6/R7:
#define OFF_Y2N   7525888   // bf16 y2 [25600][256] (partials dead after y1red)
#define OFF_DWN   469504    // bf16 dw [25600][256] (xpad dead after cv1)
#define OFF_RAWN  10802688  // fp32 raw [25600][27]
#define OFF_ZN    11493888  // bf16 z [25600][256]

typedef __attribute__((ext_vector_type(8))) short bf16x8;
typedef __attribute__((ext_vector_type(4))) float f32x4;

__device__ __forceinline__ float siluf(float v) { return v / (1.f + expf(-v)); }
__device__ __forceinline__ short rnbf(float f) {
  unsigned u = __float_as_uint(f);
  unsigned r = (u + 0x7fffu + ((u >> 16) & 1u)) >> 16;
  return (short)r;
}
__device__ __forceinline__ float bf2f(short s) {
  return __uint_as_float(((unsigned)(unsigned short)s) << 16);
}

// ---------------- prep: weight transposes + BN constant folding ----------------
__global__ __launch_bounds__(256) void k_prep(
    const float* __restrict__ w1, const float* __restrict__ g1, const float* __restrict__ b1,
    const float* __restrict__ m1, const float* __restrict__ v1,
    const float* __restrict__ w2, const float* __restrict__ g2, const float* __restrict__ b2,
    const float* __restrict__ m2, const float* __restrict__ v2,
    const float* __restrict__ dww, const float* __restrict__ offw, const float* __restrict__ offb,
    const float* __restrict__ mskw, const float* __restrict__ mskb,
    const float* __restrict__ inw, const float* __restrict__ outw, const float* __restrict__ outb,
    const float* __restrict__ g3, const float* __restrict__ b3,
    const float* __restrict__ m3, const float* __restrict__ v3,
    float* __restrict__ ws)
{
  int i = blockIdx.x * 256 + threadIdx.x;
  if (i < 294912) {
    int co = i / 2304; int r = i - co * 2304;
    int tap = r >> 8; int ci = r & 255; int ky = tap / 3; int kx = tap - ky * 3;
    float s = g1[co] * __frsqrt_rn(v1[co] + 1e-5f);
    ((short*)(ws + OFF_WBF))[i] = rnbf(w1[((co * TC1 + ci) * 3 + ky) * 3 + kx] * s);
    return;
  }
  i -= 294912;
  if (i < 32768) {
    int co = i >> 7; int ci = i & 127;
    float s = g2[co] * __frsqrt_rn(v2[co] + 1e-5f);
    ((short*)(ws + OFF_W2B))[i] = rnbf(w2[co * TCH + ci] * s);
    return;
  }
  i -= 32768;
  if (i < 65536) {
    int co = i >> 8; int ci = i & 255;
    ((short*)(ws + OFF_INWB))[i] = rnbf(inw[co * TC2 + ci]);
    return;
  }
  i -= 65536;
  if (i < 65536) {
    int co = i >> 8; int ci = i & 255;
    float s = g3[co] * __frsqrt_rn(v3[co] + 1e-5f);
    ((short*)(ws + OFF_OUTWB))[i] = rnbf(outw[co * TC2 + ci] * s);
    return;
  }
  i -= 65536;
  if (i < 2304) { int c = i & 255; int j = i >> 8; ws[OFF_DWT + i] = dww[c * 9 + j]; return; }
  i -= 2304;
  if (i < 8192) {
    int c = i & 255; int j = i >> 8;
    float v = 0.f;
    if (j < 18) v = offw[j * 256 + c];
    else if (j < 27) v = mskw[(j - 18) * 256 + c];
    ((short*)(ws + OFF_WCAT))[i] = rnbf(v);
    return;
  }
  i -= 8192;
  if (i < 27) { ws[OFF_WCATB + i] = (i < 18) ? offb[i] : mskb[i - 18]; return; }
  i -= 27;
  if (i < 128) { float s = g1[i] / sqrtf(v1[i] + 1e-5f); ws[OFF_T1 + i] = b1[i] - m1[i] * s; return; }
  i -= 128;
  if (i < 256) { float s = g2[i] / sqrtf(v2[i] + 1e-5f); ws[OFF_T2 + i] = b2[i] - m2[i] * s; return; }
  i -= 256;
  if (i < 256) { float s = g3[i] / sqrtf(v3[i] + 1e-5f); ws[OFF_T3P + i] = outb[i] * s + b3[i] - m3[i] * s; return; }
}

// ---------------- x -> bf16 NHWC padded [4][82][84][256], zero halo (vectorized) ----------------
// grid = 4n * 82hp * 8cc; float4 reads, short4 LDS (stride 40 shorts = 8B-aligned), short4 stores
__global__ __launch_bounds__(256) void k_padx(const float* __restrict__ x, short* __restrict__ xpn)
{
  __shared__ short lds[80 * 40];
  int b = blockIdx.x;
  int cc = b & 7; int hp = (b >> 3) % THP; int n = b / (THP * 8);
  int c0 = cc * 32;
  int t = threadIdx.x;
  int h = hp - 1;
  bool hv = (h >= 0 && h < TH);
  if (hv) {
    for (int f = t; f < 640; f += 256) {          // 32 ci x 20 float4
      int ci = f / 20; int w4 = (f - ci * 20) * 4;
      float4 xv = *(const float4*)(x + ((n * TC1 + c0 + ci) * TH + h) * TW + w4);
      lds[(w4 + 0) * 40 + ci] = rnbf(xv.x);
      lds[(w4 + 1) * 40 + ci] = rnbf(xv.y);
      lds[(w4 + 2) * 40 + ci] = rnbf(xv.z);
      lds[(w4 + 3) * 40 + ci] = rnbf(xv.w);
    }
  }
  __syncthreads();
  short* op = xpn + ((n * THP + hp) * TWP) * TC2 + c0;
  for (int g = t; g < 672; g += 256) {            // 84 wp x 8 ci4
    int ci4 = (g & 7) * 4; int wp = g >> 3;
    short4 v = {0, 0, 0, 0};
    if (hv && wp >= 1 && wp <= TW) v = *(const short4*)(&lds[(wp - 1) * 40 + ci4]);
    *(short4*)(op + wp * TC2 + ci4) = v;
  }
}

// ---------------- cv1: LDS double-buffered bf16 MFMA implicit-GEMM (unchanged) ----------------
#define A_STR 40
__global__ __launch_bounds__(256) void k_cv1(const short* __restrict__ xpn, const short* __restrict__ wbf,
                                             float* __restrict__ y1p)
{
  __shared__ short As[2][128 * A_STR];
  __shared__ short Bs[2][128 * A_STR];

  int b = blockIdx.x;
  int wt = b % 5; b /= 5; int ht = b % 10; b /= 10; int n = b & 3; int ks = b >> 2;
  int w0 = wt * 16, h0 = ht * 8;
  int tap0 = ks * 3;

  int tid = threadIdx.x;
  int wave = tid >> 6, lane = tid & 63;
  int ln = lane & 15, q = lane >> 4;
  int cohalf = (wave & 1) * 64;
  int pxhalf = (wave >> 1) * 64;

  int srow = tid >> 1;
  int ssub = (tid & 1) * 16;
  int hr = srow >> 4, wc = srow & 15;
  const short* arow = wbf + srow * 2304 + ssub;
  const short* brow = xpn + ((n * THP + h0 + hr) * TWP + (w0 + wc)) * 256 + ssub;

  f32x4 acc[4][4];
#pragma unroll
  for (int i = 0; i < 4; ++i)
#pragma unroll
    for (int j = 0; j < 4; ++j) acc[i][j] = (f32x4){0.f, 0.f, 0.f, 0.f};

  bf16x8 ra0, ra1, rb0, rb1;

  auto grab = [&](int c) {
    int rt = c >> 3;
    int atap = tap0 + rt;
    int ci0 = (c & 7) * 32;
    int ky = atap / 3, kx = atap - ky * 3;
    const short* ap = arow + atap * 256 + ci0;
    const short* bp = brow + (ky * TWP + kx) * 256 + ci0;
    ra0 = *(const bf16x8*)(ap);
    ra1 = *(const bf16x8*)(ap + 8);
    rb0 = *(const bf16x8*)(bp);
    rb1 = *(const bf16x8*)(bp + 8);
  };
  auto put = [&](int buf) {
    int o = srow * A_STR + ssub;
    *(bf16x8*)(&As[buf][o])     = ra0;
    *(bf16x8*)(&As[buf][o + 8]) = ra1;
    *(bf16x8*)(&Bs[buf][o])     = rb0;
    *(bf16x8*)(&Bs[buf][o + 8]) = rb1;
  };
  auto comp = [&](int buf) {
    bf16x8 af[4], bfv[4];
#pragma unroll
    for (int mt = 0; mt < 4; ++mt)
      af[mt] = *(const bf16x8*)(&As[buf][(cohalf + mt * 16 + ln) * A_STR + q * 8]);
#pragma unroll
    for (int nt = 0; nt < 4; ++nt)
      bfv[nt] = *(const bf16x8*)(&Bs[buf][(pxhalf + nt * 16 + ln) * A_STR + q * 8]);
#pragma unroll
    for (int mt = 0; mt < 4; ++mt)
#pragma unroll
      for (int nt = 0; nt < 4; ++nt)
        acc[mt][nt] = __builtin_amdgcn_mfma_f32_16x16x32_bf16(af[mt], bfv[nt], acc[mt][nt], 0, 0, 0);
  };

  grab(0);
  put(0);
  __syncthreads();
  for (int c = 0; c < 24; ++c) {
    if (c < 23) grab(c + 1);
    comp(c & 1);
    if (c < 23) {
      __syncthreads();
      put((c + 1) & 1);
      __syncthreads();
    }
  }

  float* yp = y1p + ks * (NPIX * TCH);
#pragma unroll
  for (int mt = 0; mt < 4; ++mt)
#pragma unroll
    for (int nt = 0; nt < 4; ++nt) {
      int p = pxhalf + nt * 16 + ln;
      int pr = p >> 4, pc = p & 15;
      int pix = (n * TH + h0 + pr) * TW + (w0 + pc);
      int co = cohalf + mt * 16 + q * 4;
      *(f32x4*)(yp + pix * TCH + co) = acc[mt][nt];
    }
}

// ---------------- y1 reduce: silu(p0+p1+p2+t1) -> bf16 NHWC ----------------
__global__ __launch_bounds__(256) void k_y1red(const float* __restrict__ y1p, const float* __restrict__ t1v,
                                               short* __restrict__ y1b)
{
  int i = blockIdx.x * 256 + threadIdx.x;
  int co4 = (i & 31) * 4;
  int pix = i >> 5;
  float4 a = *(const float4*)(y1p + pix * TCH + co4);
  float4 bq = *(const float4*)(y1p + NPIX * TCH + pix * TCH + co4);
  float4 cq = *(const float4*)(y1p + 2 * NPIX * TCH + pix * TCH + co4);
  float4 t = *(const float4*)(t1v + co4);
  short4 o;
  o.x = rnbf(siluf(a.x + bq.x + cq.x + t.x));
  o.y = rnbf(siluf(a.y + bq.y + cq.y + t.y));
  o.z = rnbf(siluf(a.z + bq.z + cq.z + t.z));
  o.w = rnbf(siluf(a.w + bq.w + cq.w + t.w));
  *(short4*)(y1b + pix * TCH + co4) = o;
}

// ---------------- cv2: LDS-staged bf16 MFMA GEMM 128->256 + BN + SiLU (unchanged) ----------------
__global__ __launch_bounds__(256) void k_cv2(const short* __restrict__ y1b, const short* __restrict__ w2b,
                                             const float* __restrict__ t2v, short* __restrict__ y2b)
{
  __shared__ short As[2][128 * A_STR];
  __shared__ short Bs[2][128 * A_STR];

  int b = blockIdx.x;
  int ch = b & 1; int pt = b >> 1;
  int co_base = ch * 128;
  int pix0 = pt * 128;

  int tid = threadIdx.x;
  int wave = tid >> 6, lane = tid & 63;
  int ln = lane & 15, q = lane >> 4;
  int coh = (wave & 1) * 64;
  int pxh = (wave >> 1) * 64;

  int srow = tid >> 1;
  int ssub = (tid & 1) * 16;
  const short* arow = w2b + (co_base + srow) * TCH + ssub;
  const short* brow = y1b + (pix0 + srow) * TCH + ssub;

  f32x4 acc[4][4];
#pragma unroll
  for (int i = 0; i < 4; ++i)
#pragma unroll
    for (int j = 0; j < 4; ++j) acc[i][j] = (f32x4){0.f, 0.f, 0.f, 0.f};

  bf16x8 ra0, ra1, rb0, rb1;
  auto grab = [&](int c) {
    const short* ap = arow + c * 32;
    const short* bp = brow + c * 32;
    ra0 = *(const bf16x8*)(ap);
    ra1 = *(const bf16x8*)(ap + 8);
    rb0 = *(const bf16x8*)(bp);
    rb1 = *(const bf16x8*)(bp + 8);
  };
  auto put = [&](int buf) {
    int o = srow * A_STR + ssub;
    *(bf16x8*)(&As[buf][o])     = ra0;
    *(bf16x8*)(&As[buf][o + 8]) = ra1;
    *(bf16x8*)(&Bs[buf][o])     = rb0;
    *(bf16x8*)(&Bs[buf][o + 8]) = rb1;
  };
  auto comp = [&](int buf) {
    bf16x8 af[4], bfv[4];
#pragma unroll
    for (int mt = 0; mt < 4; ++mt)
      af[mt] = *(const bf16x8*)(&As[buf][(coh + mt * 16 + ln) * A_STR + q * 8]);
#pragma unroll
    for (int nt = 0; nt < 4; ++nt)
      bfv[nt] = *(const bf16x8*)(&Bs[buf][(pxh + nt * 16 + ln) * A_STR + q * 8]);
#pragma unroll
    for (int mt = 0; mt < 4; ++mt)
#pragma unroll
      for (int nt = 0; nt < 4; ++nt)
        acc[mt][nt] = __builtin_amdgcn_mfma_f32_16x16x32_bf16(af[mt], bfv[nt], acc[mt][nt], 0, 0, 0);
  };

  const int NCH = TCH / 32;
  grab(0);
  put(0);
  __syncthreads();
  for (int c = 0; c < NCH; ++c) {
    if (c < NCH - 1) grab(c + 1);
    comp(c & 1);
    if (c < NCH - 1) {
      __syncthreads();
      put((c + 1) & 1);
      __syncthreads();
    }
  }

#pragma unroll
  for (int mt = 0; mt < 4; ++mt) {
    int co = co_base + coh + mt * 16 + q * 4;
    float t0 = t2v[co], t1 = t2v[co + 1], t2 = t2v[co + 2], t3 = t2v[co + 3];
#pragma unroll
    for (int nt = 0; nt < 4; ++nt) {
      int pix = pix0 + pxh + nt * 16 + ln;
      short4 p;
      p.x = rnbf(siluf(acc[mt][nt][0] + t0));
      p.y = rnbf(siluf(acc[mt][nt][1] + t1));
      p.z = rnbf(siluf(acc[mt][nt][2] + t2));
      p.w = rnbf(siluf(acc[mt][nt][3] + t3));
      *(short4*)(y2b + pix * TC2 + co) = p;
    }
  }
}

// ---------------- input_proj: LDS-staged bf16 MFMA GEMM 256->256 + bias (unchanged) ----------------
__global__ __launch_bounds__(256) void k_proj_in(const short* __restrict__ y2b, const short* __restrict__ inwb,
                                                 const float* __restrict__ inb, short* __restrict__ xproj)
{
  __shared__ short As[2][128 * A_STR];
  __shared__ short Bs[2][128 * A_STR];

  int b = blockIdx.x;
  int ch = b & 1; int pt = b >> 1;
  int co_base = ch * 128;
  int pix0 = pt * 128;

  int tid = threadIdx.x;
  int wave = tid >> 6, lane = tid & 63;
  int ln = lane & 15, q = lane >> 4;
  int coh = (wave & 1) * 64;
  int pxh = (wave >> 1) * 64;

  int srow = tid >> 1;
  int ssub = (tid & 1) * 16;
  const short* arow = inwb + (co_base + srow) * TC2 + ssub;
  const short* brow = y2b + (pix0 + srow) * TC2 + ssub;

  f32x4 acc[4][4];
#pragma unroll
  for (int i = 0; i < 4; ++i)
#pragma unroll
    for (int j = 0; j < 4; ++j) acc[i][j] = (f32x4){0.f, 0.f, 0.f, 0.f};

  bf16x8 ra0, ra1, rb0, rb1;
  auto grab = [&](int c) {
    const short* ap = arow + c * 32;
    const short* bp = brow + c * 32;
    ra0 = *(const bf16x8*)(ap);
    ra1 = *(const bf16x8*)(ap + 8);
    rb0 = *(const bf16x8*)(bp);
    rb1 = *(const bf16x8*)(bp + 8);
  };
  auto put = [&](int buf) {
    int o = srow * A_STR + ssub;
    *(bf16x8*)(&As[buf][o])     = ra0;
    *(bf16x8*)(&As[buf][o + 8]) = ra1;
    *(bf16x8*)(&Bs[buf][o])     = rb0;
    *(bf16x8*)(&Bs[buf][o + 8]) = rb1;
  };
  auto comp = [&](int buf) {
    bf16x8 af[4], bfv[4];
#pragma unroll
    for (int mt = 0; mt < 4; ++mt)
      af[mt] = *(const bf16x8*)(&As[buf][(coh + mt * 16 + ln) * A_STR + q * 8]);
#pragma unroll
    for (int nt = 0; nt < 4; ++nt)
      bfv[nt] = *(const bf16x8*)(&Bs[buf][(pxh + nt * 16 + ln) * A_STR + q * 8]);
#pragma unroll
    for (int mt = 0; mt < 4; ++mt)
#pragma unroll
      for (int nt = 0; nt < 4; ++nt)
        acc[mt][nt] = __builtin_amdgcn_mfma_f32_16x16x32_bf16(af[mt], bfv[nt], acc[mt][nt], 0, 0, 0);
  };

  const int NCH = TC2 / 32;
  grab(0);
  put(0);
  __syncthreads();
  for (int c = 0; c < NCH; ++c) {
    if (c < NCH - 1) grab(c + 1);
    comp(c & 1);
    if (c < NCH - 1) {
      __syncthreads();
      put((c + 1) & 1);
      __syncthreads();
    }
  }

#pragma unroll
  for (int mt = 0; mt < 4; ++mt) {
    int co = co_base + coh + mt * 16 + q * 4;
    float b0 = inb[co], b1 = inb[co + 1], b2 = inb[co + 2], b3 = inb[co + 3];
#pragma unroll
    for (int nt = 0; nt < 4; ++nt) {
      int pix = pix0 + pxh + nt * 16 + ln;
      short4 p;
      p.x = rnbf(acc[mt][nt][0] + b0);
      p.y = rnbf(acc[mt][nt][1] + b1);
      p.z = rnbf(acc[mt][nt][2] + b2);
      p.w = rnbf(acc[mt][nt][3] + b3);
      *(short4*)(xproj + pix * TC2 + co) = p;
    }
  }
}

// ---------------- depthwise 3x3 + bias + LN + GELU: 2 px/wave, 8 ch/lane ----------------
// grid 3200 = 25600/8; 4 waves x 2 pixels; lane owns 8 channels (16B loads)
__global__ __launch_bounds__(256) void k_dwln(const short* __restrict__ y2b, const float* __restrict__ dwt,
                                              const float* __restrict__ dwb, const float* __restrict__ lng,
                                              const float* __restrict__ lnb, short* __restrict__ dwo)
{
  int tid = threadIdx.x;
  int wave = tid >> 6, lane = tid & 63;
  int half = lane >> 5;
  int pix = blockIdx.x * 8 + wave * 2 + half;
  int w = pix % TW; int h = (pix / TW) % TH; int n = pix / (TH * TW);
  int c0 = (lane & 31) * 8;

  float v[8];
  {
    float4 b0 = *(const float4*)(dwb + c0);
    float4 b1 = *(const float4*)(dwb + c0 + 4);
    v[0] = b0.x; v[1] = b0.y; v[2] = b0.z; v[3] = b0.w;
    v[4] = b1.x; v[5] = b1.y; v[6] = b1.z; v[7] = b1.w;
  }
#pragma unroll
  for (int dy = 0; dy < 3; ++dy) {
#pragma unroll
    for (int dx = 0; dx < 3; ++dx) {
      int hh = h + dy - 1, ww = w + dx - 1;
      bool ok = (hh >= 0) & (hh < TH) & (ww >= 0) & (ww < TW);
      int off = ok ? (((n * TH + hh) * TW + ww) * TC2 + c0) : c0;
      bf16x8 yv = *(const bf16x8*)(y2b + off);
      float m = ok ? 1.f : 0.f;
      const float* wp = dwt + (dy * 3 + dx) * TC2 + c0;
      float4 w0 = *(const float4*)(wp);
      float4 w1 = *(const float4*)(wp + 4);
      v[0] += bf2f(yv[0]) * w0.x * m;
      v[1] += bf2f(yv[1]) * w0.y * m;
      v[2] += bf2f(yv[2]) * w0.z * m;
      v[3] += bf2f(yv[3]) * w0.w * m;
      v[4] += bf2f(yv[4]) * w1.x * m;
      v[5] += bf2f(yv[5]) * w1.y * m;
      v[6] += bf2f(yv[6]) * w1.z * m;
      v[7] += bf2f(yv[7]) * w1.w * m;
    }
  }
  float sv = 0.f, sq = 0.f;
#pragma unroll
  for (int i = 0; i < 8; ++i) { sv += v[i]; sq += v[i] * v[i]; }
#pragma unroll
  for (int o = 16; o > 0; o >>= 1) { sv += __shfl_xor(sv, o); sq += __shfl_xor(sq, o); }  // o<=16: stays per-half
  float mu = sv * (1.f / 256.f);
  float var = sq * (1.f / 256.f) - mu * mu;
  float rs = 1.f / sqrtf(var + 1e-6f);
  float4 g0 = *(const float4*)(lng + c0);
  float4 g1 = *(const float4*)(lng + c0 + 4);
  float4 bb0 = *(const float4*)(lnb + c0);
  float4 bb1 = *(const float4*)(lnb + c0 + 4);
  float gv[8] = {g0.x, g0.y, g0.z, g0.w, g1.x, g1.y, g1.z, g1.w};
  float bv[8] = {bb0.x, bb0.y, bb0.z, bb0.w, bb1.x, bb1.y, bb1.z, bb1.w};
  const float is2 = 0.70710678118654752f;
  bf16x8 o8;
#pragma unroll
  for (int i = 0; i < 8; ++i) {
    float nv = (v[i] - mu) * rs * gv[i] + bv[i];
    o8[i] = rnbf(0.5f * nv * (1.f + erff(nv * is2)));
  }
  *(bf16x8*)(dwo + pix * TC2 + c0) = o8;
}

// ---------------- offset/mask logits via MFMA (unchanged) ----------------
__global__ __launch_bounds__(256) void k_offmask(const short* __restrict__ dwo, const short* __restrict__ wcatb16,
                                                 const float* __restrict__ wcatb, float* __restrict__ raw)
{
  int tid = threadIdx.x;
  int wave = tid >> 6, lane = tid & 63;
  int ln = lane & 15, q = lane >> 4;
  int pix0 = blockIdx.x * 64 + wave * 16;

  f32x4 acc0 = {0.f, 0.f, 0.f, 0.f};
  f32x4 acc1 = acc0;

  const short* a0p = wcatb16 + ln * 256 + q * 8;
  const short* a1p = wcatb16 + (16 + ln) * 256 + q * 8;
  const short* bp  = dwo + (pix0 + ln) * 256 + q * 8;
#pragma unroll
  for (int kk = 0; kk < 256; kk += 32) {
    bf16x8 bf = *(const bf16x8*)(bp + kk);
    bf16x8 a0 = *(const bf16x8*)(a0p + kk);
    bf16x8 a1 = *(const bf16x8*)(a1p + kk);
    acc0 = __builtin_amdgcn_mfma_f32_16x16x32_bf16(a0, bf, acc0, 0, 0, 0);
    acc1 = __builtin_amdgcn_mfma_f32_16x16x32_bf16(a1, bf, acc1, 0, 0, 0);
  }

  int pix = pix0 + ln;
#pragma unroll
  for (int r = 0; r < 4; ++r) {
    int j0 = q * 4 + r;
    raw[pix * 27 + j0] = acc0[r] + wcatb[j0];
    int j1 = 16 + j0;
    if (j1 < 27) raw[pix * 27 + j1] = acc1[r] + wcatb[j1];
  }
}

// ---------------- DCN core: 8 px/block setup, 2 px/wave, 8 ch/lane (16B gathers) ----------------
// grid 3200 = 25600/8
__global__ __launch_bounds__(256) void k_dcn(const short* __restrict__ xproj, const float* __restrict__ raw,
                                             short* __restrict__ z)
{
  __shared__ int2 sp[8][36];
  int tid = threadIdx.x;
  int pixbase = blockIdx.x * 8;

  for (int j = tid; j < 288; j += 256) {     // 8 px x 36 taps, setup once per block
    int pxl = j / 36, t = j - pxl * 36;
    int pix = pixbase + pxl;
    int w = pix % TW; int h = (pix / TW) % TH;
    const float* r = raw + pix * 27;
    int k = t >> 2, tap = t & 3;
    int tx = tap & 1, ty = tap >> 1;
    float mx = r[18];
#pragma unroll
    for (int kk = 1; kk < 9; ++kk) mx = fmaxf(mx, r[18 + kk]);
    float sum = 0.f, ek = 0.f;
#pragma unroll
    for (int kk = 0; kk < 9; ++kk) {
      float ee = expf(r[18 + kk] - mx);
      sum += ee;
      if (kk == k) ek = ee;
    }
    float mk = ek / sum;
    float px = (float)(w + k / 3) + r[2 * k];
    float py = (float)(h + k % 3) + r[2 * k + 1];
    float x0f = floorf(px), y0f = floorf(py);
    float lw = px - x0f, lh = py - y0f;
    int x0 = (int)x0f + tx, y0 = (int)y0f + ty;
    float wt = mk * (tx ? lw : 1.f - lw) * (ty ? lh : 1.f - lh);
    bool valid = (x0 >= 1) & (x0 <= TW) & (y0 >= 1) & (y0 <= TH);
    int2 pr;
    pr.x = valid ? (((y0 - 1) * TW + (x0 - 1)) * TC2) : 0;
    pr.y = valid ? __float_as_int(wt) : 0;
    sp[pxl][t] = pr;
  }
  __syncthreads();

  int wave = tid >> 6, lane = tid & 63;
  int half = lane >> 5;
  int pxl = wave * 2 + half;
  int pix = pixbase + pxl;
  int n = pix / (TH * TW);
  int c0 = (lane & 31) * 8;
  const short* xb = xproj + n * (TH * TW * TC2) + c0;

  float a[8] = {0.f, 0.f, 0.f, 0.f, 0.f, 0.f, 0.f, 0.f};
#pragma unroll
  for (int t = 0; t < 36; ++t) {
    int2 pr = sp[pxl][t];
    float wt = __int_as_float(pr.y);
    bf16x8 v = *(const bf16x8*)(xb + pr.x);
#pragma unroll
    for (int i = 0; i < 8; ++i) a[i] += wt * bf2f(v[i]);
  }
  bf16x8 o8;
#pragma unroll
  for (int i = 0; i < 8; ++i) o8[i] = rnbf(a[i]);
  *(bf16x8*)(z + pix * TC2 + c0) = o8;
}

// ---------------- output_proj: LDS-staged MFMA + BN + SiLU + residual (unchanged) ----------------
__global__ __launch_bounds__(256) void k_proj_out(const short* __restrict__ zb, const short* __restrict__ outwb,
                                                  const float* __restrict__ t3p,
                                                  const float* __restrict__ x, float* __restrict__ out)
{
  __shared__ short As[2][128 * A_STR];
  __shared__ short Bs[2][128 * A_STR];

  int b = blockIdx.x;
  int ch = b & 1; int pt = b >> 1;
  int co_base = ch * 128;
  int pix0 = pt * 128;

  int tid = threadIdx.x;
  int wave = tid >> 6, lane = tid & 63;
  int ln = lane & 15, q = lane >> 4;
  int coh = (wave & 1) * 64;
  int pxh = (wave >> 1) * 64;

  int srow = tid >> 1;
  int ssub = (tid & 1) * 16;
  const short* arow = outwb + (co_base + srow) * TC2 + ssub;
  const short* brow = zb + (pix0 + srow) * TC2 + ssub;

  f32x4 acc[4][4];
#pragma unroll
  for (int i = 0; i < 4; ++i)
#pragma unroll
    for (int j = 0; j < 4; ++j) acc[i][j] = (f32x4){0.f, 0.f, 0.f, 0.f};

  bf16x8 ra0, ra1, rb0, rb1;
  auto grab = [&](int c) {
    const short* ap = arow + c * 32;
    const short* bp = brow + c * 32;
    ra0 = *(const bf16x8*)(ap);
    ra1 = *(const bf16x8*)(ap + 8);
    rb0 = *(const bf16x8*)(bp);
    rb1 = *(const bf16x8*)(bp + 8);
  };
  auto put = [&](int buf) {
    int o = srow * A_STR + ssub;
    *(bf16x8*)(&As[buf][o])     = ra0;
    *(bf16x8*)(&As[buf][o + 8]) = ra1;
    *(bf16x8*)(&Bs[buf][o])     = rb0;
    *(bf16x8*)(&Bs[buf][o + 8]) = rb1;
  };
  auto comp = [&](int buf) {
    bf16x8 af[4], bfv[4];
#pragma unroll
    for (int mt = 0; mt < 4; ++mt)
      af[mt] = *(const bf16x8*)(&As[buf][(coh + mt * 16 + ln) * A_STR + q * 8]);
#pragma unroll
    for (int nt = 0; nt < 4; ++nt)
      bfv[nt] = *(const bf16x8*)(&Bs[buf][(pxh + nt * 16 + ln) * A_STR + q * 8]);
#pragma unroll
    for (int mt = 0; mt < 4; ++mt)
#pragma unroll
      for (int nt = 0; nt < 4; ++nt)
        acc[mt][nt] = __builtin_amdgcn_mfma_f32_16x16x32_bf16(af[mt], bfv[nt], acc[mt][nt], 0, 0, 0);
  };

  const int NCH = TC2 / 32;
  grab(0);
  put(0);
  __syncthreads();
  for (int c = 0; c < NCH; ++c) {
    if (c < NCH - 1) grab(c + 1);
    comp(c & 1);
    if (c < NCH - 1) {
      __syncthreads();
      put((c + 1) & 1);
      __syncthreads();
    }
  }

#pragma unroll
  for (int mt = 0; mt < 4; ++mt) {
    int co = co_base + coh + mt * 16 + q * 4;
#pragma unroll
    for (int nt = 0; nt < 4; ++nt) {
      int pix = pix0 + pxh + nt * 16 + ln;
      int n = pix / (TH * TW);
      int hw = pix - n * (TH * TW);
#pragma unroll
      for (int r = 0; r < 4; ++r) {
        int addr = (n * TC2 + co + r) * (TH * TW) + hw;
        out[addr] = x[addr] + siluf(acc[mt][nt][r] + t3p[co + r]);
      }
    }
  }
}

extern "C" void kernel_launch(void* const* d_in, const int* in_sizes, int n_in,
                              void* d_out, int out_size, void* d_ws, size_t ws_size,
                              hipStream_t stream)
{
  const float* x    = (const float*)d_in[0];
  const float* w1   = (const float*)d_in[1];
  const float* g1   = (const float*)d_in[2];
  const float* b1   = (const float*)d_in[3];
  const float* m1   = (const float*)d_in[4];
  const float* v1   = (const float*)d_in[5];
  const float* w2   = (const float*)d_in[6];
  const float* g2   = (const float*)d_in[7];
  const float* b2   = (const float*)d_in[8];
  const float* m2   = (const float*)d_in[9];
  const float* v2   = (const float*)d_in[10];
  const float* dww  = (const float*)d_in[11];
  const float* dwb  = (const float*)d_in[12];
  const float* lng  = (const float*)d_in[13];
  const float* lnb  = (const float*)d_in[14];
  const float* offw = (const float*)d_in[15];
  const float* offb = (const float*)d_in[16];
  const float* mskw = (const float*)d_in[17];
  const float* mskb = (const float*)d_in[18];
  const float* inw  = (const float*)d_in[19];
  const float* inb  = (const float*)d_in[20];
  const float* outw = (const float*)d_in[21];
  const float* outb = (const float*)d_in[22];
  const float* g3   = (const float*)d_in[23];
  const float* b3   = (const float*)d_in[24];
  const float* m3   = (const float*)d_in[25];
  const float* v3   = (const float*)d_in[26];

  float* ws  = (float*)d_ws;
  float* out = (float*)d_out;

  short* xpn    = (short*)(ws + OFF_XPAD);
  short* wbf    = (short*)(ws + OFF_WBF);
  short* w2b    = (short*)(ws + OFF_W2B);
  short* inwb   = (short*)(ws + OFF_INWB);
  short* outwb  = (short*)(ws + OFF_OUTWB);
  short* wcat16 = (short*)(ws + OFF_WCAT);
  float* y1p    = ws + OFF_Y1P;
  short* y1b    = (short*)(ws + OFF_Y1B);
  short* y2b    = (short*)(ws + OFF_Y2N);
  short* dwo    = (short*)(ws + OFF_DWN);
  float* raw    = ws + OFF_RAWN;
  short* zb     = (short*)(ws + OFF_ZN);
  short* xproj  = (short*)d_out;

  hipLaunchKernelGGL(k_prep, dim3(1836), dim3(256), 0, stream,
                     w1, g1, b1, m1, v1, w2, g2, b2, m2, v2,
                     dww, offw, offb, mskw, mskb, inw, outw, outb, g3, b3, m3, v3, ws);
  hipLaunchKernelGGL(k_padx,     dim3(TN * THP * 8), dim3(256), 0, stream, x, xpn);
  hipLaunchKernelGGL(k_cv1,      dim3(600),   dim3(256), 0, stream, xpn, wbf, y1p);
  hipLaunchKernelGGL(k_y1red,    dim3(3200),  dim3(256), 0, stream, y1p, ws + OFF_T1, y1b);
  hipLaunchKernelGGL(k_cv2,      dim3(400),   dim3(256), 0, stream, y1b, w2b, ws + OFF_T2, y2b);
  hipLaunchKernelGGL(k_proj_in,  dim3(400),   dim3(256), 0, stream, y2b, inwb, inb, xproj);
  hipLaunchKernelGGL(k_dwln,     dim3(3200),  dim3(256), 0, stream, y2b, ws + OFF_DWT, dwb, lng, lnb, dwo);
  hipLaunchKernelGGL(k_offmask,  dim3(400),   dim3(256), 0, stream, dwo, wcat16, ws + OFF_WCATB, raw);
  hipLaunchKernelGGL(k_dcn,      dim3(3200),  dim3(256), 0, stream, xproj, raw, zb);
  hipLaunchKernelGGL(k_proj_out, dim3(400),   dim3(256), 0, stream, zb, outwb, ws + OFF_T3P, x, out);
}